// Round 1
// baseline (883.826 us; speedup 1.0000x reference)
//
#include <hip/hip_runtime.h>

#define NN 50000
#define NE 800000
#define ET 850000   // NE + NN self-loops

// ---------------------------------------------------------------- utilities
__device__ __forceinline__ float elu1(float x) {
    return x > 0.f ? x : (__expf(x) - 1.f);
}

// ---------------------------------------------------------------- CSR build
__global__ void k_init(int* __restrict__ cursor, float* __restrict__ gsum) {
    int i = blockIdx.x * blockDim.x + threadIdx.x;
    if (i < NN) cursor[i] = 1;          // pre-count the self-loop of node i
    if (i < 64) gsum[i] = 0.f;
}

__global__ void k_hist(const int* __restrict__ dst, int* __restrict__ cursor) {
    int e = blockIdx.x * blockDim.x + threadIdx.x;
    if (e < NE) atomicAdd(&cursor[dst[e]], 1);
}

// single block, 1024 threads: exclusive scan of cursor -> row_ptr, cursor := row_ptr
__global__ void k_scan(int* __restrict__ cursor, int* __restrict__ row_ptr) {
    __shared__ int wsum[16];
    __shared__ int chunk_tot;
    int t = threadIdx.x, lane = t & 63, w = t >> 6;
    int carry = 0;
    for (int base = 0; base < NN; base += 1024) {
        int i = base + t;
        int v = (i < NN) ? cursor[i] : 0;
        int x = v;
        #pragma unroll
        for (int o = 1; o < 64; o <<= 1) {
            int y = __shfl_up(x, o, 64);
            if (lane >= o) x += y;
        }
        if (lane == 63) wsum[w] = x;
        __syncthreads();
        if (t == 0) {
            int acc = 0;
            #pragma unroll
            for (int k = 0; k < 16; k++) { int tmp = wsum[k]; wsum[k] = acc; acc += tmp; }
            chunk_tot = acc;
        }
        __syncthreads();
        int excl = x - v + wsum[w] + carry;
        if (i < NN) { row_ptr[i] = excl; cursor[i] = excl; }
        carry += chunk_tot;
        __syncthreads();
    }
    if (t == 0) row_ptr[NN] = ET;
}

__global__ void k_scatter(const int* __restrict__ ei, int* __restrict__ cursor,
                          int* __restrict__ csr) {
    int e = blockIdx.x * blockDim.x + threadIdx.x;
    if (e >= ET) return;
    int s, d;
    if (e < NE) { s = ei[e]; d = ei[NE + e]; }
    else        { s = d = e - NE; }
    int pos = atomicAdd(&cursor[d], 1);
    csr[pos] = s;
}

// ---------------------------------------------------------------- fp32 GEMM
// C[M x NC] = A[M x K] @ B[K x NC] (+bias, +elu). BM=BN=64, BK=16, 256 thr, 4x4/thr
template<bool ELU>
__global__ __launch_bounds__(256) void gemm_f32(const float* __restrict__ A,
                                                const float* __restrict__ B,
                                                const float* __restrict__ bias,
                                                float* __restrict__ C,
                                                int M, int K, int NC) {
    __shared__ float As[16][68];   // padded: keeps float4 reads aligned, conflicts <=2-way
    __shared__ float Bs[16][64];
    int tid = threadIdx.x;
    int tx = tid & 15, ty = tid >> 4;
    int mb = blockIdx.x * 64, nb = blockIdx.y * 64;

    int am = tid >> 2;           // 0..63  (A tile row)
    int ak = (tid & 3) * 4;      // 0,4,8,12
    int bn = (tid & 15) * 4;     // B tile col
    int bk = tid >> 4;           // 0..15
    int arow = mb + am; if (arow > M - 1) arow = M - 1;   // clamp (results masked at store)
    const float* Aptr = A + (size_t)arow * K + ak;

    float acc[4][4] = {};
    for (int k0 = 0; k0 < K; k0 += 16) {
        float4 av = *(const float4*)(Aptr + k0);
        float4 bv = *(const float4*)(B + (size_t)(k0 + bk) * NC + nb + bn);
        As[ak + 0][am] = av.x; As[ak + 1][am] = av.y;
        As[ak + 2][am] = av.z; As[ak + 3][am] = av.w;
        *(float4*)&Bs[bk][bn] = bv;
        __syncthreads();
        #pragma unroll
        for (int kk = 0; kk < 16; kk++) {
            float4 a = *(const float4*)&As[kk][ty * 4];
            float4 b = *(const float4*)&Bs[kk][tx * 4];
            acc[0][0] += a.x * b.x; acc[0][1] += a.x * b.y; acc[0][2] += a.x * b.z; acc[0][3] += a.x * b.w;
            acc[1][0] += a.y * b.x; acc[1][1] += a.y * b.y; acc[1][2] += a.y * b.z; acc[1][3] += a.y * b.w;
            acc[2][0] += a.z * b.x; acc[2][1] += a.z * b.y; acc[2][2] += a.z * b.z; acc[2][3] += a.z * b.w;
            acc[3][0] += a.w * b.x; acc[3][1] += a.w * b.y; acc[3][2] += a.w * b.z; acc[3][3] += a.w * b.w;
        }
        __syncthreads();
    }
    #pragma unroll
    for (int i = 0; i < 4; i++) {
        int r = mb + ty * 4 + i;
        if (r < M) {
            float4 o;
            float* op = (float*)&o;
            #pragma unroll
            for (int j = 0; j < 4; j++) {
                float v = acc[i][j];
                if (bias) v += bias[nb + tx * 4 + j];
                if (ELU) v = elu1(v);
                op[j] = v;
            }
            *(float4*)&C[(size_t)r * NC + nb + tx * 4] = o;
        }
    }
}

// ------------------------------------------------- per-node attention logits
// e_src[n,h] = dot(xl[n,h,:], a_s[h,:]); e_dst likewise. 1 wave = 1 (node,head).
template<int HEADS>
__global__ __launch_bounds__(256) void k_edot(const float* __restrict__ xl,
                                              const float* __restrict__ a_s,
                                              const float* __restrict__ a_d,
                                              float* __restrict__ es,
                                              float* __restrict__ ed) {
    constexpr int NPB = 4 / HEADS;   // nodes per 256-thread block
    int lane = threadIdx.x & 63, wave = threadIdx.x >> 6;
    int node = blockIdx.x * NPB + wave / HEADS;
    int head = wave % HEADS;
    if (node >= NN) return;
    float v = xl[(size_t)node * (HEADS * 64) + head * 64 + lane];
    float ps = v * a_s[head * 64 + lane];
    float pd = v * a_d[head * 64 + lane];
    #pragma unroll
    for (int o = 32; o >= 1; o >>= 1) {
        ps += __shfl_down(ps, o, 64);
        pd += __shfl_down(pd, o, 64);
    }
    if (lane == 0) {
        es[node * HEADS + head] = ps;
        ed[node * HEADS + head] = pd;
    }
}

// ------------------------------------------------- online-softmax aggregate
// 1 wave per dst node; lane holds VEC consecutive feature dims (one head each).
template<int HEADS>
__global__ __launch_bounds__(256) void k_agg(const float* __restrict__ xl,
                                             const float* __restrict__ es,
                                             const float* __restrict__ ed,
                                             const int* __restrict__ row_ptr,
                                             const int* __restrict__ csr,
                                             const float* __restrict__ bias,
                                             float* __restrict__ out) {
    constexpr int ROW = HEADS * 64;
    constexpr int VEC = ROW / 64;    // 4 for HEADS=4, 1 for HEADS=1
    int lane = threadIdx.x & 63, wave = threadIdx.x >> 6;
    int node = blockIdx.x * 4 + wave;
    if (node >= NN) return;
    int head = (lane * VEC) >> 6;
    float edl = ed[node * HEADS + head];
    int start = row_ptr[node], end = row_ptr[node + 1];

    float m = -1e30f, lsum = 0.f;
    float a0 = 0.f, a1 = 0.f, a2 = 0.f, a3 = 0.f;
    int s_next = __builtin_amdgcn_readfirstlane(csr[start]);   // deg >= 1 (self-loop)
    for (int j = start; j < end; ++j) {
        int s = s_next;
        if (j + 1 < end) s_next = __builtin_amdgcn_readfirstlane(csr[j + 1]);
        float e = es[s * HEADS + head] + edl;
        e = e > 0.f ? e : 0.2f * e;              // leaky_relu(0.2)
        float mn = fmaxf(m, e);
        float sc = __expf(m - mn);
        float w  = __expf(e - mn);
        lsum = lsum * sc + w;
        if constexpr (VEC == 4) {
            float4 xv = *(const float4*)(xl + (size_t)s * ROW + lane * 4);
            a0 = a0 * sc + w * xv.x;
            a1 = a1 * sc + w * xv.y;
            a2 = a2 * sc + w * xv.z;
            a3 = a3 * sc + w * xv.w;
        } else {
            float xv = xl[(size_t)s * ROW + lane];
            a0 = a0 * sc + w * xv;
        }
        m = mn;
    }
    float inv = 1.f / lsum;
    if constexpr (VEC == 4) {
        float4 o;
        o.x = elu1(a0 * inv + bias[lane * 4 + 0]);
        o.y = elu1(a1 * inv + bias[lane * 4 + 1]);
        o.z = elu1(a2 * inv + bias[lane * 4 + 2]);
        o.w = elu1(a3 * inv + bias[lane * 4 + 3]);
        *(float4*)(out + (size_t)node * ROW + lane * 4) = o;
    } else {
        out[(size_t)node * ROW + lane] = elu1(a0 * inv + bias[lane]);
    }
}

// ---------------------------------------------------------------- pooling
__global__ void k_pool(const float* __restrict__ fnl, float* __restrict__ gsum) {
    __shared__ float sm[4][64];
    int t = threadIdx.x, c = t & 63, w = t >> 6;
    float s = 0.f;
    for (int r = blockIdx.x * 4 + w; r < NN; r += gridDim.x * 4)
        s += fnl[(size_t)r * 64 + c];
    sm[w][c] = s;
    __syncthreads();
    if (w == 0) {
        float tot = sm[0][c] + sm[1][c] + sm[2][c] + sm[3][c];
        atomicAdd(&gsum[c], tot);
    }
}

__global__ void k_final(const float* __restrict__ gsum, const float* __restrict__ w_out,
                        const float* __restrict__ b_out, float* __restrict__ out) {
    int j = threadIdx.x;   // 128
    float s = b_out[j];
    const float invn = 1.f / (float)NN;
    #pragma unroll 8
    for (int k = 0; k < 64; k++)
        s += (gsum[k] * invn) * w_out[k * 128 + j];
    out[j] = s;
}

// ---------------------------------------------------------------- launcher
extern "C" void kernel_launch(void* const* d_in, const int* in_sizes, int n_in,
                              void* d_out, int out_size, void* d_ws, size_t ws_size,
                              hipStream_t stream) {
    const float* x    = (const float*)d_in[0];
    const int*   ei   = (const int*)d_in[1];
    const float* w_in = (const float*)d_in[2];
    const float* b_in = (const float*)d_in[3];
    const float* W0   = (const float*)d_in[4];
    const float* as0  = (const float*)d_in[5];
    const float* ad0  = (const float*)d_in[6];
    const float* bb0  = (const float*)d_in[7];
    const float* W1   = (const float*)d_in[8];
    const float* as1  = (const float*)d_in[9];
    const float* ad1  = (const float*)d_in[10];
    const float* bb1  = (const float*)d_in[11];
    const float* W2   = (const float*)d_in[12];
    const float* as2  = (const float*)d_in[13];
    const float* ad2  = (const float*)d_in[14];
    const float* bb2  = (const float*)d_in[15];
    const float* w_out= (const float*)d_in[16];
    const float* b_out= (const float*)d_in[17];
    float* out = (float*)d_out;

    // workspace carve-up (~121 MB)
    char* p = (char*)d_ws;
    size_t off = 0;
    auto take = [&](size_t bytes) {
        char* r = p + off;
        off = (off + bytes + 255) & ~(size_t)255;
        return r;
    };
    float* h0     = (float*)take((size_t)NN * 64 * 4);    // reused as xl2 for layer 2
    float* xl     = (float*)take((size_t)NN * 256 * 4);   // reused as fnl for layer 2 out
    float* hb     = (float*)take((size_t)NN * 256 * 4);
    float* es     = (float*)take((size_t)NN * 4 * 4);
    float* ed     = (float*)take((size_t)NN * 4 * 4);
    int*   row_ptr= (int*)take((size_t)(NN + 1) * 4);
    int*   cursor = (int*)take((size_t)NN * 4);
    int*   csr    = (int*)take((size_t)ET * 4);
    float* gsum   = (float*)take(64 * 4);

    // ---- CSR build (by dst, with self-loops) ----
    k_init   <<<(NN + 255) / 256, 256, 0, stream>>>(cursor, gsum);
    k_hist   <<<(NE + 255) / 256, 256, 0, stream>>>(ei + NE, cursor);
    k_scan   <<<1, 1024, 0, stream>>>(cursor, row_ptr);
    k_scatter<<<(ET + 255) / 256, 256, 0, stream>>>(ei, cursor, csr);

    const int GX = (NN + 63) / 64;   // 782

    // ---- input projection: h0 = elu(x @ w_in + b_in) ----
    gemm_f32<true><<<dim3(GX, 1), 256, 0, stream>>>(x, w_in, b_in, h0, NN, 256, 64);

    // ---- GAT layer 0 (heads=4, concat) ----
    gemm_f32<false><<<dim3(GX, 4), 256, 0, stream>>>(h0, W0, nullptr, xl, NN, 64, 256);
    k_edot<4><<<NN, 256, 0, stream>>>(xl, as0, ad0, es, ed);
    k_agg<4><<<(NN + 3) / 4, 256, 0, stream>>>(xl, es, ed, row_ptr, csr, bb0, hb);

    // ---- GAT layer 1 (heads=4, concat) ----
    gemm_f32<false><<<dim3(GX, 4), 256, 0, stream>>>(hb, W1, nullptr, xl, NN, 256, 256);
    k_edot<4><<<NN, 256, 0, stream>>>(xl, as1, ad1, es, ed);
    k_agg<4><<<(NN + 3) / 4, 256, 0, stream>>>(xl, es, ed, row_ptr, csr, bb1, hb);

    // ---- GAT layer 2 (heads=1, mean==identity) ----
    gemm_f32<false><<<dim3(GX, 1), 256, 0, stream>>>(hb, W2, nullptr, h0, NN, 256, 64);
    k_edot<1><<<(NN + 3) / 4, 256, 0, stream>>>(h0, as2, ad2, es, ed);
    k_agg<1><<<(NN + 3) / 4, 256, 0, stream>>>(h0, es, ed, row_ptr, csr, bb2, xl);

    // ---- global mean pool + output projection ----
    k_pool <<<128, 256, 0, stream>>>(xl, gsum);
    k_final<<<1, 128, 0, stream>>>(gsum, w_out, b_out, out);
}

// Round 2
// 760.862 us; speedup vs baseline: 1.1616x; 1.1616x over previous
//
#include <hip/hip_runtime.h>

#define NN 50000
#define NE 800000
#define ET 850000   // NE + NN self-loops

typedef unsigned short ushort_t;
typedef unsigned int uint_t;

// ---------------------------------------------------------------- utilities
__device__ __forceinline__ float elu1(float x) {
    return x > 0.f ? x : (__expf(x) - 1.f);
}
__device__ __forceinline__ float bf2f(ushort_t u) {
    return __uint_as_float(((uint_t)u) << 16);
}
__device__ __forceinline__ ushort_t f2bf(float f) {   // round-to-nearest-even
    uint_t u = __float_as_uint(f);
    u += 0x7FFFu + ((u >> 16) & 1u);
    return (ushort_t)(u >> 16);
}

// ---------------------------------------------------------------- CSR build
__global__ void k_init(int* __restrict__ cursor, float* __restrict__ gsum) {
    int i = blockIdx.x * blockDim.x + threadIdx.x;
    if (i < NN) cursor[i] = 1;          // pre-count the self-loop of node i
    if (i < 64) gsum[i] = 0.f;
}

__global__ void k_hist(const int* __restrict__ dst, int* __restrict__ cursor) {
    int e = blockIdx.x * blockDim.x + threadIdx.x;
    if (e < NE) atomicAdd(&cursor[dst[e]], 1);
}

// single block, 1024 threads: exclusive scan of cursor -> row_ptr, cursor := row_ptr
__global__ void k_scan(int* __restrict__ cursor, int* __restrict__ row_ptr) {
    __shared__ int wsum[16];
    __shared__ int chunk_tot;
    int t = threadIdx.x, lane = t & 63, w = t >> 6;
    int carry = 0;
    for (int base = 0; base < NN; base += 1024) {
        int i = base + t;
        int v = (i < NN) ? cursor[i] : 0;
        int x = v;
        #pragma unroll
        for (int o = 1; o < 64; o <<= 1) {
            int y = __shfl_up(x, o, 64);
            if (lane >= o) x += y;
        }
        if (lane == 63) wsum[w] = x;
        __syncthreads();
        if (t == 0) {
            int acc = 0;
            #pragma unroll
            for (int k = 0; k < 16; k++) { int tmp = wsum[k]; wsum[k] = acc; acc += tmp; }
            chunk_tot = acc;
        }
        __syncthreads();
        int excl = x - v + wsum[w] + carry;
        if (i < NN) { row_ptr[i] = excl; cursor[i] = excl; }
        carry += chunk_tot;
        __syncthreads();
    }
    if (t == 0) row_ptr[NN] = ET;
}

__global__ void k_scatter(const int* __restrict__ ei, int* __restrict__ cursor,
                          int* __restrict__ csr) {
    int e = blockIdx.x * blockDim.x + threadIdx.x;
    if (e >= ET) return;
    int s, d;
    if (e < NE) { s = ei[e]; d = ei[NE + e]; }
    else        { s = d = e - NE; }
    int pos = atomicAdd(&cursor[d], 1);
    csr[pos] = s;
}

// ---------------------------------------------------------------- fp32 GEMM
// C[M x NC] = A[M x K] @ B[K x NC] (+bias, +elu). BM=BN=64, BK=16, 256 thr, 4x4/thr
// BF16OUT: epilogue packs to bf16 (for buffers that feed the gather kernels)
template<bool ELU, bool BF16OUT>
__global__ __launch_bounds__(256) void gemm_f32(const float* __restrict__ A,
                                                const float* __restrict__ B,
                                                const float* __restrict__ bias,
                                                void* __restrict__ Cv,
                                                int M, int K, int NC) {
    __shared__ float As[16][68];
    __shared__ float Bs[16][64];
    int tid = threadIdx.x;
    int tx = tid & 15, ty = tid >> 4;
    int mb = blockIdx.x * 64, nb = blockIdx.y * 64;

    int am = tid >> 2;           // 0..63  (A tile row)
    int ak = (tid & 3) * 4;      // 0,4,8,12
    int bn = (tid & 15) * 4;     // B tile col
    int bk = tid >> 4;           // 0..15
    int arow = mb + am; if (arow > M - 1) arow = M - 1;   // clamp (masked at store)
    const float* Aptr = A + (size_t)arow * K + ak;

    float acc[4][4] = {};
    for (int k0 = 0; k0 < K; k0 += 16) {
        float4 av = *(const float4*)(Aptr + k0);
        float4 bv = *(const float4*)(B + (size_t)(k0 + bk) * NC + nb + bn);
        As[ak + 0][am] = av.x; As[ak + 1][am] = av.y;
        As[ak + 2][am] = av.z; As[ak + 3][am] = av.w;
        *(float4*)&Bs[bk][bn] = bv;
        __syncthreads();
        #pragma unroll
        for (int kk = 0; kk < 16; kk++) {
            float4 a = *(const float4*)&As[kk][ty * 4];
            float4 b = *(const float4*)&Bs[kk][tx * 4];
            acc[0][0] += a.x * b.x; acc[0][1] += a.x * b.y; acc[0][2] += a.x * b.z; acc[0][3] += a.x * b.w;
            acc[1][0] += a.y * b.x; acc[1][1] += a.y * b.y; acc[1][2] += a.y * b.z; acc[1][3] += a.y * b.w;
            acc[2][0] += a.z * b.x; acc[2][1] += a.z * b.y; acc[2][2] += a.z * b.z; acc[2][3] += a.z * b.w;
            acc[3][0] += a.w * b.x; acc[3][1] += a.w * b.y; acc[3][2] += a.w * b.z; acc[3][3] += a.w * b.w;
        }
        __syncthreads();
    }
    #pragma unroll
    for (int i = 0; i < 4; i++) {
        int r = mb + ty * 4 + i;
        if (r < M) {
            float v[4];
            #pragma unroll
            for (int j = 0; j < 4; j++) {
                float t = acc[i][j];
                if (bias) t += bias[nb + tx * 4 + j];
                if (ELU) t = elu1(t);
                v[j] = t;
            }
            if constexpr (BF16OUT) {
                ushort_t* Cb = (ushort_t*)Cv;
                ushort4 o;
                o.x = f2bf(v[0]); o.y = f2bf(v[1]); o.z = f2bf(v[2]); o.w = f2bf(v[3]);
                *(ushort4*)&Cb[(size_t)r * NC + nb + tx * 4] = o;
            } else {
                float* Cf = (float*)Cv;
                float4 o; o.x = v[0]; o.y = v[1]; o.z = v[2]; o.w = v[3];
                *(float4*)&Cf[(size_t)r * NC + nb + tx * 4] = o;
            }
        }
    }
}

// ------------------------------------------------- per-node attention logits
// e_src[n,h] = dot(xl[n,h,:], a_s[h,:]); e_dst likewise. 1 wave = 1 (node,head).
template<int HEADS>
__global__ __launch_bounds__(256) void k_edot(const ushort_t* __restrict__ xl,
                                              const float* __restrict__ a_s,
                                              const float* __restrict__ a_d,
                                              float* __restrict__ es,
                                              float* __restrict__ ed) {
    constexpr int NPB = 4 / HEADS;   // nodes per 256-thread block
    int lane = threadIdx.x & 63, wave = threadIdx.x >> 6;
    int node = blockIdx.x * NPB + wave / HEADS;
    int head = wave % HEADS;
    if (node >= NN) return;
    float v = bf2f(xl[(size_t)node * (HEADS * 64) + head * 64 + lane]);
    float ps = v * a_s[head * 64 + lane];
    float pd = v * a_d[head * 64 + lane];
    #pragma unroll
    for (int o = 32; o >= 1; o >>= 1) {
        ps += __shfl_down(ps, o, 64);
        pd += __shfl_down(pd, o, 64);
    }
    if (lane == 0) {
        es[node * HEADS + head] = ps;
        ed[node * HEADS + head] = pd;
    }
}

// ------------------------------------------------- two-pass softmax aggregate
// 1 wave per dst node. Pass 1: lane-parallel (1 edge/lane) chunk-wise softmax
// stats via butterfly reductions (matches ref's segment_max formulation).
// Pass 2: weights -> LDS, then feature-parallel bf16 gather with independent
// accumulators (no loop-carried rescale).
template<int HEADS>
__global__ __launch_bounds__(256) void k_agg(const ushort_t* __restrict__ xl,
                                             const float* __restrict__ es,
                                             const float* __restrict__ ed,
                                             const int* __restrict__ row_ptr,
                                             const int* __restrict__ csr,
                                             const float* __restrict__ bias,
                                             float* __restrict__ out) {
    constexpr int ROW = HEADS * 64;
    constexpr int VEC = ROW / 64;    // 4 for HEADS=4, 1 for HEADS=1
    __shared__ float wlds[4][64 * HEADS];
    int lane = threadIdx.x & 63, wave = threadIdx.x >> 6;
    int node = blockIdx.x * 4 + wave;
    if (node >= NN) return;
    int head = (lane * VEC) >> 6;    // 0 when HEADS==1
    int start = row_ptr[node], end = row_ptr[node + 1];   // deg >= 1 (self-loop)

    float edh[HEADS];
    #pragma unroll
    for (int h = 0; h < HEADS; h++) edh[h] = ed[node * HEADS + h];

    // ---- pass 1: global max + sum per head ----
    float m[HEADS], ssum[HEADS];
    #pragma unroll
    for (int h = 0; h < HEADS; h++) { m[h] = -1e30f; ssum[h] = 0.f; }
    for (int base = start; base < end; base += 64) {
        int i = base + lane;
        bool valid = i < end;
        int idx = csr[valid ? i : start];
        float e[HEADS];
        if constexpr (HEADS == 4) {
            float4 ev = *(const float4*)(es + (size_t)idx * 4);
            e[0] = ev.x; e[1] = ev.y; e[2] = ev.z; e[3] = ev.w;
        } else {
            e[0] = es[idx];
        }
        #pragma unroll
        for (int h = 0; h < HEADS; h++) {
            float v = e[h] + edh[h];
            v = v > 0.f ? v : 0.2f * v;            // leaky_relu(0.2)
            e[h] = valid ? v : -1e30f;
        }
        float cm[HEADS];
        #pragma unroll
        for (int h = 0; h < HEADS; h++) cm[h] = e[h];
        #pragma unroll
        for (int o = 32; o >= 1; o >>= 1) {
            #pragma unroll
            for (int h = 0; h < HEADS; h++) cm[h] = fmaxf(cm[h], __shfl_xor(cm[h], o, 64));
        }
        float cs[HEADS];
        #pragma unroll
        for (int h = 0; h < HEADS; h++) cs[h] = valid ? __expf(e[h] - cm[h]) : 0.f;
        #pragma unroll
        for (int o = 32; o >= 1; o >>= 1) {
            #pragma unroll
            for (int h = 0; h < HEADS; h++) cs[h] += __shfl_xor(cs[h], o, 64);
        }
        #pragma unroll
        for (int h = 0; h < HEADS; h++) {
            float mn = fmaxf(m[h], cm[h]);
            ssum[h] = ssum[h] * __expf(m[h] - mn) + cs[h] * __expf(cm[h] - mn);
            m[h] = mn;
        }
    }
    float inv[HEADS];
    #pragma unroll
    for (int h = 0; h < HEADS; h++) inv[h] = 1.f / ssum[h];

    // ---- pass 2: alpha -> LDS, gather-accumulate ----
    float a[VEC];
    #pragma unroll
    for (int v = 0; v < VEC; v++) a[v] = 0.f;

    for (int base = start; base < end; base += 64) {
        int i = base + lane;
        bool valid = i < end;
        int idx = csr[valid ? i : start];
        int cnt = min(64, end - base);
        float e[HEADS];
        if constexpr (HEADS == 4) {
            float4 ev = *(const float4*)(es + (size_t)idx * 4);
            e[0] = ev.x; e[1] = ev.y; e[2] = ev.z; e[3] = ev.w;
        } else {
            e[0] = es[idx];
        }
        #pragma unroll
        for (int h = 0; h < HEADS; h++) {
            float v = e[h] + edh[h];
            v = v > 0.f ? v : 0.2f * v;
            e[h] = valid ? __expf(v - m[h]) * inv[h] : 0.f;
        }
        if constexpr (HEADS == 4) {
            float4 wv; wv.x = e[0]; wv.y = e[1]; wv.z = e[2]; wv.w = e[3];
            *(float4*)&wlds[wave][lane * 4] = wv;
        } else {
            wlds[wave][lane] = e[0];
        }
        for (int t = 0; t < cnt; ++t) {
            int s = __shfl(idx, t, 64);
            float w = wlds[wave][t * HEADS + head];
            if constexpr (VEC == 4) {
                ushort4 u = *(const ushort4*)(xl + (size_t)s * ROW + lane * 4);
                a[0] += w * bf2f(u.x);
                a[1] += w * bf2f(u.y);
                a[2] += w * bf2f(u.z);
                a[3] += w * bf2f(u.w);
            } else {
                a[0] += w * bf2f(xl[(size_t)s * ROW + lane]);
            }
        }
    }

    if constexpr (VEC == 4) {
        float4 o;
        o.x = elu1(a[0] + bias[lane * 4 + 0]);
        o.y = elu1(a[1] + bias[lane * 4 + 1]);
        o.z = elu1(a[2] + bias[lane * 4 + 2]);
        o.w = elu1(a[3] + bias[lane * 4 + 3]);
        *(float4*)(out + (size_t)node * ROW + lane * 4) = o;
    } else {
        out[(size_t)node * ROW + lane] = elu1(a[0] + bias[lane]);
    }
}

// ---------------------------------------------------------------- pooling
__global__ void k_pool(const float* __restrict__ fnl, float* __restrict__ gsum) {
    __shared__ float sm[4][64];
    int t = threadIdx.x, c = t & 63, w = t >> 6;
    float s = 0.f;
    for (int r = blockIdx.x * 4 + w; r < NN; r += gridDim.x * 4)
        s += fnl[(size_t)r * 64 + c];
    sm[w][c] = s;
    __syncthreads();
    if (w == 0) {
        float tot = sm[0][c] + sm[1][c] + sm[2][c] + sm[3][c];
        atomicAdd(&gsum[c], tot);
    }
}

__global__ void k_final(const float* __restrict__ gsum, const float* __restrict__ w_out,
                        const float* __restrict__ b_out, float* __restrict__ out) {
    int j = threadIdx.x;   // 128
    float s = b_out[j];
    const float invn = 1.f / (float)NN;
    #pragma unroll 8
    for (int k = 0; k < 64; k++)
        s += (gsum[k] * invn) * w_out[k * 128 + j];
    out[j] = s;
}

// ---------------------------------------------------------------- launcher
extern "C" void kernel_launch(void* const* d_in, const int* in_sizes, int n_in,
                              void* d_out, int out_size, void* d_ws, size_t ws_size,
                              hipStream_t stream) {
    const float* x    = (const float*)d_in[0];
    const int*   ei   = (const int*)d_in[1];
    const float* w_in = (const float*)d_in[2];
    const float* b_in = (const float*)d_in[3];
    const float* W0   = (const float*)d_in[4];
    const float* as0  = (const float*)d_in[5];
    const float* ad0  = (const float*)d_in[6];
    const float* bb0  = (const float*)d_in[7];
    const float* W1   = (const float*)d_in[8];
    const float* as1  = (const float*)d_in[9];
    const float* ad1  = (const float*)d_in[10];
    const float* bb1  = (const float*)d_in[11];
    const float* W2   = (const float*)d_in[12];
    const float* as2  = (const float*)d_in[13];
    const float* ad2  = (const float*)d_in[14];
    const float* bb2  = (const float*)d_in[15];
    const float* w_out= (const float*)d_in[16];
    const float* b_out= (const float*)d_in[17];
    float* out = (float*)d_out;

    char* p = (char*)d_ws;
    size_t off = 0;
    auto take = [&](size_t bytes) {
        char* r = p + off;
        off = (off + bytes + 255) & ~(size_t)255;
        return r;
    };
    float*    h0     = (float*)take((size_t)NN * 64 * 4);     // 12.8 MB
    ushort_t* xl_bf  = (ushort_t*)take((size_t)NN * 256 * 2); // 25.6 MB
    ushort_t* h2_bf  = (ushort_t*)take((size_t)NN * 64 * 2);  //  6.4 MB
    float*    hb     = (float*)take((size_t)NN * 256 * 4);    // 51.2 MB
    float*    fnl    = (float*)take((size_t)NN * 64 * 4);     // 12.8 MB
    float*    es     = (float*)take((size_t)NN * 4 * 4);
    float*    ed     = (float*)take((size_t)NN * 4 * 4);
    int*      row_ptr= (int*)take((size_t)(NN + 1) * 4);
    int*      cursor = (int*)take((size_t)NN * 4);
    int*      csr    = (int*)take((size_t)ET * 4);
    float*    gsum   = (float*)take(64 * 4);

    // ---- CSR build (by dst, with self-loops) ----
    k_init   <<<(NN + 255) / 256, 256, 0, stream>>>(cursor, gsum);
    k_hist   <<<(NE + 255) / 256, 256, 0, stream>>>(ei + NE, cursor);
    k_scan   <<<1, 1024, 0, stream>>>(cursor, row_ptr);
    k_scatter<<<(ET + 255) / 256, 256, 0, stream>>>(ei, cursor, csr);

    const int GX = (NN + 63) / 64;   // 782

    // ---- input projection: h0 = elu(x @ w_in + b_in) ----
    gemm_f32<true, false><<<dim3(GX, 1), 256, 0, stream>>>(x, w_in, b_in, h0, NN, 256, 64);

    // ---- GAT layer 0 (heads=4, concat) ----
    gemm_f32<false, true><<<dim3(GX, 4), 256, 0, stream>>>(h0, W0, nullptr, xl_bf, NN, 64, 256);
    k_edot<4><<<NN, 256, 0, stream>>>(xl_bf, as0, ad0, es, ed);
    k_agg<4><<<(NN + 3) / 4, 256, 0, stream>>>(xl_bf, es, ed, row_ptr, csr, bb0, hb);

    // ---- GAT layer 1 (heads=4, concat) ----
    gemm_f32<false, true><<<dim3(GX, 4), 256, 0, stream>>>(hb, W1, nullptr, xl_bf, NN, 256, 256);
    k_edot<4><<<NN, 256, 0, stream>>>(xl_bf, as1, ad1, es, ed);
    k_agg<4><<<(NN + 3) / 4, 256, 0, stream>>>(xl_bf, es, ed, row_ptr, csr, bb1, hb);

    // ---- GAT layer 2 (heads=1, mean==identity) ----
    gemm_f32<false, true><<<dim3(GX, 1), 256, 0, stream>>>(hb, W2, nullptr, h2_bf, NN, 256, 64);
    k_edot<1><<<(NN + 3) / 4, 256, 0, stream>>>(h2_bf, as2, ad2, es, ed);
    k_agg<1><<<(NN + 3) / 4, 256, 0, stream>>>(h2_bf, es, ed, row_ptr, csr, bb2, fnl);

    // ---- global mean pool + output projection ----
    k_pool <<<128, 256, 0, stream>>>(fnl, gsum);
    k_final<<<1, 128, 0, stream>>>(gsum, w_out, b_out, out);
}

// Round 3
// 666.890 us; speedup vs baseline: 1.3253x; 1.1409x over previous
//
#include <hip/hip_runtime.h>

#define NN 50000
#define NE 800000
#define ET 850000   // NE + NN self-loops

typedef unsigned short ushort_t;
typedef unsigned int uint_t;
typedef __attribute__((ext_vector_type(8))) short short8;
typedef __attribute__((ext_vector_type(4))) float f32x4;

// ---------------------------------------------------------------- utilities
__device__ __forceinline__ float elu1(float x) {
    return x > 0.f ? x : (__expf(x) - 1.f);
}
__device__ __forceinline__ float bf2f(ushort_t u) {
    return __uint_as_float(((uint_t)u) << 16);
}
__device__ __forceinline__ ushort_t f2bf(float f) {   // round-to-nearest-even
    uint_t u = __float_as_uint(f);
    u += 0x7FFFu + ((u >> 16) & 1u);
    return (ushort_t)(u >> 16);
}
__device__ __forceinline__ void gl_lds16(const ushort_t* g, ushort_t* l) {
    // async global->LDS, 16B/lane; LDS dest = wave-uniform base + lane*16
    __builtin_amdgcn_global_load_lds((const __attribute__((address_space(1))) void*)g,
                                     (__attribute__((address_space(3))) void*)l,
                                     16, 0, 0);
}

// ---------------------------------------------------------------- CSR build
__global__ void k_init(int* __restrict__ cursor, float* __restrict__ gsum) {
    int i = blockIdx.x * blockDim.x + threadIdx.x;
    if (i < NN) cursor[i] = 1;          // pre-count the self-loop of node i
    if (i < 64) gsum[i] = 0.f;
}

__global__ void k_hist(const int* __restrict__ dst, int* __restrict__ cursor) {
    int e = blockIdx.x * blockDim.x + threadIdx.x;
    if (e < NE) atomicAdd(&cursor[dst[e]], 1);
}

// single block, 1024 threads: exclusive scan of cursor -> row_ptr, cursor := row_ptr
__global__ void k_scan(int* __restrict__ cursor, int* __restrict__ row_ptr) {
    __shared__ int wsum[16];
    __shared__ int chunk_tot;
    int t = threadIdx.x, lane = t & 63, w = t >> 6;
    int carry = 0;
    for (int base = 0; base < NN; base += 1024) {
        int i = base + t;
        int v = (i < NN) ? cursor[i] : 0;
        int x = v;
        #pragma unroll
        for (int o = 1; o < 64; o <<= 1) {
            int y = __shfl_up(x, o, 64);
            if (lane >= o) x += y;
        }
        if (lane == 63) wsum[w] = x;
        __syncthreads();
        if (t == 0) {
            int acc = 0;
            #pragma unroll
            for (int k = 0; k < 16; k++) { int tmp = wsum[k]; wsum[k] = acc; acc += tmp; }
            chunk_tot = acc;
        }
        __syncthreads();
        int excl = x - v + wsum[w] + carry;
        if (i < NN) { row_ptr[i] = excl; cursor[i] = excl; }
        carry += chunk_tot;
        __syncthreads();
    }
    if (t == 0) row_ptr[NN] = ET;
}

__global__ void k_scatter(const int* __restrict__ ei, int* __restrict__ cursor,
                          int* __restrict__ csr) {
    int e = blockIdx.x * blockDim.x + threadIdx.x;
    if (e >= ET) return;
    int s, d;
    if (e < NE) { s = ei[e]; d = ei[NE + e]; }
    else        { s = d = e - NE; }
    int pos = atomicAdd(&cursor[d], 1);
    csr[pos] = s;
}

// ---------------------------------------------------------------- prep
// x fp32 -> bf16
__global__ void k_castx(const float4* __restrict__ x, ushort4* __restrict__ xb, int n4) {
    int i = blockIdx.x * blockDim.x + threadIdx.x;
    if (i >= n4) return;
    float4 v = x[i];
    ushort4 o;
    o.x = f2bf(v.x); o.y = f2bf(v.y); o.z = f2bf(v.z); o.w = f2bf(v.w);
    xb[i] = o;
}

// W (K x N fp32 row-major) -> Bt (N x 2K bf16): cols [0,K)=high, [K,2K)=low split
__global__ void k_prep(const float* __restrict__ W, ushort_t* __restrict__ Bt,
                       int K, int N) {
    int i = blockIdx.x * blockDim.x + threadIdx.x;
    if (i >= K * N) return;
    int k = i / N, n = i % N;
    float v = W[i];
    ushort_t h = f2bf(v);
    float r = v - bf2f(h);
    Bt[(size_t)n * 2 * K + k] = h;
    Bt[(size_t)n * 2 * K + K + k] = f2bf(r);
}

// ---------------------------------------------------------------- MFMA GEMM
// C[M x N](bf16) = A[M x K](bf16) @ (Bh + Bl)  with split-bf16 weights.
// BM=128, BN=64, BK=64, 256 thr (4 waves), mfma 16x16x32, wave = 32 rows x 64 cols.
// A frags staged per-wave (private mtiles), B frags shared; frag-ordered LDS:
// each 16(m/n) x 32(k) frag-block is 64 lanes x 16B contiguous (conflict-free b128).
template<bool ELU, bool BIAS>
__global__ __launch_bounds__(256) void gemm_mfma(const ushort_t* __restrict__ A,
                                                 const ushort_t* __restrict__ Bt,
                                                 const float* __restrict__ bias,
                                                 ushort_t* __restrict__ C,
                                                 int M, int K, int N) {
    __shared__ __align__(16) ushort_t lds[16384];  // [0,8192) A, [8192,16384) B
    int tid = threadIdx.x;
    int wave = tid >> 6, lane = tid & 63;
    int quad = lane >> 4, l16 = lane & 15;
    int mb = blockIdx.x * 128, nb = blockIdx.y * 64;
    int K2 = 2 * K;

    f32x4 acc[2][4];
    #pragma unroll
    for (int mt = 0; mt < 2; mt++)
        #pragma unroll
        for (int nt = 0; nt < 4; nt++)
            acc[mt][nt] = (f32x4){0.f, 0.f, 0.f, 0.f};

    for (int k0 = 0; k0 < K; k0 += 64) {
        // ---- stage A: wave w fills frag-blocks for its own mtiles {2w, 2w+1} ----
        #pragma unroll
        for (int c = 0; c < 4; c++) {
            int mt = wave * 2 + (c >> 1);          // global mtile 0..7
            int ks = c & 1;
            int row = mb + mt * 16 + l16;
            row = min(row, M - 1);                 // clamp; store is masked
            int col = k0 + ks * 32 + quad * 8;
            gl_lds16(A + (size_t)row * K + col, &lds[(mt * 2 + ks) * 512]);
        }
        // ---- stage B: 16 frag-blocks (2 splits x 4 ntiles x 2 ksteps) over 4 waves ----
        #pragma unroll
        for (int c = 0; c < 4; c++) {
            int id = wave * 4 + c;                 // 0..15
            int ntile = id & 3;
            int ks = (id >> 2) & 1;
            int split = id >> 3;
            int n = nb + ntile * 16 + l16;
            int col = split * K + k0 + ks * 32 + quad * 8;
            gl_lds16(Bt + (size_t)n * K2 + col,
                     &lds[8192 + ((split * 4 + ntile) * 2 + ks) * 512]);
        }
        __syncthreads();
        #pragma unroll
        for (int ks = 0; ks < 2; ks++) {
            short8 af[2];
            #pragma unroll
            for (int mt = 0; mt < 2; mt++)
                af[mt] = *(const short8*)&lds[((wave * 2 + mt) * 2 + ks) * 512 + lane * 8];
            short8 bh[4], bl[4];
            #pragma unroll
            for (int nt = 0; nt < 4; nt++) {
                bh[nt] = *(const short8*)&lds[8192 + (nt * 2 + ks) * 512 + lane * 8];
                bl[nt] = *(const short8*)&lds[8192 + ((4 + nt) * 2 + ks) * 512 + lane * 8];
            }
            #pragma unroll
            for (int mt = 0; mt < 2; mt++)
                #pragma unroll
                for (int nt = 0; nt < 4; nt++) {
                    acc[mt][nt] = __builtin_amdgcn_mfma_f32_16x16x32_bf16(
                        af[mt], bh[nt], acc[mt][nt], 0, 0, 0);
                    acc[mt][nt] = __builtin_amdgcn_mfma_f32_16x16x32_bf16(
                        af[mt], bl[nt], acc[mt][nt], 0, 0, 0);
                }
        }
        __syncthreads();
    }
    // ---- epilogue: C/D layout col=lane&15, row=quad*4+reg ----
    #pragma unroll
    for (int mt = 0; mt < 2; mt++) {
        int mrow = mb + (wave * 2 + mt) * 16 + quad * 4;
        #pragma unroll
        for (int nt = 0; nt < 4; nt++) {
            int n = nb + nt * 16 + l16;
            #pragma unroll
            for (int r = 0; r < 4; r++) {
                int m = mrow + r;
                if (m < M) {
                    float v = acc[mt][nt][r];
                    if (BIAS) v += bias[n];
                    if (ELU) v = elu1(v);
                    C[(size_t)m * N + n] = f2bf(v);
                }
            }
        }
    }
}

// ------------------------------------------------- per-node attention logits
template<int HEADS>
__global__ __launch_bounds__(256) void k_edot(const ushort_t* __restrict__ xl,
                                              const float* __restrict__ a_s,
                                              const float* __restrict__ a_d,
                                              float* __restrict__ es,
                                              float* __restrict__ ed) {
    constexpr int NPB = 4 / HEADS;   // nodes per 256-thread block
    int lane = threadIdx.x & 63, wave = threadIdx.x >> 6;
    int node = blockIdx.x * NPB + wave / HEADS;
    int head = wave % HEADS;
    if (node >= NN) return;
    float v = bf2f(xl[(size_t)node * (HEADS * 64) + head * 64 + lane]);
    float ps = v * a_s[head * 64 + lane];
    float pd = v * a_d[head * 64 + lane];
    #pragma unroll
    for (int o = 32; o >= 1; o >>= 1) {
        ps += __shfl_down(ps, o, 64);
        pd += __shfl_down(pd, o, 64);
    }
    if (lane == 0) {
        es[node * HEADS + head] = ps;
        ed[node * HEADS + head] = pd;
    }
}

// ------------------------------------------------- two-pass softmax aggregate
template<int HEADS, bool BFOUT>
__global__ __launch_bounds__(256) void k_agg(const ushort_t* __restrict__ xl,
                                             const float* __restrict__ es,
                                             const float* __restrict__ ed,
                                             const int* __restrict__ row_ptr,
                                             const int* __restrict__ csr,
                                             const float* __restrict__ bias,
                                             void* __restrict__ outv) {
    constexpr int ROW = HEADS * 64;
    constexpr int VEC = ROW / 64;    // 4 for HEADS=4, 1 for HEADS=1
    __shared__ float wlds[4][64 * HEADS];
    int lane = threadIdx.x & 63, wave = threadIdx.x >> 6;
    int node = blockIdx.x * 4 + wave;
    if (node >= NN) return;
    int head = (lane * VEC) >> 6;    // 0 when HEADS==1
    int start = row_ptr[node], end = row_ptr[node + 1];   // deg >= 1 (self-loop)

    float edh[HEADS];
    #pragma unroll
    for (int h = 0; h < HEADS; h++) edh[h] = ed[node * HEADS + h];

    // ---- pass 1: global max + sum per head ----
    float m[HEADS], ssum[HEADS];
    #pragma unroll
    for (int h = 0; h < HEADS; h++) { m[h] = -1e30f; ssum[h] = 0.f; }
    for (int base = start; base < end; base += 64) {
        int i = base + lane;
        bool valid = i < end;
        int idx = csr[valid ? i : start];
        float e[HEADS];
        if constexpr (HEADS == 4) {
            float4 ev = *(const float4*)(es + (size_t)idx * 4);
            e[0] = ev.x; e[1] = ev.y; e[2] = ev.z; e[3] = ev.w;
        } else {
            e[0] = es[idx];
        }
        #pragma unroll
        for (int h = 0; h < HEADS; h++) {
            float v = e[h] + edh[h];
            v = v > 0.f ? v : 0.2f * v;            // leaky_relu(0.2)
            e[h] = valid ? v : -1e30f;
        }
        float cm[HEADS];
        #pragma unroll
        for (int h = 0; h < HEADS; h++) cm[h] = e[h];
        #pragma unroll
        for (int o = 32; o >= 1; o >>= 1) {
            #pragma unroll
            for (int h = 0; h < HEADS; h++) cm[h] = fmaxf(cm[h], __shfl_xor(cm[h], o, 64));
        }
        float cs[HEADS];
        #pragma unroll
        for (int h = 0; h < HEADS; h++) cs[h] = valid ? __expf(e[h] - cm[h]) : 0.f;
        #pragma unroll
        for (int o = 32; o >= 1; o >>= 1) {
            #pragma unroll
            for (int h = 0; h < HEADS; h++) cs[h] += __shfl_xor(cs[h], o, 64);
        }
        #pragma unroll
        for (int h = 0; h < HEADS; h++) {
            float mn = fmaxf(m[h], cm[h]);
            ssum[h] = ssum[h] * __expf(m[h] - mn) + cs[h] * __expf(cm[h] - mn);
            m[h] = mn;
        }
    }
    float inv[HEADS];
    #pragma unroll
    for (int h = 0; h < HEADS; h++) inv[h] = 1.f / ssum[h];

    // ---- pass 2: alpha -> LDS, gather-accumulate ----
    float a[VEC];
    #pragma unroll
    for (int v = 0; v < VEC; v++) a[v] = 0.f;

    for (int base = start; base < end; base += 64) {
        int i = base + lane;
        bool valid = i < end;
        int idx = csr[valid ? i : start];
        int cnt = min(64, end - base);
        float e[HEADS];
        if constexpr (HEADS == 4) {
            float4 ev = *(const float4*)(es + (size_t)idx * 4);
            e[0] = ev.x; e[1] = ev.y; e[2] = ev.z; e[3] = ev.w;
        } else {
            e[0] = es[idx];
        }
        #pragma unroll
        for (int h = 0; h < HEADS; h++) {
            float v = e[h] + edh[h];
            v = v > 0.f ? v : 0.2f * v;
            e[h] = valid ? __expf(v - m[h]) * inv[h] : 0.f;
        }
        if constexpr (HEADS == 4) {
            float4 wv; wv.x = e[0]; wv.y = e[1]; wv.z = e[2]; wv.w = e[3];
            *(float4*)&wlds[wave][lane * 4] = wv;
        } else {
            wlds[wave][lane] = e[0];
        }
        for (int t = 0; t < cnt; ++t) {
            int s = __shfl(idx, t, 64);
            float w = wlds[wave][t * HEADS + head];
            if constexpr (VEC == 4) {
                ushort4 u = *(const ushort4*)(xl + (size_t)s * ROW + lane * 4);
                a[0] += w * bf2f(u.x);
                a[1] += w * bf2f(u.y);
                a[2] += w * bf2f(u.z);
                a[3] += w * bf2f(u.w);
            } else {
                a[0] += w * bf2f(xl[(size_t)s * ROW + lane]);
            }
        }
    }

    if constexpr (VEC == 4) {
        float o0 = elu1(a[0] + bias[lane * 4 + 0]);
        float o1 = elu1(a[1] + bias[lane * 4 + 1]);
        float o2 = elu1(a[2] + bias[lane * 4 + 2]);
        float o3 = elu1(a[3] + bias[lane * 4 + 3]);
        if constexpr (BFOUT) {
            ushort4 o; o.x = f2bf(o0); o.y = f2bf(o1); o.z = f2bf(o2); o.w = f2bf(o3);
            *(ushort4*)((ushort_t*)outv + (size_t)node * ROW + lane * 4) = o;
        } else {
            float4 o; o.x = o0; o.y = o1; o.z = o2; o.w = o3;
            *(float4*)((float*)outv + (size_t)node * ROW + lane * 4) = o;
        }
    } else {
        float o0 = elu1(a[0] + bias[lane]);
        if constexpr (BFOUT)
            ((ushort_t*)outv)[(size_t)node * ROW + lane] = f2bf(o0);
        else
            ((float*)outv)[(size_t)node * ROW + lane] = o0;
    }
}

// ---------------------------------------------------------------- pooling
__global__ void k_pool(const float* __restrict__ fnl, float* __restrict__ gsum) {
    __shared__ float sm[4][64];
    int t = threadIdx.x, c = t & 63, w = t >> 6;
    float s = 0.f;
    for (int r = blockIdx.x * 4 + w; r < NN; r += gridDim.x * 4)
        s += fnl[(size_t)r * 64 + c];
    sm[w][c] = s;
    __syncthreads();
    if (w == 0) {
        float tot = sm[0][c] + sm[1][c] + sm[2][c] + sm[3][c];
        atomicAdd(&gsum[c], tot);
    }
}

__global__ void k_final(const float* __restrict__ gsum, const float* __restrict__ w_out,
                        const float* __restrict__ b_out, float* __restrict__ out) {
    int j = threadIdx.x;   // 128
    float s = b_out[j];
    const float invn = 1.f / (float)NN;
    #pragma unroll 8
    for (int k = 0; k < 64; k++)
        s += (gsum[k] * invn) * w_out[k * 128 + j];
    out[j] = s;
}

// ---------------------------------------------------------------- launcher
extern "C" void kernel_launch(void* const* d_in, const int* in_sizes, int n_in,
                              void* d_out, int out_size, void* d_ws, size_t ws_size,
                              hipStream_t stream) {
    const float* x    = (const float*)d_in[0];
    const int*   ei   = (const int*)d_in[1];
    const float* w_in = (const float*)d_in[2];
    const float* b_in = (const float*)d_in[3];
    const float* W0   = (const float*)d_in[4];
    const float* as0  = (const float*)d_in[5];
    const float* ad0  = (const float*)d_in[6];
    const float* bb0  = (const float*)d_in[7];
    const float* W1   = (const float*)d_in[8];
    const float* as1  = (const float*)d_in[9];
    const float* ad1  = (const float*)d_in[10];
    const float* bb1  = (const float*)d_in[11];
    const float* W2   = (const float*)d_in[12];
    const float* as2  = (const float*)d_in[13];
    const float* ad2  = (const float*)d_in[14];
    const float* bb2  = (const float*)d_in[15];
    const float* w_out= (const float*)d_in[16];
    const float* b_out= (const float*)d_in[17];
    float* out = (float*)d_out;

    char* p = (char*)d_ws;
    size_t off = 0;
    auto take = [&](size_t bytes) {
        char* r = p + off;
        off = (off + bytes + 255) & ~(size_t)255;
        return r;
    };
    ushort_t* xb     = (ushort_t*)take((size_t)NN * 256 * 2); // 25.6 MB
    ushort_t* h0b    = (ushort_t*)take((size_t)NN * 64 * 2);  //  6.4 MB
    ushort_t* xl_bf  = (ushort_t*)take((size_t)NN * 256 * 2); // 25.6 MB
    ushort_t* hb_bf  = (ushort_t*)take((size_t)NN * 256 * 2); // 25.6 MB
    ushort_t* h2_bf  = (ushort_t*)take((size_t)NN * 64 * 2);  //  6.4 MB
    float*    fnl    = (float*)take((size_t)NN * 64 * 4);     // 12.8 MB
    ushort_t* wiT    = (ushort_t*)take((size_t)64 * 512 * 2);
    ushort_t* w0T    = (ushort_t*)take((size_t)256 * 128 * 2);
    ushort_t* w1T    = (ushort_t*)take((size_t)256 * 512 * 2);
    ushort_t* w2T    = (ushort_t*)take((size_t)64 * 512 * 2);
    float*    es     = (float*)take((size_t)NN * 4 * 4);
    float*    ed     = (float*)take((size_t)NN * 4 * 4);
    int*      row_ptr= (int*)take((size_t)(NN + 1) * 4);
    int*      cursor = (int*)take((size_t)NN * 4);
    int*      csr    = (int*)take((size_t)ET * 4);
    float*    gsum   = (float*)take(64 * 4);

    // ---- CSR build (by dst, with self-loops) ----
    k_init   <<<(NN + 255) / 256, 256, 0, stream>>>(cursor, gsum);
    k_hist   <<<(NE + 255) / 256, 256, 0, stream>>>(ei + NE, cursor);
    k_scan   <<<1, 1024, 0, stream>>>(cursor, row_ptr);
    k_scatter<<<(ET + 255) / 256, 256, 0, stream>>>(ei, cursor, csr);

    // ---- prep: cast x to bf16; split-transpose weights ----
    k_castx<<<(NN * 64 + 255) / 256, 256, 0, stream>>>((const float4*)x, (ushort4*)xb, NN * 64);
    k_prep <<<(256 * 64 + 255) / 256, 256, 0, stream>>>(w_in, wiT, 256, 64);
    k_prep <<<(64 * 256 + 255) / 256, 256, 0, stream>>>(W0, w0T, 64, 256);
    k_prep <<<(256 * 256 + 255) / 256, 256, 0, stream>>>(W1, w1T, 256, 256);
    k_prep <<<(256 * 64 + 255) / 256, 256, 0, stream>>>(W2, w2T, 256, 64);

    const int GM = (NN + 127) / 128;   // 391

    // ---- input projection: h0 = elu(x @ w_in + b_in) ----
    gemm_mfma<true, true><<<dim3(GM, 1), 256, 0, stream>>>(xb, wiT, b_in, h0b, NN, 256, 64);

    // ---- GAT layer 0 (heads=4, concat) ----
    gemm_mfma<false, false><<<dim3(GM, 4), 256, 0, stream>>>(h0b, w0T, nullptr, xl_bf, NN, 64, 256);
    k_edot<4><<<NN, 256, 0, stream>>>(xl_bf, as0, ad0, es, ed);
    k_agg<4, true><<<(NN + 3) / 4, 256, 0, stream>>>(xl_bf, es, ed, row_ptr, csr, bb0, hb_bf);

    // ---- GAT layer 1 (heads=4, concat) ----
    gemm_mfma<false, false><<<dim3(GM, 4), 256, 0, stream>>>(hb_bf, w1T, nullptr, xl_bf, NN, 256, 256);
    k_edot<4><<<NN, 256, 0, stream>>>(xl_bf, as1, ad1, es, ed);
    k_agg<4, true><<<(NN + 3) / 4, 256, 0, stream>>>(xl_bf, es, ed, row_ptr, csr, bb1, hb_bf);

    // ---- GAT layer 2 (heads=1, mean==identity) ----
    gemm_mfma<false, false><<<dim3(GM, 1), 256, 0, stream>>>(hb_bf, w2T, nullptr, h2_bf, NN, 256, 64);
    k_edot<1><<<(NN + 3) / 4, 256, 0, stream>>>(h2_bf, as2, ad2, es, ed);
    k_agg<1, false><<<(NN + 3) / 4, 256, 0, stream>>>(h2_bf, es, ed, row_ptr, csr, bb2, fnl);

    // ---- global mean pool + output projection ----
    k_pool <<<128, 256, 0, stream>>>(fnl, gsum);
    k_final<<<1, 128, 0, stream>>>(gsum, w_out, b_out, out);
}

// Round 4
// 535.817 us; speedup vs baseline: 1.6495x; 1.2446x over previous
//
#include <hip/hip_runtime.h>

#define NN 50000
#define NE 800000
#define ET 850000   // NE + NN self-loops
#define NBLK 196    // ceil(NN/256) for the parallel scan

typedef unsigned short ushort_t;
typedef unsigned int uint_t;
typedef __attribute__((ext_vector_type(8))) short short8;
typedef __attribute__((ext_vector_type(4))) float f32x4;

// ---------------------------------------------------------------- utilities
__device__ __forceinline__ float elu1(float x) {
    return x > 0.f ? x : (__expf(x) - 1.f);
}
__device__ __forceinline__ float bf2f(ushort_t u) {
    return __uint_as_float(((uint_t)u) << 16);
}
__device__ __forceinline__ ushort_t f2bf(float f) {   // round-to-nearest-even
    uint_t u = __float_as_uint(f);
    u += 0x7FFFu + ((u >> 16) & 1u);
    return (ushort_t)(u >> 16);
}
__device__ __forceinline__ void gl_lds16(const ushort_t* g, ushort_t* l) {
    // async global->LDS, 16B/lane; LDS dest = wave-uniform base + lane*16
    __builtin_amdgcn_global_load_lds((const __attribute__((address_space(1))) void*)g,
                                     (__attribute__((address_space(3))) void*)l,
                                     16, 0, 0);
}

// ---------------------------------------------------------------- CSR build
__global__ void k_init(int* __restrict__ cursor, float* __restrict__ gsum) {
    int i = blockIdx.x * blockDim.x + threadIdx.x;
    if (i < NN) cursor[i] = 1;          // pre-count the self-loop of node i
    if (i < 64) gsum[i] = 0.f;
}

__global__ void k_hist(const int* __restrict__ dst, int* __restrict__ cursor) {
    int e = blockIdx.x * blockDim.x + threadIdx.x;
    if (e < NE) atomicAdd(&cursor[dst[e]], 1);
}

// parallel exclusive scan: scan1 (block-local) -> scan2 (block sums) -> scan3 (add)
__global__ void k_scan1(const int* __restrict__ cnt, int* __restrict__ excl,
                        int* __restrict__ bsum) {
    __shared__ int wsum[4];
    int t = threadIdx.x, lane = t & 63, w = t >> 6;
    int i = blockIdx.x * 256 + t;
    int v = (i < NN) ? cnt[i] : 0;
    int x = v;
    #pragma unroll
    for (int o = 1; o < 64; o <<= 1) {
        int y = __shfl_up(x, o, 64);
        if (lane >= o) x += y;
    }
    if (lane == 63) wsum[w] = x;
    __syncthreads();
    int wo = 0;
    #pragma unroll
    for (int k = 0; k < 4; k++) wo += (k < w) ? wsum[k] : 0;
    if (i < NN) excl[i] = x - v + wo;
    if (t == 255) bsum[blockIdx.x] = wo + x;     // block total
}

__global__ void k_scan2(int* __restrict__ bsum) {   // 1 block, 256 threads
    __shared__ int wsum[4];
    int t = threadIdx.x, lane = t & 63, w = t >> 6;
    int v = (t < NBLK) ? bsum[t] : 0;
    int x = v;
    #pragma unroll
    for (int o = 1; o < 64; o <<= 1) {
        int y = __shfl_up(x, o, 64);
        if (lane >= o) x += y;
    }
    if (lane == 63) wsum[w] = x;
    __syncthreads();
    int wo = 0;
    #pragma unroll
    for (int k = 0; k < 4; k++) wo += (k < w) ? wsum[k] : 0;
    if (t < NBLK) bsum[t] = x - v + wo;          // exclusive
}

__global__ void k_scan3(int* __restrict__ row_ptr, const int* __restrict__ bsum,
                        int* __restrict__ cursor) {
    int i = blockIdx.x * 256 + threadIdx.x;
    if (i < NN) {
        int r = row_ptr[i] + bsum[blockIdx.x];
        row_ptr[i] = r;
        cursor[i] = r;
    }
    if (i == 0) row_ptr[NN] = ET;
}

__global__ void k_scatter(const int* __restrict__ ei, int* __restrict__ cursor,
                          int* __restrict__ csr) {
    int e = blockIdx.x * blockDim.x + threadIdx.x;
    if (e >= ET) return;
    int s, d;
    if (e < NE) { s = ei[e]; d = ei[NE + e]; }
    else        { s = d = e - NE; }
    int pos = atomicAdd(&cursor[d], 1);
    csr[pos] = s;
}

// ---------------------------------------------------------------- prep
__global__ void k_castx(const float4* __restrict__ x, ushort4* __restrict__ xb, int n4) {
    int i = blockIdx.x * blockDim.x + threadIdx.x;
    if (i >= n4) return;
    float4 v = x[i];
    ushort4 o;
    o.x = f2bf(v.x); o.y = f2bf(v.y); o.z = f2bf(v.z); o.w = f2bf(v.w);
    xb[i] = o;
}

// W (K x N fp32 row-major) -> Bt (N x 2K bf16): cols [0,K)=high, [K,2K)=low split
__global__ void k_prep(const float* __restrict__ W, ushort_t* __restrict__ Bt,
                       int K, int N) {
    int i = blockIdx.x * blockDim.x + threadIdx.x;
    if (i >= K * N) return;
    int k = i / N, n = i % N;
    float v = W[i];
    ushort_t h = f2bf(v);
    float r = v - bf2f(h);
    Bt[(size_t)n * 2 * K + k] = h;
    Bt[(size_t)n * 2 * K + K + k] = f2bf(r);
}

// ---------------------------------------------------------------- MFMA GEMM
// C[M x N](bf16) = A[M x K](bf16) @ (Bh + Bl), split-bf16 weights.
// BM=128, BN=64, BK=64, 256 thr (4 waves), mfma 16x16x32.
// EDOT: blockIdx.y covers exactly one head (64 cols); epilogue computes
// es/ed = C . a_s/.a_d via per-quad 16-lane butterfly (replaces k_edot).
template<bool ELU, bool BIAS, bool EDOT>
__global__ __launch_bounds__(256) void gemm_mfma(const ushort_t* __restrict__ A,
                                                 const ushort_t* __restrict__ Bt,
                                                 const float* __restrict__ bias,
                                                 ushort_t* __restrict__ C,
                                                 const float* __restrict__ a_s,
                                                 const float* __restrict__ a_d,
                                                 float* __restrict__ es,
                                                 float* __restrict__ ed,
                                                 int esStride,
                                                 int M, int K, int N) {
    __shared__ __align__(16) ushort_t lds[16384];  // [0,8192) A, [8192,16384) B
    int tid = threadIdx.x;
    int wave = tid >> 6, lane = tid & 63;
    int quad = lane >> 4, l16 = lane & 15;
    int mb = blockIdx.x * 128, nb = blockIdx.y * 64;
    int K2 = 2 * K;

    f32x4 acc[2][4];
    #pragma unroll
    for (int mt = 0; mt < 2; mt++)
        #pragma unroll
        for (int nt = 0; nt < 4; nt++)
            acc[mt][nt] = (f32x4){0.f, 0.f, 0.f, 0.f};

    for (int k0 = 0; k0 < K; k0 += 64) {
        #pragma unroll
        for (int c = 0; c < 4; c++) {
            int mt = wave * 2 + (c >> 1);
            int ks = c & 1;
            int row = mb + mt * 16 + l16;
            row = min(row, M - 1);
            int col = k0 + ks * 32 + quad * 8;
            gl_lds16(A + (size_t)row * K + col, &lds[(mt * 2 + ks) * 512]);
        }
        #pragma unroll
        for (int c = 0; c < 4; c++) {
            int id = wave * 4 + c;
            int ntile = id & 3;
            int ks = (id >> 2) & 1;
            int split = id >> 3;
            int n = nb + ntile * 16 + l16;
            int col = split * K + k0 + ks * 32 + quad * 8;
            gl_lds16(Bt + (size_t)n * K2 + col,
                     &lds[8192 + ((split * 4 + ntile) * 2 + ks) * 512]);
        }
        __syncthreads();
        #pragma unroll
        for (int ks = 0; ks < 2; ks++) {
            short8 af[2];
            #pragma unroll
            for (int mt = 0; mt < 2; mt++)
                af[mt] = *(const short8*)&lds[((wave * 2 + mt) * 2 + ks) * 512 + lane * 8];
            short8 bh[4], bl[4];
            #pragma unroll
            for (int nt = 0; nt < 4; nt++) {
                bh[nt] = *(const short8*)&lds[8192 + (nt * 2 + ks) * 512 + lane * 8];
                bl[nt] = *(const short8*)&lds[8192 + ((4 + nt) * 2 + ks) * 512 + lane * 8];
            }
            #pragma unroll
            for (int mt = 0; mt < 2; mt++)
                #pragma unroll
                for (int nt = 0; nt < 4; nt++) {
                    acc[mt][nt] = __builtin_amdgcn_mfma_f32_16x16x32_bf16(
                        af[mt], bh[nt], acc[mt][nt], 0, 0, 0);
                    acc[mt][nt] = __builtin_amdgcn_mfma_f32_16x16x32_bf16(
                        af[mt], bl[nt], acc[mt][nt], 0, 0, 0);
                }
        }
        __syncthreads();
    }
    // ---- epilogue: C/D layout col=lane&15, row=quad*4+reg ----
    float asl[4], adl[4];
    if constexpr (EDOT) {
        #pragma unroll
        for (int nt = 0; nt < 4; nt++) {
            asl[nt] = a_s[nb + nt * 16 + l16];
            adl[nt] = a_d[nb + nt * 16 + l16];
        }
    }
    int head = blockIdx.y;
    #pragma unroll
    for (int mt = 0; mt < 2; mt++) {
        int mrow = mb + (wave * 2 + mt) * 16 + quad * 4;
        #pragma unroll
        for (int r = 0; r < 4; r++) {
            int m = mrow + r;
            if constexpr (EDOT) {
                float ps = 0.f, pd = 0.f;
                #pragma unroll
                for (int nt = 0; nt < 4; nt++) {
                    float v = acc[mt][nt][r];
                    ps += v * asl[nt];
                    pd += v * adl[nt];
                }
                #pragma unroll
                for (int o = 8; o >= 1; o >>= 1) {
                    ps += __shfl_xor(ps, o, 64);
                    pd += __shfl_xor(pd, o, 64);
                }
                if (l16 == 0 && m < M) {
                    es[(size_t)m * esStride + head] = ps;
                    ed[(size_t)m * esStride + head] = pd;
                }
            }
            if (m < M) {
                #pragma unroll
                for (int nt = 0; nt < 4; nt++) {
                    int n = nb + nt * 16 + l16;
                    float v = acc[mt][nt][r];
                    if (BIAS) v += bias[n];
                    if (ELU) v = elu1(v);
                    C[(size_t)m * N + n] = f2bf(v);
                }
            }
        }
    }
}

// ------------------------------------------------- softmax aggregate, 4 heads
// 1 wave per node. Fast path (deg<=64, always true at Poisson(16)+1): single
// chunk keeps leaky logits in registers across softmax-stat and weight steps.
// Gather loop manually unrolled x4 for memory-level parallelism.
template<bool BFOUT>
__global__ __launch_bounds__(256) void k_agg4(const ushort_t* __restrict__ xl,
                                              const float* __restrict__ es,
                                              const float* __restrict__ ed,
                                              const int* __restrict__ row_ptr,
                                              const int* __restrict__ csr,
                                              const float* __restrict__ bias,
                                              void* __restrict__ outv) {
    __shared__ float wlds[4][256];
    int lane = threadIdx.x & 63, wave = threadIdx.x >> 6;
    int node = blockIdx.x * 4 + wave;
    if (node >= NN) return;
    int head = lane >> 4;
    int start = row_ptr[node], end = row_ptr[node + 1];
    int deg = end - start;
    float4 edv = *(const float4*)(ed + (size_t)node * 4);
    float edh[4] = {edv.x, edv.y, edv.z, edv.w};
    float a0 = 0.f, a1 = 0.f, a2 = 0.f, a3 = 0.f;

    if (deg <= 64) {
        // ---- fused single-chunk softmax ----
        int i = start + lane;
        bool valid = i < end;
        int idx = csr[valid ? i : start];
        float4 ev = *(const float4*)(es + (size_t)idx * 4);
        float e[4] = {ev.x, ev.y, ev.z, ev.w};
        #pragma unroll
        for (int h = 0; h < 4; h++) {
            float v = e[h] + edh[h];
            v = v > 0.f ? v : 0.2f * v;
            e[h] = valid ? v : -1e30f;
        }
        float cm[4];
        #pragma unroll
        for (int h = 0; h < 4; h++) cm[h] = e[h];
        #pragma unroll
        for (int o = 32; o >= 1; o >>= 1)
            #pragma unroll
            for (int h = 0; h < 4; h++) cm[h] = fmaxf(cm[h], __shfl_xor(cm[h], o, 64));
        float cs[4];
        #pragma unroll
        for (int h = 0; h < 4; h++) cs[h] = valid ? __expf(e[h] - cm[h]) : 0.f;
        #pragma unroll
        for (int o = 32; o >= 1; o >>= 1)
            #pragma unroll
            for (int h = 0; h < 4; h++) cs[h] += __shfl_xor(cs[h], o, 64);
        float4 wv;
        wv.x = valid ? __expf(e[0] - cm[0]) / cs[0] : 0.f;
        wv.y = valid ? __expf(e[1] - cm[1]) / cs[1] : 0.f;
        wv.z = valid ? __expf(e[2] - cm[2]) / cs[2] : 0.f;
        wv.w = valid ? __expf(e[3] - cm[3]) / cs[3] : 0.f;
        *(float4*)&wlds[wave][lane * 4] = wv;
        // ---- gather, unrolled x4 ----
        int t = 0;
        for (; t + 4 <= deg; t += 4) {
            int s0 = __shfl(idx, t + 0, 64);
            int s1 = __shfl(idx, t + 1, 64);
            int s2 = __shfl(idx, t + 2, 64);
            int s3 = __shfl(idx, t + 3, 64);
            float w0 = wlds[wave][(t + 0) * 4 + head];
            float w1 = wlds[wave][(t + 1) * 4 + head];
            float w2 = wlds[wave][(t + 2) * 4 + head];
            float w3 = wlds[wave][(t + 3) * 4 + head];
            ushort4 u0 = *(const ushort4*)(xl + (size_t)s0 * 256 + lane * 4);
            ushort4 u1 = *(const ushort4*)(xl + (size_t)s1 * 256 + lane * 4);
            ushort4 u2 = *(const ushort4*)(xl + (size_t)s2 * 256 + lane * 4);
            ushort4 u3 = *(const ushort4*)(xl + (size_t)s3 * 256 + lane * 4);
            a0 += w0 * bf2f(u0.x); a1 += w0 * bf2f(u0.y); a2 += w0 * bf2f(u0.z); a3 += w0 * bf2f(u0.w);
            a0 += w1 * bf2f(u1.x); a1 += w1 * bf2f(u1.y); a2 += w1 * bf2f(u1.z); a3 += w1 * bf2f(u1.w);
            a0 += w2 * bf2f(u2.x); a1 += w2 * bf2f(u2.y); a2 += w2 * bf2f(u2.z); a3 += w2 * bf2f(u2.w);
            a0 += w3 * bf2f(u3.x); a1 += w3 * bf2f(u3.y); a2 += w3 * bf2f(u3.z); a3 += w3 * bf2f(u3.w);
        }
        for (; t < deg; ++t) {
            int s = __shfl(idx, t, 64);
            float w = wlds[wave][t * 4 + head];
            ushort4 u = *(const ushort4*)(xl + (size_t)s * 256 + lane * 4);
            a0 += w * bf2f(u.x); a1 += w * bf2f(u.y); a2 += w * bf2f(u.z); a3 += w * bf2f(u.w);
        }
    } else {
        // ---- general two-pass path (deg > 64, essentially never) ----
        float m[4], ssum[4];
        #pragma unroll
        for (int h = 0; h < 4; h++) { m[h] = -1e30f; ssum[h] = 0.f; }
        for (int base = start; base < end; base += 64) {
            int i = base + lane;
            bool valid = i < end;
            int idx = csr[valid ? i : start];
            float4 ev = *(const float4*)(es + (size_t)idx * 4);
            float e[4] = {ev.x, ev.y, ev.z, ev.w};
            #pragma unroll
            for (int h = 0; h < 4; h++) {
                float v = e[h] + edh[h];
                v = v > 0.f ? v : 0.2f * v;
                e[h] = valid ? v : -1e30f;
            }
            float cm[4];
            #pragma unroll
            for (int h = 0; h < 4; h++) cm[h] = e[h];
            #pragma unroll
            for (int o = 32; o >= 1; o >>= 1)
                #pragma unroll
                for (int h = 0; h < 4; h++) cm[h] = fmaxf(cm[h], __shfl_xor(cm[h], o, 64));
            float cs[4];
            #pragma unroll
            for (int h = 0; h < 4; h++) cs[h] = valid ? __expf(e[h] - cm[h]) : 0.f;
            #pragma unroll
            for (int o = 32; o >= 1; o >>= 1)
                #pragma unroll
                for (int h = 0; h < 4; h++) cs[h] += __shfl_xor(cs[h], o, 64);
            #pragma unroll
            for (int h = 0; h < 4; h++) {
                float mn = fmaxf(m[h], cm[h]);
                ssum[h] = ssum[h] * __expf(m[h] - mn) + cs[h] * __expf(cm[h] - mn);
                m[h] = mn;
            }
        }
        float inv[4];
        #pragma unroll
        for (int h = 0; h < 4; h++) inv[h] = 1.f / ssum[h];
        for (int base = start; base < end; base += 64) {
            int i = base + lane;
            bool valid = i < end;
            int idx = csr[valid ? i : start];
            int cnt = min(64, end - base);
            float4 ev = *(const float4*)(es + (size_t)idx * 4);
            float e[4] = {ev.x, ev.y, ev.z, ev.w};
            #pragma unroll
            for (int h = 0; h < 4; h++) {
                float v = e[h] + edh[h];
                v = v > 0.f ? v : 0.2f * v;
                e[h] = valid ? __expf(v - m[h]) * inv[h] : 0.f;
            }
            float4 wv; wv.x = e[0]; wv.y = e[1]; wv.z = e[2]; wv.w = e[3];
            *(float4*)&wlds[wave][lane * 4] = wv;
            for (int t = 0; t < cnt; ++t) {
                int s = __shfl(idx, t, 64);
                float w = wlds[wave][t * 4 + head];
                ushort4 u = *(const ushort4*)(xl + (size_t)s * 256 + lane * 4);
                a0 += w * bf2f(u.x); a1 += w * bf2f(u.y); a2 += w * bf2f(u.z); a3 += w * bf2f(u.w);
            }
        }
    }

    float o0 = elu1(a0 + bias[lane * 4 + 0]);
    float o1 = elu1(a1 + bias[lane * 4 + 1]);
    float o2 = elu1(a2 + bias[lane * 4 + 2]);
    float o3 = elu1(a3 + bias[lane * 4 + 3]);
    if constexpr (BFOUT) {
        ushort4 o; o.x = f2bf(o0); o.y = f2bf(o1); o.z = f2bf(o2); o.w = f2bf(o3);
        *(ushort4*)((ushort_t*)outv + (size_t)node * 256 + lane * 4) = o;
    } else {
        float4 o; o.x = o0; o.y = o1; o.z = o2; o.w = o3;
        *(float4*)((float*)outv + (size_t)node * 256 + lane * 4) = o;
    }
}

// ------------------------------------------------- softmax aggregate, 1 head
// 4 nodes per wave (16-lane groups, ushort4 = 4 dims/lane); mean-pool fused:
// block-reduces elu outputs and issues 64 atomicAdds into gsum.
__global__ __launch_bounds__(256) void k_agg1(const ushort_t* __restrict__ xl,
                                              const float* __restrict__ es,
                                              const float* __restrict__ ed,
                                              const int* __restrict__ row_ptr,
                                              const int* __restrict__ csr,
                                              const float* __restrict__ bias,
                                              float* __restrict__ gsum) {
    __shared__ float wlds[4][64];
    __shared__ float ps[4][64];
    int lane = threadIdx.x & 63, wave = threadIdx.x >> 6;
    int g = lane >> 4, l16 = lane & 15;
    int node = blockIdx.x * 16 + wave * 4 + g;
    bool vn = node < NN;
    int start = vn ? row_ptr[node] : 0;
    int end   = vn ? row_ptr[node + 1] : 0;
    float edl = vn ? ed[node] : 0.f;

    // ---- pass 1: softmax stats, 16 edges/chunk per group ----
    float m = -1e30f, ssum = 0.f;
    for (int base = start; base < end; base += 16) {
        int i = base + l16;
        bool valid = i < end;
        int idx = csr[valid ? i : start];
        float e = es[idx] + edl;
        e = e > 0.f ? e : 0.2f * e;
        e = valid ? e : -1e30f;
        float cm = e;
        #pragma unroll
        for (int o = 8; o >= 1; o >>= 1) cm = fmaxf(cm, __shfl_xor(cm, o, 64));
        float cs = valid ? __expf(e - cm) : 0.f;
        #pragma unroll
        for (int o = 8; o >= 1; o >>= 1) cs += __shfl_xor(cs, o, 64);
        float mn = fmaxf(m, cm);
        ssum = ssum * __expf(m - mn) + cs * __expf(cm - mn);
        m = mn;
    }
    float inv = 1.f / ssum;

    // ---- pass 2: weights -> LDS, gather unrolled x4 ----
    float a[4] = {0.f, 0.f, 0.f, 0.f};
    for (int base = start; base < end; base += 16) {
        int i = base + l16;
        bool valid = i < end;
        int idx = csr[valid ? i : start];
        int cnt = min(16, end - base);
        float e = es[idx] + edl;
        e = e > 0.f ? e : 0.2f * e;
        wlds[wave][g * 16 + l16] = valid ? __expf(e - m) * inv : 0.f;
        int t = 0;
        for (; t + 4 <= cnt; t += 4) {
            int s0 = __shfl(idx, g * 16 + t + 0, 64);
            int s1 = __shfl(idx, g * 16 + t + 1, 64);
            int s2 = __shfl(idx, g * 16 + t + 2, 64);
            int s3 = __shfl(idx, g * 16 + t + 3, 64);
            float w0 = wlds[wave][g * 16 + t + 0];
            float w1 = wlds[wave][g * 16 + t + 1];
            float w2 = wlds[wave][g * 16 + t + 2];
            float w3 = wlds[wave][g * 16 + t + 3];
            ushort4 u0 = *(const ushort4*)(xl + (size_t)s0 * 64 + l16 * 4);
            ushort4 u1 = *(const ushort4*)(xl + (size_t)s1 * 64 + l16 * 4);
            ushort4 u2 = *(const ushort4*)(xl + (size_t)s2 * 64 + l16 * 4);
            ushort4 u3 = *(const ushort4*)(xl + (size_t)s3 * 64 + l16 * 4);
            a[0] += w0 * bf2f(u0.x); a[1] += w0 * bf2f(u0.y); a[2] += w0 * bf2f(u0.z); a[3] += w0 * bf2f(u0.w);
            a[0] += w1 * bf2f(u1.x); a[1] += w1 * bf2f(u1.y); a[2] += w1 * bf2f(u1.z); a[3] += w1 * bf2f(u1.w);
            a[0] += w2 * bf2f(u2.x); a[1] += w2 * bf2f(u2.y); a[2] += w2 * bf2f(u2.z); a[3] += w2 * bf2f(u2.w);
            a[0] += w3 * bf2f(u3.x); a[1] += w3 * bf2f(u3.y); a[2] += w3 * bf2f(u3.z); a[3] += w3 * bf2f(u3.w);
        }
        for (; t < cnt; ++t) {
            int s = __shfl(idx, g * 16 + t, 64);
            float w = wlds[wave][g * 16 + t];
            ushort4 u = *(const ushort4*)(xl + (size_t)s * 64 + l16 * 4);
            a[0] += w * bf2f(u.x); a[1] += w * bf2f(u.y); a[2] += w * bf2f(u.z); a[3] += w * bf2f(u.w);
        }
    }

    // ---- fused mean-pool ----
    float o[4];
    #pragma unroll
    for (int j = 0; j < 4; j++)
        o[j] = vn ? elu1(a[j] + bias[l16 * 4 + j]) : 0.f;
    #pragma unroll
    for (int j = 0; j < 4; j++) {
        o[j] += __shfl_xor(o[j], 16, 64);
        o[j] += __shfl_xor(o[j], 32, 64);
    }
    if (lane < 16) {
        float4 v; v.x = o[0]; v.y = o[1]; v.z = o[2]; v.w = o[3];
        *(float4*)&ps[wave][l16 * 4] = v;
    }
    __syncthreads();
    int tid = threadIdx.x;
    if (tid < 64) {
        float tot = ps[0][tid] + ps[1][tid] + ps[2][tid] + ps[3][tid];
        atomicAdd(&gsum[tid], tot);
    }
}

// ---------------------------------------------------------------- final
__global__ void k_final(const float* __restrict__ gsum, const float* __restrict__ w_out,
                        const float* __restrict__ b_out, float* __restrict__ out) {
    int j = threadIdx.x;   // 128
    float s = b_out[j];
    const float invn = 1.f / (float)NN;
    #pragma unroll 8
    for (int k = 0; k < 64; k++)
        s += (gsum[k] * invn) * w_out[k * 128 + j];
    out[j] = s;
}

// ---------------------------------------------------------------- launcher
extern "C" void kernel_launch(void* const* d_in, const int* in_sizes, int n_in,
                              void* d_out, int out_size, void* d_ws, size_t ws_size,
                              hipStream_t stream) {
    const float* x    = (const float*)d_in[0];
    const int*   ei   = (const int*)d_in[1];
    const float* w_in = (const float*)d_in[2];
    const float* b_in = (const float*)d_in[3];
    const float* W0   = (const float*)d_in[4];
    const float* as0  = (const float*)d_in[5];
    const float* ad0  = (const float*)d_in[6];
    const float* bb0  = (const float*)d_in[7];
    const float* W1   = (const float*)d_in[8];
    const float* as1  = (const float*)d_in[9];
    const float* ad1  = (const float*)d_in[10];
    const float* bb1  = (const float*)d_in[11];
    const float* W2   = (const float*)d_in[12];
    const float* as2  = (const float*)d_in[13];
    const float* ad2  = (const float*)d_in[14];
    const float* bb2  = (const float*)d_in[15];
    const float* w_out= (const float*)d_in[16];
    const float* b_out= (const float*)d_in[17];
    float* out = (float*)d_out;

    char* p = (char*)d_ws;
    size_t off = 0;
    auto take = [&](size_t bytes) {
        char* r = p + off;
        off = (off + bytes + 255) & ~(size_t)255;
        return r;
    };
    ushort_t* xb     = (ushort_t*)take((size_t)NN * 256 * 2); // 25.6 MB
    ushort_t* h0b    = (ushort_t*)take((size_t)NN * 64 * 2);  //  6.4 MB
    ushort_t* xl_bf  = (ushort_t*)take((size_t)NN * 256 * 2); // 25.6 MB
    ushort_t* hb_bf  = (ushort_t*)take((size_t)NN * 256 * 2); // 25.6 MB
    ushort_t* h2_bf  = (ushort_t*)take((size_t)NN * 64 * 2);  //  6.4 MB
    ushort_t* wiT    = (ushort_t*)take((size_t)64 * 512 * 2);
    ushort_t* w0T    = (ushort_t*)take((size_t)256 * 128 * 2);
    ushort_t* w1T    = (ushort_t*)take((size_t)256 * 512 * 2);
    ushort_t* w2T    = (ushort_t*)take((size_t)64 * 512 * 2);
    float*    es     = (float*)take((size_t)NN * 4 * 4);
    float*    ed     = (float*)take((size_t)NN * 4 * 4);
    int*      row_ptr= (int*)take((size_t)(NN + 1) * 4);
    int*      cursor = (int*)take((size_t)NN * 4);
    int*      csr    = (int*)take((size_t)ET * 4);
    int*      bsum   = (int*)take((size_t)NBLK * 4);
    float*    gsum   = (float*)take(64 * 4);

    // ---- CSR build (by dst, with self-loops) ----
    k_init   <<<(NN + 255) / 256, 256, 0, stream>>>(cursor, gsum);
    k_hist   <<<(NE + 255) / 256, 256, 0, stream>>>(ei + NE, cursor);
    k_scan1  <<<NBLK, 256, 0, stream>>>(cursor, row_ptr, bsum);
    k_scan2  <<<1, 256, 0, stream>>>(bsum);
    k_scan3  <<<NBLK, 256, 0, stream>>>(row_ptr, bsum, cursor);
    k_scatter<<<(ET + 255) / 256, 256, 0, stream>>>(ei, cursor, csr);

    // ---- prep: cast x to bf16; split-transpose weights ----
    k_castx<<<(NN * 64 + 255) / 256, 256, 0, stream>>>((const float4*)x, (ushort4*)xb, NN * 64);
    k_prep <<<(256 * 64 + 255) / 256, 256, 0, stream>>>(w_in, wiT, 256, 64);
    k_prep <<<(64 * 256 + 255) / 256, 256, 0, stream>>>(W0, w0T, 64, 256);
    k_prep <<<(256 * 256 + 255) / 256, 256, 0, stream>>>(W1, w1T, 256, 256);
    k_prep <<<(256 * 64 + 255) / 256, 256, 0, stream>>>(W2, w2T, 256, 64);

    const int GM = (NN + 127) / 128;   // 391

    // ---- input projection: h0 = elu(x @ w_in + b_in) ----
    gemm_mfma<true, true, false><<<dim3(GM, 1), 256, 0, stream>>>(
        xb, wiT, b_in, h0b, nullptr, nullptr, nullptr, nullptr, 0, NN, 256, 64);

    // ---- GAT layer 0 (heads=4, concat); es/ed fused in GEMM epilogue ----
    gemm_mfma<false, false, true><<<dim3(GM, 4), 256, 0, stream>>>(
        h0b, w0T, nullptr, xl_bf, as0, ad0, es, ed, 4, NN, 64, 256);
    k_agg4<true><<<(NN + 3) / 4, 256, 0, stream>>>(xl_bf, es, ed, row_ptr, csr, bb0, hb_bf);

    // ---- GAT layer 1 (heads=4, concat) ----
    gemm_mfma<false, false, true><<<dim3(GM, 4), 256, 0, stream>>>(
        hb_bf, w1T, nullptr, xl_bf, as1, ad1, es, ed, 4, NN, 256, 256);
    k_agg4<true><<<(NN + 3) / 4, 256, 0, stream>>>(xl_bf, es, ed, row_ptr, csr, bb1, hb_bf);

    // ---- GAT layer 2 (heads=1) + fused mean-pool ----
    gemm_mfma<false, false, true><<<dim3(GM, 1), 256, 0, stream>>>(
        hb_bf, w2T, nullptr, h2_bf, as2, ad2, es, ed, 1, NN, 256, 64);
    k_agg1<<<(NN + 15) / 16, 256, 0, stream>>>(h2_bf, es, ed, row_ptr, csr, bb2, gsum);

    // ---- output projection ----
    k_final<<<1, 128, 0, stream>>>(gsum, w_out, b_out, out);
}

// Round 5
// 476.418 us; speedup vs baseline: 1.8552x; 1.1247x over previous
//
#include <hip/hip_runtime.h>

#define NN 50000
#define NE 800000
#define ET 850000   // NE + NN self-loops
#define NBLK 196    // ceil(NN/256) for the parallel scan
#define NAGG1 3125  // k_agg1 grid (= NN/16), also rows of `part`

typedef unsigned short ushort_t;
typedef unsigned int uint_t;
typedef __attribute__((ext_vector_type(8))) short short8;
typedef __attribute__((ext_vector_type(4))) float f32x4;

// ---------------------------------------------------------------- utilities
__device__ __forceinline__ float elu1(float x) {
    return x > 0.f ? x : (__expf(x) - 1.f);
}
__device__ __forceinline__ float bf2f(ushort_t u) {
    return __uint_as_float(((uint_t)u) << 16);
}
__device__ __forceinline__ ushort_t f2bf(float f) {   // round-to-nearest-even
    uint_t u = __float_as_uint(f);
    u += 0x7FFFu + ((u >> 16) & 1u);
    return (ushort_t)(u >> 16);
}
__device__ __forceinline__ void gl_lds16(const ushort_t* g, ushort_t* l) {
    // async global->LDS, 16B/lane; LDS dest = wave-uniform base + lane*16
    __builtin_amdgcn_global_load_lds((const __attribute__((address_space(1))) void*)g,
                                     (__attribute__((address_space(3))) void*)l,
                                     16, 0, 0);
}

// ---------------------------------------------------------------- CSR build
__global__ void k_init(int* __restrict__ cursor, float* __restrict__ gsum) {
    int i = blockIdx.x * blockDim.x + threadIdx.x;
    if (i < NN) cursor[i] = 1;          // pre-count the self-loop of node i
    if (i < 64) gsum[i] = 0.f;
}

__global__ void k_hist(const int* __restrict__ dst, int* __restrict__ cursor) {
    int e = blockIdx.x * blockDim.x + threadIdx.x;
    if (e < NE) atomicAdd(&cursor[dst[e]], 1);
}

// parallel exclusive scan: scan1 (block-local) -> scan2 (block sums) -> scan3 (add)
__global__ void k_scan1(const int* __restrict__ cnt, int* __restrict__ excl,
                        int* __restrict__ bsum) {
    __shared__ int wsum[4];
    int t = threadIdx.x, lane = t & 63, w = t >> 6;
    int i = blockIdx.x * 256 + t;
    int v = (i < NN) ? cnt[i] : 0;
    int x = v;
    #pragma unroll
    for (int o = 1; o < 64; o <<= 1) {
        int y = __shfl_up(x, o, 64);
        if (lane >= o) x += y;
    }
    if (lane == 63) wsum[w] = x;
    __syncthreads();
    int wo = 0;
    #pragma unroll
    for (int k = 0; k < 4; k++) wo += (k < w) ? wsum[k] : 0;
    if (i < NN) excl[i] = x - v + wo;
    if (t == 255) bsum[blockIdx.x] = wo + x;     // block total
}

__global__ void k_scan2(int* __restrict__ bsum) {   // 1 block, 256 threads
    __shared__ int wsum[4];
    int t = threadIdx.x, lane = t & 63, w = t >> 6;
    int v = (t < NBLK) ? bsum[t] : 0;
    int x = v;
    #pragma unroll
    for (int o = 1; o < 64; o <<= 1) {
        int y = __shfl_up(x, o, 64);
        if (lane >= o) x += y;
    }
    if (lane == 63) wsum[w] = x;
    __syncthreads();
    int wo = 0;
    #pragma unroll
    for (int k = 0; k < 4; k++) wo += (k < w) ? wsum[k] : 0;
    if (t < NBLK) bsum[t] = x - v + wo;          // exclusive
}

__global__ void k_scan3(int* __restrict__ row_ptr, const int* __restrict__ bsum,
                        int* __restrict__ cursor) {
    int i = blockIdx.x * 256 + threadIdx.x;
    if (i < NN) {
        int r = row_ptr[i] + bsum[blockIdx.x];
        row_ptr[i] = r;
        cursor[i] = r;
    }
    if (i == 0) row_ptr[NN] = ET;
}

__global__ void k_scatter(const int* __restrict__ ei, int* __restrict__ cursor,
                          int* __restrict__ csr) {
    int e = blockIdx.x * blockDim.x + threadIdx.x;
    if (e >= ET) return;
    int s, d;
    if (e < NE) { s = ei[e]; d = ei[NE + e]; }
    else        { s = d = e - NE; }
    int pos = atomicAdd(&cursor[d], 1);
    csr[pos] = s;
}

// ---------------------------------------------------------------- prep
__global__ void k_castx(const float4* __restrict__ x, ushort4* __restrict__ xb, int n4) {
    int i = blockIdx.x * blockDim.x + threadIdx.x;
    if (i >= n4) return;
    float4 v = x[i];
    ushort4 o;
    o.x = f2bf(v.x); o.y = f2bf(v.y); o.z = f2bf(v.z); o.w = f2bf(v.w);
    xb[i] = o;
}

// W (K x N fp32 row-major) -> Bt (N x 2K bf16): cols [0,K)=high, [K,2K)=low split
__global__ void k_prep(const float* __restrict__ W, ushort_t* __restrict__ Bt,
                       int K, int N) {
    int i = blockIdx.x * blockDim.x + threadIdx.x;
    if (i >= K * N) return;
    int k = i / N, n = i % N;
    float v = W[i];
    ushort_t h = f2bf(v);
    float r = v - bf2f(h);
    Bt[(size_t)n * 2 * K + k] = h;
    Bt[(size_t)n * 2 * K + K + k] = f2bf(r);
}

// ---------------------------------------------------------------- MFMA GEMM
// C[M x N](bf16) = A[M x K](bf16) @ (Bh + Bl), split-bf16 weights.
// BM=128, BN=64, BK=64, 256 thr (4 waves), mfma 16x16x32.
// EDOT: blockIdx.y covers exactly one head (64 cols); epilogue computes
// es/ed = C . a_s/.a_d via per-quad 16-lane butterfly (replaces k_edot).
template<bool ELU, bool BIAS, bool EDOT>
__global__ __launch_bounds__(256) void gemm_mfma(const ushort_t* __restrict__ A,
                                                 const ushort_t* __restrict__ Bt,
                                                 const float* __restrict__ bias,
                                                 ushort_t* __restrict__ C,
                                                 const float* __restrict__ a_s,
                                                 const float* __restrict__ a_d,
                                                 float* __restrict__ es,
                                                 float* __restrict__ ed,
                                                 int esStride,
                                                 int M, int K, int N) {
    __shared__ __align__(16) ushort_t lds[16384];  // [0,8192) A, [8192,16384) B
    int tid = threadIdx.x;
    int wave = tid >> 6, lane = tid & 63;
    int quad = lane >> 4, l16 = lane & 15;
    int mb = blockIdx.x * 128, nb = blockIdx.y * 64;
    int K2 = 2 * K;

    f32x4 acc[2][4];
    #pragma unroll
    for (int mt = 0; mt < 2; mt++)
        #pragma unroll
        for (int nt = 0; nt < 4; nt++)
            acc[mt][nt] = (f32x4){0.f, 0.f, 0.f, 0.f};

    for (int k0 = 0; k0 < K; k0 += 64) {
        #pragma unroll
        for (int c = 0; c < 4; c++) {
            int mt = wave * 2 + (c >> 1);
            int ks = c & 1;
            int row = mb + mt * 16 + l16;
            row = min(row, M - 1);
            int col = k0 + ks * 32 + quad * 8;
            gl_lds16(A + (size_t)row * K + col, &lds[(mt * 2 + ks) * 512]);
        }
        #pragma unroll
        for (int c = 0; c < 4; c++) {
            int id = wave * 4 + c;
            int ntile = id & 3;
            int ks = (id >> 2) & 1;
            int split = id >> 3;
            int n = nb + ntile * 16 + l16;
            int col = split * K + k0 + ks * 32 + quad * 8;
            gl_lds16(Bt + (size_t)n * K2 + col,
                     &lds[8192 + ((split * 4 + ntile) * 2 + ks) * 512]);
        }
        __syncthreads();
        #pragma unroll
        for (int ks = 0; ks < 2; ks++) {
            short8 af[2];
            #pragma unroll
            for (int mt = 0; mt < 2; mt++)
                af[mt] = *(const short8*)&lds[((wave * 2 + mt) * 2 + ks) * 512 + lane * 8];
            short8 bh[4], bl[4];
            #pragma unroll
            for (int nt = 0; nt < 4; nt++) {
                bh[nt] = *(const short8*)&lds[8192 + (nt * 2 + ks) * 512 + lane * 8];
                bl[nt] = *(const short8*)&lds[8192 + ((4 + nt) * 2 + ks) * 512 + lane * 8];
            }
            #pragma unroll
            for (int mt = 0; mt < 2; mt++)
                #pragma unroll
                for (int nt = 0; nt < 4; nt++) {
                    acc[mt][nt] = __builtin_amdgcn_mfma_f32_16x16x32_bf16(
                        af[mt], bh[nt], acc[mt][nt], 0, 0, 0);
                    acc[mt][nt] = __builtin_amdgcn_mfma_f32_16x16x32_bf16(
                        af[mt], bl[nt], acc[mt][nt], 0, 0, 0);
                }
        }
        __syncthreads();
    }
    // ---- epilogue: C/D layout col=lane&15, row=quad*4+reg ----
    float asl[4], adl[4];
    if constexpr (EDOT) {
        #pragma unroll
        for (int nt = 0; nt < 4; nt++) {
            asl[nt] = a_s[nb + nt * 16 + l16];
            adl[nt] = a_d[nb + nt * 16 + l16];
        }
    }
    int head = blockIdx.y;
    #pragma unroll
    for (int mt = 0; mt < 2; mt++) {
        int mrow = mb + (wave * 2 + mt) * 16 + quad * 4;
        #pragma unroll
        for (int r = 0; r < 4; r++) {
            int m = mrow + r;
            if constexpr (EDOT) {
                float ps = 0.f, pd = 0.f;
                #pragma unroll
                for (int nt = 0; nt < 4; nt++) {
                    float v = acc[mt][nt][r];
                    ps += v * asl[nt];
                    pd += v * adl[nt];
                }
                #pragma unroll
                for (int o = 8; o >= 1; o >>= 1) {
                    ps += __shfl_xor(ps, o, 64);
                    pd += __shfl_xor(pd, o, 64);
                }
                if (l16 == 0 && m < M) {
                    es[(size_t)m * esStride + head] = ps;
                    ed[(size_t)m * esStride + head] = pd;
                }
            }
            if (m < M) {
                #pragma unroll
                for (int nt = 0; nt < 4; nt++) {
                    int n = nb + nt * 16 + l16;
                    float v = acc[mt][nt][r];
                    if (BIAS) v += bias[n];
                    if (ELU) v = elu1(v);
                    C[(size_t)m * N + n] = f2bf(v);
                }
            }
        }
    }
}

// ------------------------------------------------- softmax aggregate, 4 heads
// 1 wave per node. Fast path (deg<=64): single chunk keeps leaky logits in
// registers across softmax-stat and weight steps. Gather unrolled x4.
template<bool BFOUT>
__global__ __launch_bounds__(256) void k_agg4(const ushort_t* __restrict__ xl,
                                              const float* __restrict__ es,
                                              const float* __restrict__ ed,
                                              const int* __restrict__ row_ptr,
                                              const int* __restrict__ csr,
                                              const float* __restrict__ bias,
                                              void* __restrict__ outv) {
    __shared__ float wlds[4][256];
    int lane = threadIdx.x & 63, wave = threadIdx.x >> 6;
    int node = blockIdx.x * 4 + wave;
    if (node >= NN) return;
    int head = lane >> 4;
    int start = row_ptr[node], end = row_ptr[node + 1];
    int deg = end - start;
    float4 edv = *(const float4*)(ed + (size_t)node * 4);
    float edh[4] = {edv.x, edv.y, edv.z, edv.w};
    float a0 = 0.f, a1 = 0.f, a2 = 0.f, a3 = 0.f;

    if (deg <= 64) {
        // ---- fused single-chunk softmax ----
        int i = start + lane;
        bool valid = i < end;
        int idx = csr[valid ? i : start];
        float4 ev = *(const float4*)(es + (size_t)idx * 4);
        float e[4] = {ev.x, ev.y, ev.z, ev.w};
        #pragma unroll
        for (int h = 0; h < 4; h++) {
            float v = e[h] + edh[h];
            v = v > 0.f ? v : 0.2f * v;
            e[h] = valid ? v : -1e30f;
        }
        float cm[4];
        #pragma unroll
        for (int h = 0; h < 4; h++) cm[h] = e[h];
        #pragma unroll
        for (int o = 32; o >= 1; o >>= 1)
            #pragma unroll
            for (int h = 0; h < 4; h++) cm[h] = fmaxf(cm[h], __shfl_xor(cm[h], o, 64));
        float cs[4];
        #pragma unroll
        for (int h = 0; h < 4; h++) cs[h] = valid ? __expf(e[h] - cm[h]) : 0.f;
        #pragma unroll
        for (int o = 32; o >= 1; o >>= 1)
            #pragma unroll
            for (int h = 0; h < 4; h++) cs[h] += __shfl_xor(cs[h], o, 64);
        float4 wv;
        wv.x = valid ? __expf(e[0] - cm[0]) / cs[0] : 0.f;
        wv.y = valid ? __expf(e[1] - cm[1]) / cs[1] : 0.f;
        wv.z = valid ? __expf(e[2] - cm[2]) / cs[2] : 0.f;
        wv.w = valid ? __expf(e[3] - cm[3]) / cs[3] : 0.f;
        *(float4*)&wlds[wave][lane * 4] = wv;
        // ---- gather, unrolled x4 ----
        int t = 0;
        for (; t + 4 <= deg; t += 4) {
            int s0 = __shfl(idx, t + 0, 64);
            int s1 = __shfl(idx, t + 1, 64);
            int s2 = __shfl(idx, t + 2, 64);
            int s3 = __shfl(idx, t + 3, 64);
            float w0 = wlds[wave][(t + 0) * 4 + head];
            float w1 = wlds[wave][(t + 1) * 4 + head];
            float w2 = wlds[wave][(t + 2) * 4 + head];
            float w3 = wlds[wave][(t + 3) * 4 + head];
            ushort4 u0 = *(const ushort4*)(xl + (size_t)s0 * 256 + lane * 4);
            ushort4 u1 = *(const ushort4*)(xl + (size_t)s1 * 256 + lane * 4);
            ushort4 u2 = *(const ushort4*)(xl + (size_t)s2 * 256 + lane * 4);
            ushort4 u3 = *(const ushort4*)(xl + (size_t)s3 * 256 + lane * 4);
            a0 += w0 * bf2f(u0.x); a1 += w0 * bf2f(u0.y); a2 += w0 * bf2f(u0.z); a3 += w0 * bf2f(u0.w);
            a0 += w1 * bf2f(u1.x); a1 += w1 * bf2f(u1.y); a2 += w1 * bf2f(u1.z); a3 += w1 * bf2f(u1.w);
            a0 += w2 * bf2f(u2.x); a1 += w2 * bf2f(u2.y); a2 += w2 * bf2f(u2.z); a3 += w2 * bf2f(u2.w);
            a0 += w3 * bf2f(u3.x); a1 += w3 * bf2f(u3.y); a2 += w3 * bf2f(u3.z); a3 += w3 * bf2f(u3.w);
        }
        for (; t < deg; ++t) {
            int s = __shfl(idx, t, 64);
            float w = wlds[wave][t * 4 + head];
            ushort4 u = *(const ushort4*)(xl + (size_t)s * 256 + lane * 4);
            a0 += w * bf2f(u.x); a1 += w * bf2f(u.y); a2 += w * bf2f(u.z); a3 += w * bf2f(u.w);
        }
    } else {
        // ---- general two-pass path (deg > 64, essentially never) ----
        float m[4], ssum[4];
        #pragma unroll
        for (int h = 0; h < 4; h++) { m[h] = -1e30f; ssum[h] = 0.f; }
        for (int base = start; base < end; base += 64) {
            int i = base + lane;
            bool valid = i < end;
            int idx = csr[valid ? i : start];
            float4 ev = *(const float4*)(es + (size_t)idx * 4);
            float e[4] = {ev.x, ev.y, ev.z, ev.w};
            #pragma unroll
            for (int h = 0; h < 4; h++) {
                float v = e[h] + edh[h];
                v = v > 0.f ? v : 0.2f * v;
                e[h] = valid ? v : -1e30f;
            }
            float cm[4];
            #pragma unroll
            for (int h = 0; h < 4; h++) cm[h] = e[h];
            #pragma unroll
            for (int o = 32; o >= 1; o >>= 1)
                #pragma unroll
                for (int h = 0; h < 4; h++) cm[h] = fmaxf(cm[h], __shfl_xor(cm[h], o, 64));
            float cs[4];
            #pragma unroll
            for (int h = 0; h < 4; h++) cs[h] = valid ? __expf(e[h] - cm[h]) : 0.f;
            #pragma unroll
            for (int o = 32; o >= 1; o >>= 1)
                #pragma unroll
                for (int h = 0; h < 4; h++) cs[h] += __shfl_xor(cs[h], o, 64);
            #pragma unroll
            for (int h = 0; h < 4; h++) {
                float mn = fmaxf(m[h], cm[h]);
                ssum[h] = ssum[h] * __expf(m[h] - mn) + cs[h] * __expf(cm[h] - mn);
                m[h] = mn;
            }
        }
        float inv[4];
        #pragma unroll
        for (int h = 0; h < 4; h++) inv[h] = 1.f / ssum[h];
        for (int base = start; base < end; base += 64) {
            int i = base + lane;
            bool valid = i < end;
            int idx = csr[valid ? i : start];
            int cnt = min(64, end - base);
            float4 ev = *(const float4*)(es + (size_t)idx * 4);
            float e[4] = {ev.x, ev.y, ev.z, ev.w};
            #pragma unroll
            for (int h = 0; h < 4; h++) {
                float v = e[h] + edh[h];
                v = v > 0.f ? v : 0.2f * v;
                e[h] = valid ? __expf(v - m[h]) * inv[h] : 0.f;
            }
            float4 wv; wv.x = e[0]; wv.y = e[1]; wv.z = e[2]; wv.w = e[3];
            *(float4*)&wlds[wave][lane * 4] = wv;
            for (int t = 0; t < cnt; ++t) {
                int s = __shfl(idx, t, 64);
                float w = wlds[wave][t * 4 + head];
                ushort4 u = *(const ushort4*)(xl + (size_t)s * 256 + lane * 4);
                a0 += w * bf2f(u.x); a1 += w * bf2f(u.y); a2 += w * bf2f(u.z); a3 += w * bf2f(u.w);
            }
        }
    }

    float o0 = elu1(a0 + bias[lane * 4 + 0]);
    float o1 = elu1(a1 + bias[lane * 4 + 1]);
    float o2 = elu1(a2 + bias[lane * 4 + 2]);
    float o3 = elu1(a3 + bias[lane * 4 + 3]);
    if constexpr (BFOUT) {
        ushort4 o; o.x = f2bf(o0); o.y = f2bf(o1); o.z = f2bf(o2); o.w = f2bf(o3);
        *(ushort4*)((ushort_t*)outv + (size_t)node * 256 + lane * 4) = o;
    } else {
        float4 o; o.x = o0; o.y = o1; o.z = o2; o.w = o3;
        *(float4*)((float*)outv + (size_t)node * 256 + lane * 4) = o;
    }
}

// ------------------------------------------------- softmax aggregate, 1 head
// 4 nodes per wave (16-lane groups, ushort4 = 4 dims/lane); mean-pool partial:
// block-reduces elu outputs and STORES one 64-float row per block (no atomics
// — G12: 200k same-line atomics serialized at the coherent point in R4).
__global__ __launch_bounds__(256) void k_agg1(const ushort_t* __restrict__ xl,
                                              const float* __restrict__ es,
                                              const float* __restrict__ ed,
                                              const int* __restrict__ row_ptr,
                                              const int* __restrict__ csr,
                                              const float* __restrict__ bias,
                                              float* __restrict__ part) {
    __shared__ float wlds[4][64];
    __shared__ float ps[4][64];
    int lane = threadIdx.x & 63, wave = threadIdx.x >> 6;
    int g = lane >> 4, l16 = lane & 15;
    int node = blockIdx.x * 16 + wave * 4 + g;
    bool vn = node < NN;
    int start = vn ? row_ptr[node] : 0;
    int end   = vn ? row_ptr[node + 1] : 0;
    float edl = vn ? ed[node] : 0.f;

    // ---- pass 1: softmax stats, 16 edges/chunk per group ----
    float m = -1e30f, ssum = 0.f;
    for (int base = start; base < end; base += 16) {
        int i = base + l16;
        bool valid = i < end;
        int idx = csr[valid ? i : start];
        float e = es[idx] + edl;
        e = e > 0.f ? e : 0.2f * e;
        e = valid ? e : -1e30f;
        float cm = e;
        #pragma unroll
        for (int o = 8; o >= 1; o >>= 1) cm = fmaxf(cm, __shfl_xor(cm, o, 64));
        float cs = valid ? __expf(e - cm) : 0.f;
        #pragma unroll
        for (int o = 8; o >= 1; o >>= 1) cs += __shfl_xor(cs, o, 64);
        float mn = fmaxf(m, cm);
        ssum = ssum * __expf(m - mn) + cs * __expf(cm - mn);
        m = mn;
    }
    float inv = 1.f / ssum;

    // ---- pass 2: weights -> LDS, gather unrolled x4 ----
    float a[4] = {0.f, 0.f, 0.f, 0.f};
    for (int base = start; base < end; base += 16) {
        int i = base + l16;
        bool valid = i < end;
        int idx = csr[valid ? i : start];
        int cnt = min(16, end - base);
        float e = es[idx] + edl;
        e = e > 0.f ? e : 0.2f * e;
        wlds[wave][g * 16 + l16] = valid ? __expf(e - m) * inv : 0.f;
        int t = 0;
        for (; t + 4 <= cnt; t += 4) {
            int s0 = __shfl(idx, g * 16 + t + 0, 64);
            int s1 = __shfl(idx, g * 16 + t + 1, 64);
            int s2 = __shfl(idx, g * 16 + t + 2, 64);
            int s3 = __shfl(idx, g * 16 + t + 3, 64);
            float w0 = wlds[wave][g * 16 + t + 0];
            float w1 = wlds[wave][g * 16 + t + 1];
            float w2 = wlds[wave][g * 16 + t + 2];
            float w3 = wlds[wave][g * 16 + t + 3];
            ushort4 u0 = *(const ushort4*)(xl + (size_t)s0 * 64 + l16 * 4);
            ushort4 u1 = *(const ushort4*)(xl + (size_t)s1 * 64 + l16 * 4);
            ushort4 u2 = *(const ushort4*)(xl + (size_t)s2 * 64 + l16 * 4);
            ushort4 u3 = *(const ushort4*)(xl + (size_t)s3 * 64 + l16 * 4);
            a[0] += w0 * bf2f(u0.x); a[1] += w0 * bf2f(u0.y); a[2] += w0 * bf2f(u0.z); a[3] += w0 * bf2f(u0.w);
            a[0] += w1 * bf2f(u1.x); a[1] += w1 * bf2f(u1.y); a[2] += w1 * bf2f(u1.z); a[3] += w1 * bf2f(u1.w);
            a[0] += w2 * bf2f(u2.x); a[1] += w2 * bf2f(u2.y); a[2] += w2 * bf2f(u2.z); a[3] += w2 * bf2f(u2.w);
            a[0] += w3 * bf2f(u3.x); a[1] += w3 * bf2f(u3.y); a[2] += w3 * bf2f(u3.z); a[3] += w3 * bf2f(u3.w);
        }
        for (; t < cnt; ++t) {
            int s = __shfl(idx, g * 16 + t, 64);
            float w = wlds[wave][g * 16 + t];
            ushort4 u = *(const ushort4*)(xl + (size_t)s * 64 + l16 * 4);
            a[0] += w * bf2f(u.x); a[1] += w * bf2f(u.y); a[2] += w * bf2f(u.z); a[3] += w * bf2f(u.w);
        }
    }

    // ---- block-level partial mean-pool (non-atomic store) ----
    float o[4];
    #pragma unroll
    for (int j = 0; j < 4; j++)
        o[j] = vn ? elu1(a[j] + bias[l16 * 4 + j]) : 0.f;
    #pragma unroll
    for (int j = 0; j < 4; j++) {
        o[j] += __shfl_xor(o[j], 16, 64);
        o[j] += __shfl_xor(o[j], 32, 64);
    }
    if (lane < 16) {
        float4 v; v.x = o[0]; v.y = o[1]; v.z = o[2]; v.w = o[3];
        *(float4*)&ps[wave][l16 * 4] = v;
    }
    __syncthreads();
    int tid = threadIdx.x;
    if (tid < 64) {
        float tot = ps[0][tid] + ps[1][tid] + ps[2][tid] + ps[3][tid];
        part[(size_t)blockIdx.x * 64 + tid] = tot;
    }
}

// ---- reduce part[NAGG1][64] -> gsum[64] (few blocks => few atomics) ----
__global__ void k_red(const float* __restrict__ part, float* __restrict__ gsum) {
    __shared__ float sm[4][64];
    int t = threadIdx.x, c = t & 63, w = t >> 6;
    float s = 0.f;
    for (int r = blockIdx.x * 4 + w; r < NAGG1; r += gridDim.x * 4)
        s += part[(size_t)r * 64 + c];
    sm[w][c] = s;
    __syncthreads();
    if (w == 0) {
        float tot = sm[0][c] + sm[1][c] + sm[2][c] + sm[3][c];
        atomicAdd(&gsum[c], tot);
    }
}

// ---------------------------------------------------------------- final
__global__ void k_final(const float* __restrict__ gsum, const float* __restrict__ w_out,
                        const float* __restrict__ b_out, float* __restrict__ out) {
    int j = threadIdx.x;   // 128
    float s = b_out[j];
    const float invn = 1.f / (float)NN;
    #pragma unroll 8
    for (int k = 0; k < 64; k++)
        s += (gsum[k] * invn) * w_out[k * 128 + j];
    out[j] = s;
}

// ---------------------------------------------------------------- launcher
extern "C" void kernel_launch(void* const* d_in, const int* in_sizes, int n_in,
                              void* d_out, int out_size, void* d_ws, size_t ws_size,
                              hipStream_t stream) {
    const float* x    = (const float*)d_in[0];
    const int*   ei   = (const int*)d_in[1];
    const float* w_in = (const float*)d_in[2];
    const float* b_in = (const float*)d_in[3];
    const float* W0   = (const float*)d_in[4];
    const float* as0  = (const float*)d_in[5];
    const float* ad0  = (const float*)d_in[6];
    const float* bb0  = (const float*)d_in[7];
    const float* W1   = (const float*)d_in[8];
    const float* as1  = (const float*)d_in[9];
    const float* ad1  = (const float*)d_in[10];
    const float* bb1  = (const float*)d_in[11];
    const float* W2   = (const float*)d_in[12];
    const float* as2  = (const float*)d_in[13];
    const float* ad2  = (const float*)d_in[14];
    const float* bb2  = (const float*)d_in[15];
    const float* w_out= (const float*)d_in[16];
    const float* b_out= (const float*)d_in[17];
    float* out = (float*)d_out;

    char* p = (char*)d_ws;
    size_t off = 0;
    auto take = [&](size_t bytes) {
        char* r = p + off;
        off = (off + bytes + 255) & ~(size_t)255;
        return r;
    };
    ushort_t* xb     = (ushort_t*)take((size_t)NN * 256 * 2); // 25.6 MB
    ushort_t* h0b    = (ushort_t*)take((size_t)NN * 64 * 2);  //  6.4 MB
    ushort_t* xl_bf  = (ushort_t*)take((size_t)NN * 256 * 2); // 25.6 MB
    ushort_t* hb_bf  = (ushort_t*)take((size_t)NN * 256 * 2); // 25.6 MB
    ushort_t* h2_bf  = (ushort_t*)take((size_t)NN * 64 * 2);  //  6.4 MB
    ushort_t* wiT    = (ushort_t*)take((size_t)64 * 512 * 2);
    ushort_t* w0T    = (ushort_t*)take((size_t)256 * 128 * 2);
    ushort_t* w1T    = (ushort_t*)take((size_t)256 * 512 * 2);
    ushort_t* w2T    = (ushort_t*)take((size_t)64 * 512 * 2);
    float*    es     = (float*)take((size_t)NN * 4 * 4);
    float*    ed     = (float*)take((size_t)NN * 4 * 4);
    int*      row_ptr= (int*)take((size_t)(NN + 1) * 4);
    int*      cursor = (int*)take((size_t)NN * 4);
    int*      csr    = (int*)take((size_t)ET * 4);
    int*      bsum   = (int*)take((size_t)NBLK * 4);
    float*    part   = (float*)take((size_t)NAGG1 * 64 * 4);  // 0.8 MB
    float*    gsum   = (float*)take(64 * 4);

    // ---- CSR build (by dst, with self-loops) ----
    k_init   <<<(NN + 255) / 256, 256, 0, stream>>>(cursor, gsum);
    k_hist   <<<(NE + 255) / 256, 256, 0, stream>>>(ei + NE, cursor);
    k_scan1  <<<NBLK, 256, 0, stream>>>(cursor, row_ptr, bsum);
    k_scan2  <<<1, 256, 0, stream>>>(bsum);
    k_scan3  <<<NBLK, 256, 0, stream>>>(row_ptr, bsum, cursor);
    k_scatter<<<(ET + 255) / 256, 256, 0, stream>>>(ei, cursor, csr);

    // ---- prep: cast x to bf16; split-transpose weights ----
    k_castx<<<(NN * 64 + 255) / 256, 256, 0, stream>>>((const float4*)x, (ushort4*)xb, NN * 64);
    k_prep <<<(256 * 64 + 255) / 256, 256, 0, stream>>>(w_in, wiT, 256, 64);
    k_prep <<<(64 * 256 + 255) / 256, 256, 0, stream>>>(W0, w0T, 64, 256);
    k_prep <<<(256 * 256 + 255) / 256, 256, 0, stream>>>(W1, w1T, 256, 256);
    k_prep <<<(256 * 64 + 255) / 256, 256, 0, stream>>>(W2, w2T, 256, 64);

    const int GM = (NN + 127) / 128;   // 391

    // ---- input projection: h0 = elu(x @ w_in + b_in) ----
    gemm_mfma<true, true, false><<<dim3(GM, 1), 256, 0, stream>>>(
        xb, wiT, b_in, h0b, nullptr, nullptr, nullptr, nullptr, 0, NN, 256, 64);

    // ---- GAT layer 0 (heads=4, concat); es/ed fused in GEMM epilogue ----
    gemm_mfma<false, false, true><<<dim3(GM, 4), 256, 0, stream>>>(
        h0b, w0T, nullptr, xl_bf, as0, ad0, es, ed, 4, NN, 64, 256);
    k_agg4<true><<<(NN + 3) / 4, 256, 0, stream>>>(xl_bf, es, ed, row_ptr, csr, bb0, hb_bf);

    // ---- GAT layer 1 (heads=4, concat) ----
    gemm_mfma<false, false, true><<<dim3(GM, 4), 256, 0, stream>>>(
        hb_bf, w1T, nullptr, xl_bf, as1, ad1, es, ed, 4, NN, 256, 256);
    k_agg4<true><<<(NN + 3) / 4, 256, 0, stream>>>(xl_bf, es, ed, row_ptr, csr, bb1, hb_bf);

    // ---- GAT layer 2 (heads=1) + partial mean-pool ----
    gemm_mfma<false, false, true><<<dim3(GM, 1), 256, 0, stream>>>(
        hb_bf, w2T, nullptr, h2_bf, as2, ad2, es, ed, 1, NN, 256, 64);
    k_agg1<<<NAGG1, 256, 0, stream>>>(h2_bf, es, ed, row_ptr, csr, bb2, part);
    k_red <<<64, 256, 0, stream>>>(part, gsum);

    // ---- output projection ----
    k_final<<<1, 128, 0, stream>>>(gsum, w_out, b_out, out);
}

// Round 7
// 475.371 us; speedup vs baseline: 1.8592x; 1.0022x over previous
//
#include <hip/hip_runtime.h>

#define NN 50000
#define NE 800000
#define ET 850000   // NE + NN self-loops
#define NBLK 196    // ceil(NN/256) for the parallel scan
#define NAGG1 3125  // k_agg1 grid (= NN/16), also rows of `part`
#define MEGA_CAST 12500          // castx blocks: NN*256 elems / 4 per float4 / 256 thr
#define MEGA_GRID (12500 + 448)  // + weight-prep blocks (114688/256)

typedef unsigned short ushort_t;
typedef unsigned int uint_t;
typedef __attribute__((ext_vector_type(8))) short short8;
typedef __attribute__((ext_vector_type(4))) float f32x4;

// ---------------------------------------------------------------- utilities
__device__ __forceinline__ float elu1(float x) {
    return x > 0.f ? x : (__expf(x) - 1.f);
}
__device__ __forceinline__ float bf2f(ushort_t u) {
    return __uint_as_float(((uint_t)u) << 16);
}
__device__ __forceinline__ ushort_t f2bf(float f) {   // round-to-nearest-even
    uint_t u = __float_as_uint(f);
    u += 0x7FFFu + ((u >> 16) & 1u);
    return (ushort_t)(u >> 16);
}
__device__ __forceinline__ void gl_lds16(const ushort_t* g, ushort_t* l) {
    // async global->LDS, 16B/lane; LDS dest = wave-uniform base + lane*16
    __builtin_amdgcn_global_load_lds((const __attribute__((address_space(1))) void*)g,
                                     (__attribute__((address_space(3))) void*)l,
                                     16, 0, 0);
}
// bf16 pair (packed in a dword) -> two fp32, exact (bf16 = truncated fp32)
#define ACC2(q, w) do { \
    a0 += (w) * __uint_as_float((q).x << 16); \
    a1 += (w) * __uint_as_float((q).x & 0xFFFF0000u); \
    a2 += (w) * __uint_as_float((q).y << 16); \
    a3 += (w) * __uint_as_float((q).y & 0xFFFF0000u); } while (0)

// ---------------------------------------------------------------- CSR build
__global__ void k_hist(const int* __restrict__ dst, int* __restrict__ cursor) {
    int e = blockIdx.x * blockDim.x + threadIdx.x;
    if (e < NE) atomicAdd(&cursor[dst[e]], 1);
}

// parallel exclusive scan: scan1 (block-local) -> scan2 (block sums) -> scan3 (add)
__global__ void k_scan1(const int* __restrict__ cnt, int* __restrict__ excl,
                        int* __restrict__ bsum) {
    __shared__ int wsum[4];
    int t = threadIdx.x, lane = t & 63, w = t >> 6;
    int i = blockIdx.x * 256 + t;
    int v = (i < NN) ? cnt[i] : 0;
    int x = v;
    #pragma unroll
    for (int o = 1; o < 64; o <<= 1) {
        int y = __shfl_up(x, o, 64);
        if (lane >= o) x += y;
    }
    if (lane == 63) wsum[w] = x;
    __syncthreads();
    int wo = 0;
    #pragma unroll
    for (int k = 0; k < 4; k++) wo += (k < w) ? wsum[k] : 0;
    if (i < NN) excl[i] = x - v + wo;
    if (t == 255) bsum[blockIdx.x] = wo + x;     // block total
}

__global__ void k_scan2(int* __restrict__ bsum) {   // 1 block, 256 threads
    __shared__ int wsum[4];
    int t = threadIdx.x, lane = t & 63, w = t >> 6;
    int v = (t < NBLK) ? bsum[t] : 0;
    int x = v;
    #pragma unroll
    for (int o = 1; o < 64; o <<= 1) {
        int y = __shfl_up(x, o, 64);
        if (lane >= o) x += y;
    }
    if (lane == 63) wsum[w] = x;
    __syncthreads();
    int wo = 0;
    #pragma unroll
    for (int k = 0; k < 4; k++) wo += (k < w) ? wsum[k] : 0;
    if (t < NBLK) bsum[t] = x - v + wo;          // exclusive
}

__global__ void k_scan3(int* __restrict__ row_ptr, const int* __restrict__ bsum,
                        int* __restrict__ cursor) {
    int i = blockIdx.x * 256 + threadIdx.x;
    if (i < NN) {
        int r = row_ptr[i] + bsum[blockIdx.x];
        row_ptr[i] = r;
        cursor[i] = r;
    }
    if (i == 0) row_ptr[NN] = ET;
}

__global__ void k_scatter(const int* __restrict__ ei, int* __restrict__ cursor,
                          int* __restrict__ csr) {
    int e = blockIdx.x * blockDim.x + threadIdx.x;
    if (e >= ET) return;
    int s, d;
    if (e < NE) { s = ei[e]; d = ei[NE + e]; }
    else        { s = d = e - NE; }
    int pos = atomicAdd(&cursor[d], 1);
    csr[pos] = s;
}

// ---------------------------------------------------------------- mega prep
// blocks [0,12500): x fp32->bf16, 256 float4/block (12500*256*4 = NN*256 exact)
//                   (+ cursor=1 init in first NBLK blocks, gsum=0 in block 0)
// blocks [12500,12948): all four weight split-transposes (exactly 114688 elems)
__global__ void k_mega(const float4* __restrict__ x, ushort4* __restrict__ xb,
                       const float* __restrict__ w_in, const float* __restrict__ W0,
                       const float* __restrict__ W1, const float* __restrict__ W2,
                       ushort_t* __restrict__ wiT, ushort_t* __restrict__ w0T,
                       ushort_t* __restrict__ w1T, ushort_t* __restrict__ w2T,
                       int* __restrict__ cursor, float* __restrict__ gsum) {
    int b = blockIdx.x, t = threadIdx.x;
    if (b < MEGA_CAST) {
        int i = b * 256 + t;                      // < NN*64 = 3,200,000 float4s
        float4 v = x[i];
        ushort4 o;
        o.x = f2bf(v.x); o.y = f2bf(v.y); o.z = f2bf(v.z); o.w = f2bf(v.w);
        xb[i] = o;
        if (b < NBLK) {
            int j = b * 256 + t;
            if (j < NN) cursor[j] = 1;            // pre-count self-loop
        }
        if (b == 0 && t < 64) gsum[t] = 0.f;
    } else {
        int i = (b - MEGA_CAST) * 256 + t;        // 0..114687
        const float* W; ushort_t* Bt; int K, N, j;
        if (i < 16384)       { W = w_in; Bt = wiT; K = 256; N = 64;  j = i; }
        else if (i < 32768)  { W = W0;   Bt = w0T; K = 64;  N = 256; j = i - 16384; }
        else if (i < 98304)  { W = W1;   Bt = w1T; K = 256; N = 256; j = i - 32768; }
        else                 { W = W2;   Bt = w2T; K = 256; N = 64;  j = i - 98304; }
        int k = j / N, n = j % N;
        float v = W[j];
        ushort_t h = f2bf(v);
        Bt[(size_t)n * 2 * K + k] = h;
        Bt[(size_t)n * 2 * K + K + k] = f2bf(v - bf2f(h));
    }
}

// ---------------------------------------------------------------- MFMA GEMM
// C[M x N](bf16) = A[M x K](bf16) @ (Bh + Bl), split-bf16 weights.
// BM=64*MT (MT=2: 128-row blocks; MT=1: 64-row blocks -> 2x grid for small-N
// GEMMs that otherwise leave half the CUs idle). BN=64, BK=64, 256 thr.
// EDOT: blockIdx.y covers exactly one head; epilogue computes es/ed via
// per-16-lane butterfly (replaces a separate k_edot pass).
template<bool ELU, bool BIAS, bool EDOT, int MT>
__global__ __launch_bounds__(256) void gemm_mfma(const ushort_t* __restrict__ A,
                                                 const ushort_t* __restrict__ Bt,
                                                 const float* __restrict__ bias,
                                                 ushort_t* __restrict__ C,
                                                 const float* __restrict__ a_s,
                                                 const float* __restrict__ a_d,
                                                 float* __restrict__ es,
                                                 float* __restrict__ ed,
                                                 int esStride,
                                                 int M, int K, int N) {
    __shared__ __align__(16) ushort_t lds[MT * 4096 + 8192]; // A | B frag-blocks
    int tid = threadIdx.x;
    int wave = tid >> 6, lane = tid & 63;
    int quad = lane >> 4, l16 = lane & 15;
    int mb = blockIdx.x * (64 * MT), nb = blockIdx.y * 64;
    int K2 = 2 * K;

    f32x4 acc[MT][4];
    #pragma unroll
    for (int mt = 0; mt < MT; mt++)
        #pragma unroll
        for (int nt = 0; nt < 4; nt++)
            acc[mt][nt] = (f32x4){0.f, 0.f, 0.f, 0.f};

    for (int k0 = 0; k0 < K; k0 += 64) {
        #pragma unroll
        for (int c = 0; c < 2 * MT; c++) {
            int mt = (MT == 2) ? (wave * 2 + (c >> 1)) : wave;
            int ks = (MT == 2) ? (c & 1) : c;
            int row = mb + mt * 16 + l16;
            row = min(row, M - 1);
            int col = k0 + ks * 32 + quad * 8;
            gl_lds16(A + (size_t)row * K + col, &lds[(mt * 2 + ks) * 512]);
        }
        #pragma unroll
        for (int c = 0; c < 4; c++) {
            int id = wave * 4 + c;
            int ntile = id & 3;
            int ks = (id >> 2) & 1;
            int split = id >> 3;
            int n = nb + ntile * 16 + l16;
            int col = split * K + k0 + ks * 32 + quad * 8;
            gl_lds16(Bt + (size_t)n * K2 + col,
                     &lds[MT * 4096 + ((split * 4 + ntile) * 2 + ks) * 512]);
        }
        __syncthreads();
        #pragma unroll
        for (int ks = 0; ks < 2; ks++) {
            short8 af[MT];
            #pragma unroll
            for (int mt = 0; mt < MT; mt++)
                af[mt] = *(const short8*)&lds[((wave * MT + mt) * 2 + ks) * 512 + lane * 8];
            short8 bh[4], bl[4];
            #pragma unroll
            for (int nt = 0; nt < 4; nt++) {
                bh[nt] = *(const short8*)&lds[MT * 4096 + (nt * 2 + ks) * 512 + lane * 8];
                bl[nt] = *(const short8*)&lds[MT * 4096 + ((4 + nt) * 2 + ks) * 512 + lane * 8];
            }
            #pragma unroll
            for (int mt = 0; mt < MT; mt++)
                #pragma unroll
                for (int nt = 0; nt < 4; nt++) {
                    acc[mt][nt] = __builtin_amdgcn_mfma_f32_16x16x32_bf16(
                        af[mt], bh[nt], acc[mt][nt], 0, 0, 0);
                    acc[mt][nt] = __builtin_amdgcn_mfma_f32_16x16x32_bf16(
                        af[mt], bl[nt], acc[mt][nt], 0, 0, 0);
                }
        }
        __syncthreads();
    }
    // ---- epilogue: C/D layout col=lane&15, row=quad*4+reg ----
    float asl[4], adl[4];
    if constexpr (EDOT) {
        #pragma unroll
        for (int nt = 0; nt < 4; nt++) {
            asl[nt] = a_s[nb + nt * 16 + l16];
            adl[nt] = a_d[nb + nt * 16 + l16];
        }
    }
    int head = blockIdx.y;
    #pragma unroll
    for (int mt = 0; mt < MT; mt++) {
        int mrow = mb + (wave * MT + mt) * 16 + quad * 4;
        #pragma unroll
        for (int r = 0; r < 4; r++) {
            int m = mrow + r;
            if constexpr (EDOT) {
                float ps = 0.f, pd = 0.f;
                #pragma unroll
                for (int nt = 0; nt < 4; nt++) {
                    float v = acc[mt][nt][r];
                    ps += v * asl[nt];
                    pd += v * adl[nt];
                }
                #pragma unroll
                for (int o = 8; o >= 1; o >>= 1) {
                    ps += __shfl_xor(ps, o, 64);
                    pd += __shfl_xor(pd, o, 64);
                }
                if (l16 == 0 && m < M) {
                    es[(size_t)m * esStride + head] = ps;
                    ed[(size_t)m * esStride + head] = pd;
                }
            }
            if (m < M) {
                #pragma unroll
                for (int nt = 0; nt < 4; nt++) {
                    int n = nb + nt * 16 + l16;
                    float v = acc[mt][nt][r];
                    if (BIAS) v += bias[n];
                    if (ELU) v = elu1(v);
                    C[(size_t)m * N + n] = f2bf(v);
                }
            }
        }
    }
}

// ------------------------------------------------- softmax aggregate, 4 heads
// 1 wave per node. Fast path (deg<=64): single chunk keeps leaky logits in
// registers. Gather unrolled x8 for memory-level parallelism (R5: 4-deep was
// latency-bound at VALUBusy 56%).
template<bool BFOUT>
__global__ __launch_bounds__(256) void k_agg4(const ushort_t* __restrict__ xl,
                                              const float* __restrict__ es,
                                              const float* __restrict__ ed,
                                              const int* __restrict__ row_ptr,
                                              const int* __restrict__ csr,
                                              const float* __restrict__ bias,
                                              void* __restrict__ outv) {
    __shared__ float wlds[4][256];
    int lane = threadIdx.x & 63, wave = threadIdx.x >> 6;
    int node = blockIdx.x * 4 + wave;
    if (node >= NN) return;
    int head = lane >> 4;
    int start = row_ptr[node], end = row_ptr[node + 1];
    int deg = end - start;
    float4 edv = *(const float4*)(ed + (size_t)node * 4);
    float edh[4] = {edv.x, edv.y, edv.z, edv.w};
    float a0 = 0.f, a1 = 0.f, a2 = 0.f, a3 = 0.f;

    if (deg <= 64) {
        // ---- fused single-chunk softmax ----
        int i = start + lane;
        bool valid = i < end;
        int idx = csr[valid ? i : start];
        float4 ev = *(const float4*)(es + (size_t)idx * 4);
        float e[4] = {ev.x, ev.y, ev.z, ev.w};
        #pragma unroll
        for (int h = 0; h < 4; h++) {
            float v = e[h] + edh[h];
            v = v > 0.f ? v : 0.2f * v;
            e[h] = valid ? v : -1e30f;
        }
        float cm[4];
        #pragma unroll
        for (int h = 0; h < 4; h++) cm[h] = e[h];
        #pragma unroll
        for (int o = 32; o >= 1; o >>= 1)
            #pragma unroll
            for (int h = 0; h < 4; h++) cm[h] = fmaxf(cm[h], __shfl_xor(cm[h], o, 64));
        float cs[4];
        #pragma unroll
        for (int h = 0; h < 4; h++) cs[h] = valid ? __expf(e[h] - cm[h]) : 0.f;
        #pragma unroll
        for (int o = 32; o >= 1; o >>= 1)
            #pragma unroll
            for (int h = 0; h < 4; h++) cs[h] += __shfl_xor(cs[h], o, 64);
        float4 wv;
        wv.x = valid ? __expf(e[0] - cm[0]) / cs[0] : 0.f;
        wv.y = valid ? __expf(e[1] - cm[1]) / cs[1] : 0.f;
        wv.z = valid ? __expf(e[2] - cm[2]) / cs[2] : 0.f;
        wv.w = valid ? __expf(e[3] - cm[3]) / cs[3] : 0.f;
        *(float4*)&wlds[wave][lane * 4] = wv;
        // ---- gather, unrolled x8 ----
        const uint_t* xb = (const uint_t*)xl;
        int t = 0;
        for (; t + 8 <= deg; t += 8) {
            int s0 = __shfl(idx, t + 0, 64), s1 = __shfl(idx, t + 1, 64);
            int s2 = __shfl(idx, t + 2, 64), s3 = __shfl(idx, t + 3, 64);
            int s4 = __shfl(idx, t + 4, 64), s5 = __shfl(idx, t + 5, 64);
            int s6 = __shfl(idx, t + 6, 64), s7 = __shfl(idx, t + 7, 64);
            uint2 q0 = *(const uint2*)(xb + (size_t)s0 * 128 + lane * 2);
            uint2 q1 = *(const uint2*)(xb + (size_t)s1 * 128 + lane * 2);
            uint2 q2 = *(const uint2*)(xb + (size_t)s2 * 128 + lane * 2);
            uint2 q3 = *(const uint2*)(xb + (size_t)s3 * 128 + lane * 2);
            uint2 q4 = *(const uint2*)(xb + (size_t)s4 * 128 + lane * 2);
            uint2 q5 = *(const uint2*)(xb + (size_t)s5 * 128 + lane * 2);
            uint2 q6 = *(const uint2*)(xb + (size_t)s6 * 128 + lane * 2);
            uint2 q7 = *(const uint2*)(xb + (size_t)s7 * 128 + lane * 2);
            float w0 = wlds[wave][(t + 0) * 4 + head], w1 = wlds[wave][(t + 1) * 4 + head];
            float w2 = wlds[wave][(t + 2) * 4 + head], w3 = wlds[wave][(t + 3) * 4 + head];
            float w4 = wlds[wave][(t + 4) * 4 + head], w5 = wlds[wave][(t + 5) * 4 + head];
            float w6 = wlds[wave][(t + 6) * 4 + head], w7 = wlds[wave][(t + 7) * 4 + head];
            ACC2(q0, w0); ACC2(q1, w1); ACC2(q2, w2); ACC2(q3, w3);
            ACC2(q4, w4); ACC2(q5, w5); ACC2(q6, w6); ACC2(q7, w7);
        }
        for (; t + 2 <= deg; t += 2) {
            int s0 = __shfl(idx, t + 0, 64), s1 = __shfl(idx, t + 1, 64);
            uint2 q0 = *(const uint2*)(xb + (size_t)s0 * 128 + lane * 2);
            uint2 q1 = *(const uint2*)(xb + (size_t)s1 * 128 + lane * 2);
            float w0 = wlds[wave][(t + 0) * 4 + head], w1 = wlds[wave][(t + 1) * 4 + head];
            ACC2(q0, w0); ACC2(q1, w1);
        }
        if (t < deg) {
            int s0 = __shfl(idx, t, 64);
            uint2 q0 = *(const uint2*)(xb + (size_t)s0 * 128 + lane * 2);
            float w0 = wlds[wave][t * 4 + head];
            ACC2(q0, w0);
        }
    } else {
        // ---- general two-pass path (deg > 64, essentially never) ----
        float m[4], ssum[4];
        #pragma unroll
        for (int h = 0; h < 4; h++) { m[h] = -1e30f; ssum[h] = 0.f; }
        for (int base = start; base < end; base += 64) {
            int i = base + lane;
            bool valid = i < end;
            int idx = csr[valid ? i : start];
            float4 ev = *(const float4*)(es + (size_t)idx * 4);
            float e[4] = {ev.x, ev.y, ev.z, ev.w};
            #pragma unroll
            for (int h = 0; h < 4; h++) {
                float v = e[h] + edh[h];
                v = v > 0.f ? v : 0.2f * v;
                e[h] = valid ? v : -1e30f;
            }
            float cm[4];
            #pragma unroll
            for (int h = 0; h < 4; h++) cm[h] = e[h];
            #pragma unroll
            for (int o = 32; o >= 1; o >>= 1)
                #pragma unroll
                for (int h = 0; h < 4; h++) cm[h] = fmaxf(cm[h], __shfl_xor(cm[h], o, 64));
            float cs[4];
            #pragma unroll
            for (int h = 0; h < 4; h++) cs[h] = valid ? __expf(e[h] - cm[h]) : 0.f;
            #pragma unroll
            for (int o = 32; o >= 1; o >>= 1)
                #pragma unroll
                for (int h = 0; h < 4; h++) cs[h] += __shfl_xor(cs[h], o, 64);
            #pragma unroll
            for (int h = 0; h < 4; h++) {
                float mn = fmaxf(m[h], cm[h]);
                ssum[h] = ssum[h] * __expf(m[h] - mn) + cs[h] * __expf(cm[h] - mn);
                m[h] = mn;
            }
        }
        float inv[4];
        #pragma unroll
        for (int h = 0; h < 4; h++) inv[h] = 1.f / ssum[h];
        for (int base = start; base < end; base += 64) {
            int i = base + lane;
            bool valid = i < end;
            int idx = csr[valid ? i : start];
            int cnt = min(64, end - base);
            float4 ev = *(const float4*)(es + (size_t)idx * 4);
            float e[4] = {ev.x, ev.y, ev.z, ev.w};
            #pragma unroll
            for (int h = 0; h < 4; h++) {
                float v = e[h] + edh[h];
                v = v > 0.f ? v : 0.2f * v;
                e[h] = valid ? __expf(v - m[h]) * inv[h] : 0.f;
            }
            float4 wv; wv.x = e[0]; wv.y = e[1]; wv.z = e[2]; wv.w = e[3];
            *(float4*)&wlds[wave][lane * 4] = wv;
            for (int t = 0; t < cnt; ++t) {
                int s = __shfl(idx, t, 64);
                float w = wlds[wave][t * 4 + head];
                uint2 q = *(const uint2*)((const uint_t*)xl + (size_t)s * 128 + lane * 2);
                ACC2(q, w);
            }
        }
    }

    float o0 = elu1(a0 + bias[lane * 4 + 0]);
    float o1 = elu1(a1 + bias[lane * 4 + 1]);
    float o2 = elu1(a2 + bias[lane * 4 + 2]);
    float o3 = elu1(a3 + bias[lane * 4 + 3]);
    if constexpr (BFOUT) {
        ushort4 o; o.x = f2bf(o0); o.y = f2bf(o1); o.z = f2bf(o2); o.w = f2bf(o3);
        *(ushort4*)((ushort_t*)outv + (size_t)node * 256 + lane * 4) = o;
    } else {
        float4 o; o.x = o0; o.y = o1; o.z = o2; o.w = o3;
        *(float4*)((float*)outv + (size_t)node * 256 + lane * 4) = o;
    }
}

// ------------------------------------------------- softmax aggregate, 1 head
// 4 nodes per wave (16-lane groups); partial mean-pool stored per block
// (no atomics — R4: 200k same-line atomics serialized at the coherent point).
__global__ __launch_bounds__(256) void k_agg1(const ushort_t* __restrict__ xl,
                                              const float* __restrict__ es,
                                              const float* __restrict__ ed,
                                              const int* __restrict__ row_ptr,
                                              const int* __restrict__ csr,
                                              const float* __restrict__ bias,
                                              float* __restrict__ part) {
    __shared__ float wlds[4][64];
    __shared__ float ps[4][64];
    int lane = threadIdx.x & 63, wave = threadIdx.x >> 6;
    int g = lane >> 4, l16 = lane & 15;
    int node = blockIdx.x * 16 + wave * 4 + g;
    bool vn = node < NN;
    int start = vn ? row_ptr[node] : 0;
    int end   = vn ? row_ptr[node + 1] : 0;
    float edl = vn ? ed[node] : 0.f;

    // ---- pass 1: softmax stats, 16 edges/chunk per group ----
    float m = -1e30f, ssum = 0.f;
    for (int base = start; base < end; base += 16) {
        int i = base + l16;
        bool valid = i < end;
        int idx = csr[valid ? i : start];
        float e = es[idx] + edl;
        e = e > 0.f ? e : 0.2f * e;
        e = valid ? e : -1e30f;
        float cm = e;
        #pragma unroll
        for (int o = 8; o >= 1; o >>= 1) cm = fmaxf(cm, __shfl_xor(cm, o, 64));
        float cs = valid ? __expf(e - cm) : 0.f;
        #pragma unroll
        for (int o = 8; o >= 1; o >>= 1) cs += __shfl_xor(cs, o, 64);
        float mn = fmaxf(m, cm);
        ssum = ssum * __expf(m - mn) + cs * __expf(cm - mn);
        m = mn;
    }
    float inv = 1.f / ssum;

    // ---- pass 2: weights -> LDS, gather unrolled x8 ----
    float a0 = 0.f, a1 = 0.f, a2 = 0.f, a3 = 0.f;
    const uint_t* xb = (const uint_t*)xl;
    for (int base = start; base < end; base += 16) {
        int i = base + l16;
        bool valid = i < end;
        int idx = csr[valid ? i : start];
        int cnt = min(16, end - base);
        float e = es[idx] + edl;
        e = e > 0.f ? e : 0.2f * e;
        wlds[wave][g * 16 + l16] = valid ? __expf(e - m) * inv : 0.f;
        int t = 0;
        for (; t + 8 <= cnt; t += 8) {
            int s0 = __shfl(idx, g * 16 + t + 0, 64), s1 = __shfl(idx, g * 16 + t + 1, 64);
            int s2 = __shfl(idx, g * 16 + t + 2, 64), s3 = __shfl(idx, g * 16 + t + 3, 64);
            int s4 = __shfl(idx, g * 16 + t + 4, 64), s5 = __shfl(idx, g * 16 + t + 5, 64);
            int s6 = __shfl(idx, g * 16 + t + 6, 64), s7 = __shfl(idx, g * 16 + t + 7, 64);
            uint2 q0 = *(const uint2*)(xb + (size_t)s0 * 32 + l16 * 2);
            uint2 q1 = *(const uint2*)(xb + (size_t)s1 * 32 + l16 * 2);
            uint2 q2 = *(const uint2*)(xb + (size_t)s2 * 32 + l16 * 2);
            uint2 q3 = *(const uint2*)(xb + (size_t)s3 * 32 + l16 * 2);
            uint2 q4 = *(const uint2*)(xb + (size_t)s4 * 32 + l16 * 2);
            uint2 q5 = *(const uint2*)(xb + (size_t)s5 * 32 + l16 * 2);
            uint2 q6 = *(const uint2*)(xb + (size_t)s6 * 32 + l16 * 2);
            uint2 q7 = *(const uint2*)(xb + (size_t)s7 * 32 + l16 * 2);
            float w0 = wlds[wave][g * 16 + t + 0], w1 = wlds[wave][g * 16 + t + 1];
            float w2 = wlds[wave][g * 16 + t + 2], w3 = wlds[wave][g * 16 + t + 3];
            float w4 = wlds[wave][g * 16 + t + 4], w5 = wlds[wave][g * 16 + t + 5];
            float w6 = wlds[wave][g * 16 + t + 6], w7 = wlds[wave][g * 16 + t + 7];
            ACC2(q0, w0); ACC2(q1, w1); ACC2(q2, w2); ACC2(q3, w3);
            ACC2(q4, w4); ACC2(q5, w5); ACC2(q6, w6); ACC2(q7, w7);
        }
        for (; t < cnt; ++t) {
            int s = __shfl(idx, g * 16 + t, 64);
            float w = wlds[wave][g * 16 + t];
            uint2 q = *(const uint2*)(xb + (size_t)s * 32 + l16 * 2);
            ACC2(q, w);
        }
    }

    // ---- block-level partial mean-pool (non-atomic store) ----
    float o[4];
    o[0] = vn ? elu1(a0 + bias[l16 * 4 + 0]) : 0.f;
    o[1] = vn ? elu1(a1 + bias[l16 * 4 + 1]) : 0.f;
    o[2] = vn ? elu1(a2 + bias[l16 * 4 + 2]) : 0.f;
    o[3] = vn ? elu1(a3 + bias[l16 * 4 + 3]) : 0.f;
    #pragma unroll
    for (int j = 0; j < 4; j++) {
        o[j] += __shfl_xor(o[j], 16, 64);
        o[j] += __shfl_xor(o[j], 32, 64);
    }
    if (lane < 16) {
        float4 v; v.x = o[0]; v.y = o[1]; v.z = o[2]; v.w = o[3];
        *(float4*)&ps[wave][l16 * 4] = v;
    }
    __syncthreads();
    int tid = threadIdx.x;
    if (tid < 64) {
        float tot = ps[0][tid] + ps[1][tid] + ps[2][tid] + ps[3][tid];
        part[(size_t)blockIdx.x * 64 + tid] = tot;
    }
}

// ---- reduce part[NAGG1][64] -> gsum[64] (few blocks => few atomics) ----
__global__ void k_red(const float* __restrict__ part, float* __restrict__ gsum) {
    __shared__ float sm[4][64];
    int t = threadIdx.x, c = t & 63, w = t >> 6;
    float s = 0.f;
    for (int r = blockIdx.x * 4 + w; r < NAGG1; r += gridDim.x * 4)
        s += part[(size_t)r * 64 + c];
    sm[w][c] = s;
    __syncthreads();
    if (w == 0) {
        float tot = sm[0][c] + sm[1][c] + sm[2][c] + sm[3][c];
        atomicAdd(&gsum[c], tot);
    }
}

// ---------------------------------------------------------------- final
__global__ void k_final(const float* __restrict__ gsum, const float* __restrict__ w_out,
                        const float* __restrict__ b_out, float* __restrict__ out) {
    int j = threadIdx.x;   // 128
    float s = b_out[j];
    const float invn = 1.f / (float)NN;
    #pragma unroll 8
    for (int k = 0; k < 64; k++)
        s += (gsum[k] * invn) * w_out[k * 128 + j];
    out[j] = s;
}

// ---------------------------------------------------------------- launcher
extern "C" void kernel_launch(void* const* d_in, const int* in_sizes, int n_in,
                              void* d_out, int out_size, void* d_ws, size_t ws_size,
                              hipStream_t stream) {
    const float* x    = (const float*)d_in[0];
    const int*   ei   = (const int*)d_in[1];
    const float* w_in = (const float*)d_in[2];
    const float* b_in = (const float*)d_in[3];
    const float* W0   = (const float*)d_in[4];
    const float* as0  = (const float*)d_in[5];
    const float* ad0  = (const float*)d_in[6];
    const float* bb0  = (const float*)d_in[7];
    const float* W1   = (const float*)d_in[8];
    const float* as1  = (const float*)d_in[9];
    const float* ad1  = (const float*)d_in[10];
    const float* bb1  = (const float*)d_in[11];
    const float* W2   = (const float*)d_in[12];
    const float* as2  = (const float*)d_in[13];
    const float* ad2  = (const float*)d_in[14];
    const float* bb2  = (const float*)d_in[15];
    const float* w_out= (const float*)d_in[16];
    const float* b_out= (const float*)d_in[17];
    float* out = (float*)d_out;

    char* p = (char*)d_ws;
    size_t off = 0;
    auto take = [&](size_t bytes) {
        char* r = p + off;
        off = (off + bytes + 255) & ~(size_t)255;
        return r;
    };
    ushort_t* xb     = (ushort_t*)take((size_t)NN * 256 * 2); // 25.6 MB
    ushort_t* h0b    = (ushort_t*)take((size_t)NN * 64 * 2);  //  6.4 MB
    ushort_t* xl_bf  = (ushort_t*)take((size_t)NN * 256 * 2); // 25.6 MB
    ushort_t* hb_bf  = (ushort_t*)take((size_t)NN * 256 * 2); // 25.6 MB
    ushort_t* h2_bf  = (ushort_t*)take((size_t)NN * 64 * 2);  //  6.4 MB
    ushort_t* wiT    = (ushort_t*)take((size_t)64 * 512 * 2);
    ushort_t* w0T    = (ushort_t*)take((size_t)256 * 128 * 2);
    ushort_t* w1T    = (ushort_t*)take((size_t)256 * 512 * 2);
    ushort_t* w2T    = (ushort_t*)take((size_t)64 * 512 * 2);
    float*    es     = (float*)take((size_t)NN * 4 * 4);
    float*    ed     = (float*)take((size_t)NN * 4 * 4);
    int*      row_ptr= (int*)take((size_t)(NN + 1) * 4);
    int*      cursor = (int*)take((size_t)NN * 4);
    int*      csr    = (int*)take((size_t)ET * 4);
    int*      bsum   = (int*)take((size_t)NBLK * 4);
    float*    part   = (float*)take((size_t)NAGG1 * 64 * 4);  // 0.8 MB
    float*    gsum   = (float*)take(64 * 4);

    // ---- mega prep: cursor/gsum init + x cast + weight split-transpose ----
    k_mega<<<MEGA_GRID, 256, 0, stream>>>((const float4*)x, (ushort4*)xb,
                                          w_in, W0, W1, W2, wiT, w0T, w1T, w2T,
                                          cursor, gsum);

    // ---- CSR build (by dst, with self-loops) ----
    k_hist   <<<(NE + 255) / 256, 256, 0, stream>>>(ei + NE, cursor);
    k_scan1  <<<NBLK, 256, 0, stream>>>(cursor, row_ptr, bsum);
    k_scan2  <<<1, 256, 0, stream>>>(bsum);
    k_scan3  <<<NBLK, 256, 0, stream>>>(row_ptr, bsum, cursor);
    k_scatter<<<(ET + 255) / 256, 256, 0, stream>>>(ei, cursor, csr);

    const int GM128 = (NN + 127) / 128;   // 391
    const int GM64  = (NN + 63) / 64;     // 782

    // ---- input projection (N=64 -> BM=64 for 2x block count) ----
    gemm_mfma<true, true, false, 1><<<dim3(GM64, 1), 256, 0, stream>>>(
        xb, wiT, b_in, h0b, nullptr, nullptr, nullptr, nullptr, 0, NN, 256, 64);

    // ---- GAT layer 0 (heads=4, concat); es/ed fused in GEMM epilogue ----
    gemm_mfma<false, false, true, 2><<<dim3(GM128, 4), 256, 0, stream>>>(
        h0b, w0T, nullptr, xl_bf, as0, ad0, es, ed, 4, NN, 64, 256);
    k_agg4<true><<<(NN + 3) / 4, 256, 0, stream>>>(xl_bf, es, ed, row_ptr, csr, bb0, hb_bf);

    // ---- GAT layer 1 (heads=4, concat) ----
    gemm_mfma<false, false, true, 2><<<dim3(GM128, 4), 256, 0, stream>>>(
        hb_bf, w1T, nullptr, xl_bf, as1, ad1, es, ed, 4, NN, 256, 256);
    k_agg4<true><<<(NN + 3) / 4, 256, 0, stream>>>(xl_bf, es, ed, row_ptr, csr, bb1, hb_bf);

    // ---- GAT layer 2 (heads=1, N=64 -> BM=64) + partial mean-pool ----
    gemm_mfma<false, false, true, 1><<<dim3(GM64, 1), 256, 0, stream>>>(
        hb_bf, w2T, nullptr, h2_bf, as2, ad2, es, ed, 1, NN, 256, 64);
    k_agg1<<<NAGG1, 256, 0, stream>>>(h2_bf, es, ed, row_ptr, csr, bb2, part);
    k_red <<<64, 256, 0, stream>>>(part, gsum);

    // ---- output projection ----
    k_final<<<1, 128, 0, stream>>>(gsum, w_out, b_out, out);
}

// Round 8
// 468.835 us; speedup vs baseline: 1.8852x; 1.0139x over previous
//
#include <hip/hip_runtime.h>

#define NN 50000
#define NE 800000
#define ET 850000   // NE + NN self-loops
#define NBLK 196    // ceil(NN/256) for the parallel scan
#define NAGG1 3125  // k_agg1 grid (= NN/16), also rows of `part`
#define MEGA_CAST 12500          // castx blocks: NN*256 elems / 4 per float4 / 256 thr
#define MEGA_GRID (12500 + 448)  // + weight-prep blocks (114688/256)

typedef unsigned short ushort_t;
typedef unsigned int uint_t;
typedef __attribute__((ext_vector_type(8))) short short8;
typedef __attribute__((ext_vector_type(4))) float f32x4;

// ---------------------------------------------------------------- utilities
__device__ __forceinline__ float elu1(float x) {
    return x > 0.f ? x : (__expf(x) - 1.f);
}
__device__ __forceinline__ float bf2f(ushort_t u) {
    return __uint_as_float(((uint_t)u) << 16);
}
__device__ __forceinline__ ushort_t f2bf(float f) {   // round-to-nearest-even
    uint_t u = __float_as_uint(f);
    u += 0x7FFFu + ((u >> 16) & 1u);
    return (ushort_t)(u >> 16);
}
__device__ __forceinline__ void gl_lds16(const ushort_t* g, ushort_t* l) {
    // async global->LDS, 16B/lane; LDS dest = wave-uniform base + lane*16
    __builtin_amdgcn_global_load_lds((const __attribute__((address_space(1))) void*)g,
                                     (__attribute__((address_space(3))) void*)l,
                                     16, 0, 0);
}
// bf16 pair (packed in a dword) -> two fp32, exact (bf16 = truncated fp32)
#define ACC2(q, w) do { \
    a0 += (w) * __uint_as_float((q).x << 16); \
    a1 += (w) * __uint_as_float((q).x & 0xFFFF0000u); \
    a2 += (w) * __uint_as_float((q).y << 16); \
    a3 += (w) * __uint_as_float((q).y & 0xFFFF0000u); } while (0)

// ---------------------------------------------------------------- CSR build
__global__ void k_hist(const int* __restrict__ dst, int* __restrict__ cursor) {
    int e = blockIdx.x * blockDim.x + threadIdx.x;
    if (e < NE) atomicAdd(&cursor[dst[e]], 1);
}

// parallel exclusive scan: scan1 (block-local) -> scan2 (block sums) -> scan3 (add)
__global__ void k_scan1(const int* __restrict__ cnt, int* __restrict__ excl,
                        int* __restrict__ bsum) {
    __shared__ int wsum[4];
    int t = threadIdx.x, lane = t & 63, w = t >> 6;
    int i = blockIdx.x * 256 + t;
    int v = (i < NN) ? cnt[i] : 0;
    int x = v;
    #pragma unroll
    for (int o = 1; o < 64; o <<= 1) {
        int y = __shfl_up(x, o, 64);
        if (lane >= o) x += y;
    }
    if (lane == 63) wsum[w] = x;
    __syncthreads();
    int wo = 0;
    #pragma unroll
    for (int k = 0; k < 4; k++) wo += (k < w) ? wsum[k] : 0;
    if (i < NN) excl[i] = x - v + wo;
    if (t == 255) bsum[blockIdx.x] = wo + x;     // block total
}

__global__ void k_scan2(int* __restrict__ bsum) {   // 1 block, 256 threads
    __shared__ int wsum[4];
    int t = threadIdx.x, lane = t & 63, w = t >> 6;
    int v = (t < NBLK) ? bsum[t] : 0;
    int x = v;
    #pragma unroll
    for (int o = 1; o < 64; o <<= 1) {
        int y = __shfl_up(x, o, 64);
        if (lane >= o) x += y;
    }
    if (lane == 63) wsum[w] = x;
    __syncthreads();
    int wo = 0;
    #pragma unroll
    for (int k = 0; k < 4; k++) wo += (k < w) ? wsum[k] : 0;
    if (t < NBLK) bsum[t] = x - v + wo;          // exclusive
}

__global__ void k_scan3(int* __restrict__ row_ptr, const int* __restrict__ bsum,
                        int* __restrict__ cursor) {
    int i = blockIdx.x * 256 + threadIdx.x;
    if (i < NN) {
        int r = row_ptr[i] + bsum[blockIdx.x];
        row_ptr[i] = r;
        cursor[i] = r;
    }
    if (i == 0) row_ptr[NN] = ET;
}

__global__ void k_scatter(const int* __restrict__ ei, int* __restrict__ cursor,
                          int* __restrict__ csr) {
    int e = blockIdx.x * blockDim.x + threadIdx.x;
    if (e >= ET) return;
    int s, d;
    if (e < NE) { s = ei[e]; d = ei[NE + e]; }
    else        { s = d = e - NE; }
    int pos = atomicAdd(&cursor[d], 1);
    csr[pos] = s;
}

// ---------------------------------------------------------------- mega prep
// blocks [0,12500): x fp32->bf16 (+ cursor=1 init, gsum=0 init)
// blocks [12500,12948): weight split-transposes with COLUMN PERMUTATION:
//   within each 64-col group, col j lands at row (j&3)*16 + (j>>2) of Bt, so
//   GEMM frag-block nt slot l16 holds global col l16*4+nt -> lanes own 4
//   consecutive output cols (ushort4 stores, float4 bias/a_s loads).
__global__ void k_mega(const float4* __restrict__ x, ushort4* __restrict__ xb,
                       const float* __restrict__ w_in, const float* __restrict__ W0,
                       const float* __restrict__ W1, const float* __restrict__ W2,
                       ushort_t* __restrict__ wiT, ushort_t* __restrict__ w0T,
                       ushort_t* __restrict__ w1T, ushort_t* __restrict__ w2T,
                       int* __restrict__ cursor, float* __restrict__ gsum) {
    int b = blockIdx.x, t = threadIdx.x;
    if (b < MEGA_CAST) {
        int i = b * 256 + t;                      // < NN*64 = 3,200,000 float4s
        float4 v = x[i];
        ushort4 o;
        o.x = f2bf(v.x); o.y = f2bf(v.y); o.z = f2bf(v.z); o.w = f2bf(v.w);
        xb[i] = o;
        if (b < NBLK) {
            int j = b * 256 + t;
            if (j < NN) cursor[j] = 1;            // pre-count self-loop
        }
        if (b == 0 && t < 64) gsum[t] = 0.f;
    } else {
        int i = (b - MEGA_CAST) * 256 + t;        // 0..114687
        const float* W; ushort_t* Bt; int K, N, j;
        if (i < 16384)       { W = w_in; Bt = wiT; K = 256; N = 64;  j = i; }
        else if (i < 32768)  { W = W0;   Bt = w0T; K = 64;  N = 256; j = i - 16384; }
        else if (i < 98304)  { W = W1;   Bt = w1T; K = 256; N = 256; j = i - 32768; }
        else                 { W = W2;   Bt = w2T; K = 256; N = 64;  j = i - 98304; }
        int k = j / N, n = j % N;
        int jj = n & 63;
        int rp = (n & ~63) | ((jj & 3) << 4) | (jj >> 2);   // permuted row
        float v = W[j];
        ushort_t h = f2bf(v);
        Bt[(size_t)rp * 2 * K + k] = h;
        Bt[(size_t)rp * 2 * K + K + k] = f2bf(v - bf2f(h));
    }
}

// ---------------------------------------------------------------- MFMA GEMM
// C[M x N](bf16) = A[M x K](bf16) @ (Bh + Bl), split-bf16 weights.
// BM=64*MT, BN=16*NT (NT=4 for N=64 GEMMs; NT=8 for N=256 -> halves A refetch).
// 256 thr (4 waves), mfma 16x16x32. Weight cols permuted (see k_mega) so each
// lane's NT acc values are 4 consecutive cols per 64-col group.
// EDOT: head = blockIdx.y*(NT/4)+hg; es/ed via per-16-lane butterfly.
template<bool ELU, bool BIAS, bool EDOT, int MT, int NT>
__global__ __launch_bounds__(256) void gemm_mfma(const ushort_t* __restrict__ A,
                                                 const ushort_t* __restrict__ Bt,
                                                 const float* __restrict__ bias,
                                                 ushort_t* __restrict__ C,
                                                 const float* __restrict__ a_s,
                                                 const float* __restrict__ a_d,
                                                 float* __restrict__ es,
                                                 float* __restrict__ ed,
                                                 int esStride,
                                                 int M, int K, int N) {
    constexpr int HG = NT / 4;                    // 64-col groups per block
    constexpr int BOFF = MT * 4096;               // ushort offset of B region
    __shared__ __align__(16) ushort_t lds[MT * 4096 + NT * 2048];
    int tid = threadIdx.x;
    int wave = tid >> 6, lane = tid & 63;
    int quad = lane >> 4, l16 = lane & 15;
    int mb = blockIdx.x * (64 * MT), nb = blockIdx.y * (16 * NT);
    int K2 = 2 * K;

    f32x4 acc[MT][NT];
    #pragma unroll
    for (int mt = 0; mt < MT; mt++)
        #pragma unroll
        for (int nt = 0; nt < NT; nt++)
            acc[mt][nt] = (f32x4){0.f, 0.f, 0.f, 0.f};

    for (int k0 = 0; k0 < K; k0 += 64) {
        // ---- stage A: 4*MT frag-blocks over 4 waves ----
        #pragma unroll
        for (int c = 0; c < 2 * MT; c++) {
            int mt = (MT == 2) ? (wave * 2 + (c >> 1)) : wave;
            int ks = (MT == 2) ? (c & 1) : c;
            int row = mb + mt * 16 + l16;
            row = min(row, M - 1);
            int col = k0 + ks * 32 + quad * 8;
            gl_lds16(A + (size_t)row * K + col, &lds[(mt * 2 + ks) * 512]);
        }
        // ---- stage B: 4*NT frag-blocks (2 split x NT x 2 ks) over 4 waves ----
        #pragma unroll
        for (int c = 0; c < NT; c++) {
            int id = wave * NT + c;               // 0 .. 4*NT-1
            int ntile = id % NT;
            int ks = (id / NT) & 1;
            int split = id / (2 * NT);
            int n = nb + ntile * 16 + l16;
            int col = split * K + k0 + ks * 32 + quad * 8;
            gl_lds16(Bt + (size_t)n * K2 + col,
                     &lds[BOFF + ((split * NT + ntile) * 2 + ks) * 512]);
        }
        __syncthreads();
        #pragma unroll
        for (int ks = 0; ks < 2; ks++) {
            short8 af[MT];
            #pragma unroll
            for (int mt = 0; mt < MT; mt++)
                af[mt] = *(const short8*)&lds[((wave * MT + mt) * 2 + ks) * 512 + lane * 8];
            #pragma unroll
            for (int split = 0; split < 2; split++) {
                short8 bf[NT];
                #pragma unroll
                for (int nt = 0; nt < NT; nt++)
                    bf[nt] = *(const short8*)&lds[BOFF + ((split * NT + nt) * 2 + ks) * 512 + lane * 8];
                #pragma unroll
                for (int mt = 0; mt < MT; mt++)
                    #pragma unroll
                    for (int nt = 0; nt < NT; nt++)
                        acc[mt][nt] = __builtin_amdgcn_mfma_f32_16x16x32_bf16(
                            af[mt], bf[nt], acc[mt][nt], 0, 0, 0);
            }
        }
        __syncthreads();
    }
    // ---- epilogue: C/D layout col(frag)=l16, row=quad*4+reg; permuted cols
    //      mean frag nt slot l16 = global col l16*4 + (nt%4) of group nt/4 ----
    float4 as4[HG], ad4[HG], b4[HG];
    #pragma unroll
    for (int hg = 0; hg < HG; hg++) {
        int cbase = nb + hg * 64 + l16 * 4;
        if (EDOT) {
            as4[hg] = *(const float4*)(a_s + (size_t)(blockIdx.y * HG + hg) * 64 + l16 * 4);
            ad4[hg] = *(const float4*)(a_d + (size_t)(blockIdx.y * HG + hg) * 64 + l16 * 4);
        }
        if (BIAS) b4[hg] = *(const float4*)(bias + cbase);
    }
    #pragma unroll
    for (int mt = 0; mt < MT; mt++) {
        int mrow = mb + (wave * MT + mt) * 16 + quad * 4;
        #pragma unroll
        for (int r = 0; r < 4; r++) {
            int m = mrow + r;
            bool mv = m < M;
            #pragma unroll
            for (int hg = 0; hg < HG; hg++) {
                float v0 = acc[mt][hg * 4 + 0][r];
                float v1 = acc[mt][hg * 4 + 1][r];
                float v2 = acc[mt][hg * 4 + 2][r];
                float v3 = acc[mt][hg * 4 + 3][r];
                if constexpr (EDOT) {
                    float ps = v0 * as4[hg].x + v1 * as4[hg].y + v2 * as4[hg].z + v3 * as4[hg].w;
                    float pd = v0 * ad4[hg].x + v1 * ad4[hg].y + v2 * ad4[hg].z + v3 * ad4[hg].w;
                    #pragma unroll
                    for (int o = 8; o >= 1; o >>= 1) {
                        ps += __shfl_xor(ps, o, 64);
                        pd += __shfl_xor(pd, o, 64);
                    }
                    if (l16 == 0 && mv) {
                        int head = blockIdx.y * HG + hg;
                        es[(size_t)m * esStride + head] = ps;
                        ed[(size_t)m * esStride + head] = pd;
                    }
                }
                if (mv) {
                    if (BIAS) { v0 += b4[hg].x; v1 += b4[hg].y; v2 += b4[hg].z; v3 += b4[hg].w; }
                    if (ELU) { v0 = elu1(v0); v1 = elu1(v1); v2 = elu1(v2); v3 = elu1(v3); }
                    ushort4 o;
                    o.x = f2bf(v0); o.y = f2bf(v1); o.z = f2bf(v2); o.w = f2bf(v3);
                    *(ushort4*)&C[(size_t)m * N + nb + hg * 64 + l16 * 4] = o;
                }
            }
        }
    }
}

// ------------------------------------------------- softmax aggregate, 4 heads
// 1 wave per node. Fast path (deg<=64): single chunk keeps leaky logits in
// registers. Gather unrolled x4 (R7: x8 raised VGPR 24->36, occupancy 70->65%,
// dur 66->71 -- reverted).
template<bool BFOUT>
__global__ __launch_bounds__(256) void k_agg4(const ushort_t* __restrict__ xl,
                                              const float* __restrict__ es,
                                              const float* __restrict__ ed,
                                              const int* __restrict__ row_ptr,
                                              const int* __restrict__ csr,
                                              const float* __restrict__ bias,
                                              void* __restrict__ outv) {
    __shared__ float wlds[4][256];
    int lane = threadIdx.x & 63, wave = threadIdx.x >> 6;
    int node = blockIdx.x * 4 + wave;
    if (node >= NN) return;
    int head = lane >> 4;
    int start = row_ptr[node], end = row_ptr[node + 1];
    int deg = end - start;
    float4 edv = *(const float4*)(ed + (size_t)node * 4);
    float edh[4] = {edv.x, edv.y, edv.z, edv.w};
    float a0 = 0.f, a1 = 0.f, a2 = 0.f, a3 = 0.f;
    const uint_t* xb = (const uint_t*)xl;

    if (deg <= 64) {
        // ---- fused single-chunk softmax ----
        int i = start + lane;
        bool valid = i < end;
        int idx = csr[valid ? i : start];
        float4 ev = *(const float4*)(es + (size_t)idx * 4);
        float e[4] = {ev.x, ev.y, ev.z, ev.w};
        #pragma unroll
        for (int h = 0; h < 4; h++) {
            float v = e[h] + edh[h];
            v = v > 0.f ? v : 0.2f * v;
            e[h] = valid ? v : -1e30f;
        }
        float cm[4];
        #pragma unroll
        for (int h = 0; h < 4; h++) cm[h] = e[h];
        #pragma unroll
        for (int o = 32; o >= 1; o >>= 1)
            #pragma unroll
            for (int h = 0; h < 4; h++) cm[h] = fmaxf(cm[h], __shfl_xor(cm[h], o, 64));
        float cs[4];
        #pragma unroll
        for (int h = 0; h < 4; h++) cs[h] = valid ? __expf(e[h] - cm[h]) : 0.f;
        #pragma unroll
        for (int o = 32; o >= 1; o >>= 1)
            #pragma unroll
            for (int h = 0; h < 4; h++) cs[h] += __shfl_xor(cs[h], o, 64);
        float4 wv;
        wv.x = valid ? __expf(e[0] - cm[0]) / cs[0] : 0.f;
        wv.y = valid ? __expf(e[1] - cm[1]) / cs[1] : 0.f;
        wv.z = valid ? __expf(e[2] - cm[2]) / cs[2] : 0.f;
        wv.w = valid ? __expf(e[3] - cm[3]) / cs[3] : 0.f;
        *(float4*)&wlds[wave][lane * 4] = wv;
        // ---- gather, unrolled x4 ----
        int t = 0;
        for (; t + 4 <= deg; t += 4) {
            int s0 = __shfl(idx, t + 0, 64), s1 = __shfl(idx, t + 1, 64);
            int s2 = __shfl(idx, t + 2, 64), s3 = __shfl(idx, t + 3, 64);
            uint2 q0 = *(const uint2*)(xb + (size_t)s0 * 128 + lane * 2);
            uint2 q1 = *(const uint2*)(xb + (size_t)s1 * 128 + lane * 2);
            uint2 q2 = *(const uint2*)(xb + (size_t)s2 * 128 + lane * 2);
            uint2 q3 = *(const uint2*)(xb + (size_t)s3 * 128 + lane * 2);
            float w0 = wlds[wave][(t + 0) * 4 + head], w1 = wlds[wave][(t + 1) * 4 + head];
            float w2 = wlds[wave][(t + 2) * 4 + head], w3 = wlds[wave][(t + 3) * 4 + head];
            ACC2(q0, w0); ACC2(q1, w1); ACC2(q2, w2); ACC2(q3, w3);
        }
        for (; t < deg; ++t) {
            int s0 = __shfl(idx, t, 64);
            uint2 q0 = *(const uint2*)(xb + (size_t)s0 * 128 + lane * 2);
            float w0 = wlds[wave][t * 4 + head];
            ACC2(q0, w0);
        }
    } else {
        // ---- general two-pass path (deg > 64, essentially never) ----
        float m[4], ssum[4];
        #pragma unroll
        for (int h = 0; h < 4; h++) { m[h] = -1e30f; ssum[h] = 0.f; }
        for (int base = start; base < end; base += 64) {
            int i = base + lane;
            bool valid = i < end;
            int idx = csr[valid ? i : start];
            float4 ev = *(const float4*)(es + (size_t)idx * 4);
            float e[4] = {ev.x, ev.y, ev.z, ev.w};
            #pragma unroll
            for (int h = 0; h < 4; h++) {
                float v = e[h] + edh[h];
                v = v > 0.f ? v : 0.2f * v;
                e[h] = valid ? v : -1e30f;
            }
            float cm[4];
            #pragma unroll
            for (int h = 0; h < 4; h++) cm[h] = e[h];
            #pragma unroll
            for (int o = 32; o >= 1; o >>= 1)
                #pragma unroll
                for (int h = 0; h < 4; h++) cm[h] = fmaxf(cm[h], __shfl_xor(cm[h], o, 64));
            float cs[4];
            #pragma unroll
            for (int h = 0; h < 4; h++) cs[h] = valid ? __expf(e[h] - cm[h]) : 0.f;
            #pragma unroll
            for (int o = 32; o >= 1; o >>= 1)
                #pragma unroll
                for (int h = 0; h < 4; h++) cs[h] += __shfl_xor(cs[h], o, 64);
            #pragma unroll
            for (int h = 0; h < 4; h++) {
                float mn = fmaxf(m[h], cm[h]);
                ssum[h] = ssum[h] * __expf(m[h] - mn) + cs[h] * __expf(cm[h] - mn);
                m[h] = mn;
            }
        }
        float inv[4];
        #pragma unroll
        for (int h = 0; h < 4; h++) inv[h] = 1.f / ssum[h];
        for (int base = start; base < end; base += 64) {
            int i = base + lane;
            bool valid = i < end;
            int idx = csr[valid ? i : start];
            int cnt = min(64, end - base);
            float4 ev = *(const float4*)(es + (size_t)idx * 4);
            float e[4] = {ev.x, ev.y, ev.z, ev.w};
            #pragma unroll
            for (int h = 0; h < 4; h++) {
                float v = e[h] + edh[h];
                v = v > 0.f ? v : 0.2f * v;
                e[h] = valid ? __expf(v - m[h]) * inv[h] : 0.f;
            }
            float4 wv; wv.x = e[0]; wv.y = e[1]; wv.z = e[2]; wv.w = e[3];
            *(float4*)&wlds[wave][lane * 4] = wv;
            for (int t = 0; t < cnt; ++t) {
                int s = __shfl(idx, t, 64);
                float w = wlds[wave][t * 4 + head];
                uint2 q = *(const uint2*)(xb + (size_t)s * 128 + lane * 2);
                ACC2(q, w);
            }
        }
    }

    float o0 = elu1(a0 + bias[lane * 4 + 0]);
    float o1 = elu1(a1 + bias[lane * 4 + 1]);
    float o2 = elu1(a2 + bias[lane * 4 + 2]);
    float o3 = elu1(a3 + bias[lane * 4 + 3]);
    if constexpr (BFOUT) {
        ushort4 o; o.x = f2bf(o0); o.y = f2bf(o1); o.z = f2bf(o2); o.w = f2bf(o3);
        *(ushort4*)((ushort_t*)outv + (size_t)node * 256 + lane * 4) = o;
    } else {
        float4 o; o.x = o0; o.y = o1; o.z = o2; o.w = o3;
        *(float4*)((float*)outv + (size_t)node * 256 + lane * 4) = o;
    }
}

// ------------------------------------------------- softmax aggregate, 1 head
// 4 nodes per wave (16-lane groups); partial mean-pool stored per block
// (no atomics — R4: 200k same-line atomics serialized at the coherent point).
__global__ __launch_bounds__(256) void k_agg1(const ushort_t* __restrict__ xl,
                                              const float* __restrict__ es,
                                              const float* __restrict__ ed,
                                              const int* __restrict__ row_ptr,
                                              const int* __restrict__ csr,
                                              const float* __restrict__ bias,
                                              float* __restrict__ part) {
    __shared__ float wlds[4][64];
    __shared__ float ps[4][64];
    int lane = threadIdx.x & 63, wave = threadIdx.x >> 6;
    int g = lane >> 4, l16 = lane & 15;
    int node = blockIdx.x * 16 + wave * 4 + g;
    bool vn = node < NN;
    int start = vn ? row_ptr[node] : 0;
    int end   = vn ? row_ptr[node + 1] : 0;
    float edl = vn ? ed[node] : 0.f;

    // ---- pass 1: softmax stats, 16 edges/chunk per group ----
    float m = -1e30f, ssum = 0.f;
    for (int base = start; base < end; base += 16) {
        int i = base + l16;
        bool valid = i < end;
        int idx = csr[valid ? i : start];
        float e = es[idx] + edl;
        e = e > 0.f ? e : 0.2f * e;
        e = valid ? e : -1e30f;
        float cm = e;
        #pragma unroll
        for (int o = 8; o >= 1; o >>= 1) cm = fmaxf(cm, __shfl_xor(cm, o, 64));
        float cs = valid ? __expf(e - cm) : 0.f;
        #pragma unroll
        for (int o = 8; o >= 1; o >>= 1) cs += __shfl_xor(cs, o, 64);
        float mn = fmaxf(m, cm);
        ssum = ssum * __expf(m - mn) + cs * __expf(cm - mn);
        m = mn;
    }
    float inv = 1.f / ssum;

    // ---- pass 2: weights -> LDS, gather unrolled x4 ----
    float a0 = 0.f, a1 = 0.f, a2 = 0.f, a3 = 0.f;
    const uint_t* xb = (const uint_t*)xl;
    for (int base = start; base < end; base += 16) {
        int i = base + l16;
        bool valid = i < end;
        int idx = csr[valid ? i : start];
        int cnt = min(16, end - base);
        float e = es[idx] + edl;
        e = e > 0.f ? e : 0.2f * e;
        wlds[wave][g * 16 + l16] = valid ? __expf(e - m) * inv : 0.f;
        int t = 0;
        for (; t + 4 <= cnt; t += 4) {
            int s0 = __shfl(idx, g * 16 + t + 0, 64), s1 = __shfl(idx, g * 16 + t + 1, 64);
            int s2 = __shfl(idx, g * 16 + t + 2, 64), s3 = __shfl(idx, g * 16 + t + 3, 64);
            uint2 q0 = *(const uint2*)(xb + (size_t)s0 * 32 + l16 * 2);
            uint2 q1 = *(const uint2*)(xb + (size_t)s1 * 32 + l16 * 2);
            uint2 q2 = *(const uint2*)(xb + (size_t)s2 * 32 + l16 * 2);
            uint2 q3 = *(const uint2*)(xb + (size_t)s3 * 32 + l16 * 2);
            float w0 = wlds[wave][g * 16 + t + 0], w1 = wlds[wave][g * 16 + t + 1];
            float w2 = wlds[wave][g * 16 + t + 2], w3 = wlds[wave][g * 16 + t + 3];
            ACC2(q0, w0); ACC2(q1, w1); ACC2(q2, w2); ACC2(q3, w3);
        }
        for (; t < cnt; ++t) {
            int s = __shfl(idx, g * 16 + t, 64);
            float w = wlds[wave][g * 16 + t];
            uint2 q = *(const uint2*)(xb + (size_t)s * 32 + l16 * 2);
            ACC2(q, w);
        }
    }

    // ---- block-level partial mean-pool (non-atomic store) ----
    float o[4];
    o[0] = vn ? elu1(a0 + bias[l16 * 4 + 0]) : 0.f;
    o[1] = vn ? elu1(a1 + bias[l16 * 4 + 1]) : 0.f;
    o[2] = vn ? elu1(a2 + bias[l16 * 4 + 2]) : 0.f;
    o[3] = vn ? elu1(a3 + bias[l16 * 4 + 3]) : 0.f;
    #pragma unroll
    for (int j = 0; j < 4; j++) {
        o[j] += __shfl_xor(o[j], 16, 64);
        o[j] += __shfl_xor(o[j], 32, 64);
    }
    if (lane < 16) {
        float4 v; v.x = o[0]; v.y = o[1]; v.z = o[2]; v.w = o[3];
        *(float4*)&ps[wave][l16 * 4] = v;
    }
    __syncthreads();
    int tid = threadIdx.x;
    if (tid < 64) {
        float tot = ps[0][tid] + ps[1][tid] + ps[2][tid] + ps[3][tid];
        part[(size_t)blockIdx.x * 64 + tid] = tot;
    }
}

// ---- reduce part[NAGG1][64] -> gsum[64] (few blocks => few atomics) ----
__global__ void k_red(const float* __restrict__ part, float* __restrict__ gsum) {
    __shared__ float sm[4][64];
    int t = threadIdx.x, c = t & 63, w = t >> 6;
    float s = 0.f;
    for (int r = blockIdx.x * 4 + w; r < NAGG1; r += gridDim.x * 4)
        s += part[(size_t)r * 64 + c];
    sm[w][c] = s;
    __syncthreads();
    if (w == 0) {
        float tot = sm[0][c] + sm[1][c] + sm[2][c] + sm[3][c];
        atomicAdd(&gsum[c], tot);
    }
}

// ---------------------------------------------------------------- final
__global__ void k_final(const float* __restrict__ gsum, const float* __restrict__ w_out,
                        const float* __restrict__ b_out, float* __restrict__ out) {
    int j = threadIdx.x;   // 128
    float s = b_out[j];
    const float invn = 1.f / (float)NN;
    #pragma unroll 8
    for (int k = 0; k < 64; k++)
        s += (gsum[k] * invn) * w_out[k * 128 + j];
    out[j] = s;
}

// ---------------------------------------------------------------- launcher
extern "C" void kernel_launch(void* const* d_in, const int* in_sizes, int n_in,
                              void* d_out, int out_size, void* d_ws, size_t ws_size,
                              hipStream_t stream) {
    const float* x    = (const float*)d_in[0];
    const int*   ei   = (const int*)d_in[1];
    const float* w_in = (const float*)d_in[2];
    const float* b_in = (const float*)d_in[3];
    const float* W0   = (const float*)d_in[4];
    const float* as0  = (const float*)d_in[5];
    const float* ad0  = (const float*)d_in[6];
    const float* bb0  = (const float*)d_in[7];
    const float* W1   = (const float*)d_in[8];
    const float* as1  = (const float*)d_in[9];
    const float* ad1  = (const float*)d_in[10];
    const float* bb1  = (const float*)d_in[11];
    const float* W2   = (const float*)d_in[12];
    const float* as2  = (const float*)d_in[13];
    const float* ad2  = (const float*)d_in[14];
    const float* bb2  = (const float*)d_in[15];
    const float* w_out= (const float*)d_in[16];
    const float* b_out= (const float*)d_in[17];
    float* out = (float*)d_out;

    char* p = (char*)d_ws;
    size_t off = 0;
    auto take = [&](size_t bytes) {
        char* r = p + off;
        off = (off + bytes + 255) & ~(size_t)255;
        return r;
    };
    ushort_t* xb     = (ushort_t*)take((size_t)NN * 256 * 2); // 25.6 MB
    ushort_t* h0b    = (ushort_t*)take((size_t)NN * 64 * 2);  //  6.4 MB
    ushort_t* xl_bf  = (ushort_t*)take((size_t)NN * 256 * 2); // 25.6 MB
    ushort_t* hb_bf  = (ushort_t*)take((size_t)NN * 256 * 2); // 25.6 MB
    ushort_t* h2_bf  = (ushort_t*)take((size_t)NN * 64 * 2);  //  6.4 MB
    ushort_t* wiT    = (ushort_t*)take((size_t)64 * 512 * 2);
    ushort_t* w0T    = (ushort_t*)take((size_t)256 * 128 * 2);
    ushort_t* w1T    = (ushort_t*)take((size_t)256 * 512 * 2);
    ushort_t* w2T    = (ushort_t*)take((size_t)64 * 512 * 2);
    float*    es     = (float*)take((size_t)NN * 4 * 4);
    float*    ed     = (float*)take((size_t)NN * 4 * 4);
    int*      row_ptr= (int*)take((size_t)(NN + 1) * 4);
    int*      cursor = (int*)take((size_t)NN * 4);
    int*      csr    = (int*)take((size_t)ET * 4);
    int*      bsum   = (int*)take((size_t)NBLK * 4);
    float*    part   = (float*)take((size_t)NAGG1 * 64 * 4);  // 0.8 MB
    float*    gsum   = (float*)take(64 * 4);

    // ---- mega prep: cursor/gsum init + x cast + weight split-transpose ----
    k_mega<<<MEGA_GRID, 256, 0, stream>>>((const float4*)x, (ushort4*)xb,
                                          w_in, W0, W1, W2, wiT, w0T, w1T, w2T,
                                          cursor, gsum);

    // ---- CSR build (by dst, with self-loops) ----
    k_hist   <<<(NE + 255) / 256, 256, 0, stream>>>(ei + NE, cursor);
    k_scan1  <<<NBLK, 256, 0, stream>>>(cursor, row_ptr, bsum);
    k_scan2  <<<1, 256, 0, stream>>>(bsum);
    k_scan3  <<<NBLK, 256, 0, stream>>>(row_ptr, bsum, cursor);
    k_scatter<<<(ET + 255) / 256, 256, 0, stream>>>(ei, cursor, csr);

    const int GM128 = (NN + 127) / 128;   // 391
    const int GM64  = (NN + 63) / 64;     // 782

    // ---- input projection (N=64 -> BM=64, NT=4) ----
    gemm_mfma<true, true, false, 1, 4><<<dim3(GM64, 1), 256, 0, stream>>>(
        xb, wiT, b_in, h0b, nullptr, nullptr, nullptr, nullptr, 0, NN, 256, 64);

    // ---- GAT layer 0 (heads=4, concat); BN=128, es/ed fused in epilogue ----
    gemm_mfma<false, false, true, 2, 8><<<dim3(GM128, 2), 256, 0, stream>>>(
        h0b, w0T, nullptr, xl_bf, as0, ad0, es, ed, 4, NN, 64, 256);
    k_agg4<true><<<(NN + 3) / 4, 256, 0, stream>>>(xl_bf, es, ed, row_ptr, csr, bb0, hb_bf);

    // ---- GAT layer 1 (heads=4, concat); BN=128 ----
    gemm_mfma<false, false, true, 2, 8><<<dim3(GM128, 2), 256, 0, stream>>>(
        hb_bf, w1T, nullptr, xl_bf, as1, ad1, es, ed, 4, NN, 256, 256);
    k_agg4<true><<<(NN + 3) / 4, 256, 0, stream>>>(xl_bf, es, ed, row_ptr, csr, bb1, hb_bf);

    // ---- GAT layer 2 (heads=1, N=64 -> BM=64, NT=4) + partial mean-pool ----
    gemm_mfma<false, false, true, 1, 4><<<dim3(GM64, 1), 256, 0, stream>>>(
        hb_bf, w2T, nullptr, h2_bf, as2, ad2, es, ed, 1, NN, 256, 64);
    k_agg1<<<NAGG1, 256, 0, stream>>>(h2_bf, es, ed, row_ptr, csr, bb2, part);
    k_red <<<64, 256, 0, stream>>>(part, gsum);

    // ---- output projection ----
    k_final<<<1, 128, 0, stream>>>(gsum, w_out, b_out, out);
}

// Round 9
// 463.870 us; speedup vs baseline: 1.9053x; 1.0107x over previous
//
#include <hip/hip_runtime.h>

#define NN 50000
#define NE 800000
#define ET 850000   // NE + NN self-loops
#define NBLK 196    // ceil(NN/256) for the parallel scan
#define NAGG1 3125  // k_agg1 grid (= NN/16), also rows of `part`
#define MEGA_CAST 12500                 // castx blocks: NN*256/4/256
#define MEGA_W    448                   // weight-prep blocks (114688/256)
#define MEGA_HIST 3125                  // hist blocks (NE/256)
#define MEGA_GRID (MEGA_CAST + MEGA_W + MEGA_HIST)
#define GM64 782                        // (NN+63)/64
#define GSCAT 3321                      // (ET+255)/256

typedef unsigned short ushort_t;
typedef unsigned int uint_t;
typedef __attribute__((ext_vector_type(8))) short short8;
typedef __attribute__((ext_vector_type(4))) float f32x4;

// ---------------------------------------------------------------- utilities
__device__ __forceinline__ float elu1(float x) {
    return x > 0.f ? x : (__expf(x) - 1.f);
}
__device__ __forceinline__ float bf2f(ushort_t u) {
    return __uint_as_float(((uint_t)u) << 16);
}
__device__ __forceinline__ ushort_t f2bf(float f) {   // round-to-nearest-even
    uint_t u = __float_as_uint(f);
    u += 0x7FFFu + ((u >> 16) & 1u);
    return (ushort_t)(u >> 16);
}
__device__ __forceinline__ void gl_lds16(const ushort_t* g, ushort_t* l) {
    // async global->LDS, 16B/lane; LDS dest = wave-uniform base + lane*16
    __builtin_amdgcn_global_load_lds((const __attribute__((address_space(1))) void*)g,
                                     (__attribute__((address_space(3))) void*)l,
                                     16, 0, 0);
}
// bf16 pair (packed in a dword) -> two fp32, exact (bf16 = truncated fp32)
#define ACC2(q, w) do { \
    a0 += (w) * __uint_as_float((q).x << 16); \
    a1 += (w) * __uint_as_float((q).x & 0xFFFF0000u); \
    a2 += (w) * __uint_as_float((q).y << 16); \
    a3 += (w) * __uint_as_float((q).y & 0xFFFF0000u); } while (0)

// ---------------------------------------------------------------- mega prep
// blocks [0,12500): x fp32->bf16 (+ gsum=0 init in block 0)
// blocks [12500,12948): weight split-transposes with column permutation:
//   within each 64-col group, col j -> row (j&3)*16 + (j>>2): GEMM frag nt
//   slot l16 = global col l16*4+nt -> lanes own 4 consecutive output cols.
// blocks [12948,16073): dst-degree histogram (cursor pre-zeroed by memset;
//   the +1 self-loop is folded into k_scan1).
__global__ void k_mega(const float4* __restrict__ x, ushort4* __restrict__ xb,
                       const float* __restrict__ w_in, const float* __restrict__ W0,
                       const float* __restrict__ W1, const float* __restrict__ W2,
                       ushort_t* __restrict__ wiT, ushort_t* __restrict__ w0T,
                       ushort_t* __restrict__ w1T, ushort_t* __restrict__ w2T,
                       const int* __restrict__ dst, int* __restrict__ cursor,
                       float* __restrict__ gsum) {
    int b = blockIdx.x, t = threadIdx.x;
    if (b < MEGA_CAST) {
        int i = b * 256 + t;                      // < NN*64 = 3,200,000 float4s
        float4 v = x[i];
        ushort4 o;
        o.x = f2bf(v.x); o.y = f2bf(v.y); o.z = f2bf(v.z); o.w = f2bf(v.w);
        xb[i] = o;
        if (b == 0 && t < 64) gsum[t] = 0.f;
    } else if (b < MEGA_CAST + MEGA_W) {
        int i = (b - MEGA_CAST) * 256 + t;        // 0..114687
        const float* W; ushort_t* Bt; int K, N, j;
        if (i < 16384)       { W = w_in; Bt = wiT; K = 256; N = 64;  j = i; }
        else if (i < 32768)  { W = W0;   Bt = w0T; K = 64;  N = 256; j = i - 16384; }
        else if (i < 98304)  { W = W1;   Bt = w1T; K = 256; N = 256; j = i - 32768; }
        else                 { W = W2;   Bt = w2T; K = 256; N = 64;  j = i - 98304; }
        int k = j / N, n = j % N;
        int jj = n & 63;
        int rp = (n & ~63) | ((jj & 3) << 4) | (jj >> 2);   // permuted row
        float v = W[j];
        ushort_t h = f2bf(v);
        Bt[(size_t)rp * 2 * K + k] = h;
        Bt[(size_t)rp * 2 * K + K + k] = f2bf(v - bf2f(h));
    } else {
        int e = (b - MEGA_CAST - MEGA_W) * 256 + t;
        if (e < NE) atomicAdd(&cursor[dst[e]], 1);
    }
}

// ---------------------------------------------------------------- scan
// exclusive scan of (cnt[i]+1) -> row_ptr (the +1 is the self-loop)
__global__ void k_scan1(const int* __restrict__ cnt, int* __restrict__ excl,
                        int* __restrict__ bsum) {
    __shared__ int wsum[4];
    int t = threadIdx.x, lane = t & 63, w = t >> 6;
    int i = blockIdx.x * 256 + t;
    int v = (i < NN) ? cnt[i] + 1 : 0;
    int x = v;
    #pragma unroll
    for (int o = 1; o < 64; o <<= 1) {
        int y = __shfl_up(x, o, 64);
        if (lane >= o) x += y;
    }
    if (lane == 63) wsum[w] = x;
    __syncthreads();
    int wo = 0;
    #pragma unroll
    for (int k = 0; k < 4; k++) wo += (k < w) ? wsum[k] : 0;
    if (i < NN) excl[i] = x - v + wo;
    if (t == 255) bsum[blockIdx.x] = wo + x;     // block total
}

__global__ void k_scan2(int* __restrict__ bsum) {   // 1 block, 256 threads
    __shared__ int wsum[4];
    int t = threadIdx.x, lane = t & 63, w = t >> 6;
    int v = (t < NBLK) ? bsum[t] : 0;
    int x = v;
    #pragma unroll
    for (int o = 1; o < 64; o <<= 1) {
        int y = __shfl_up(x, o, 64);
        if (lane >= o) x += y;
    }
    if (lane == 63) wsum[w] = x;
    __syncthreads();
    int wo = 0;
    #pragma unroll
    for (int k = 0; k < 4; k++) wo += (k < w) ? wsum[k] : 0;
    if (t < NBLK) bsum[t] = x - v + wo;          // exclusive
}

__global__ void k_scan3(int* __restrict__ row_ptr, const int* __restrict__ bsum,
                        int* __restrict__ cursor) {
    int i = blockIdx.x * 256 + threadIdx.x;
    if (i < NN) {
        int r = row_ptr[i] + bsum[blockIdx.x];
        row_ptr[i] = r;
        cursor[i] = r;
    }
    if (i == 0) row_ptr[NN] = ET;
}

// ---------------------------------------------------------------- GEMM body
// C[M x N](bf16) = A[M x K](bf16) @ (Bh + Bl), split-bf16 weights.
// BM=64*MT, BN=16*NT (NT=8 for N=256 GEMMs -> halves A refetch). 256 thr.
// Weight cols permuted (see k_mega) -> ushort4 C stores, float4 bias loads.
// EDOT: head = by*(NT/4)+hg; es/ed via per-16-lane butterfly.
template<bool ELU, bool BIAS, bool EDOT, int MT, int NT>
__device__ __forceinline__ void gemm_body(const ushort_t* __restrict__ A,
                                          const ushort_t* __restrict__ Bt,
                                          const float* __restrict__ bias,
                                          ushort_t* __restrict__ C,
                                          const float* __restrict__ a_s,
                                          const float* __restrict__ a_d,
                                          float* __restrict__ es,
                                          float* __restrict__ ed,
                                          int esStride, int M, int K, int N,
                                          int bx, int by) {
    constexpr int HG = NT / 4;                    // 64-col groups per block
    constexpr int BOFF = MT * 4096;               // ushort offset of B region
    __shared__ __align__(16) ushort_t lds[MT * 4096 + NT * 2048];
    int tid = threadIdx.x;
    int wave = tid >> 6, lane = tid & 63;
    int quad = lane >> 4, l16 = lane & 15;
    int mb = bx * (64 * MT), nb = by * (16 * NT);
    int K2 = 2 * K;

    f32x4 acc[MT][NT];
    #pragma unroll
    for (int mt = 0; mt < MT; mt++)
        #pragma unroll
        for (int nt = 0; nt < NT; nt++)
            acc[mt][nt] = (f32x4){0.f, 0.f, 0.f, 0.f};

    for (int k0 = 0; k0 < K; k0 += 64) {
        #pragma unroll
        for (int c = 0; c < 2 * MT; c++) {
            int mt = (MT == 2) ? (wave * 2 + (c >> 1)) : wave;
            int ks = (MT == 2) ? (c & 1) : c;
            int row = mb + mt * 16 + l16;
            row = min(row, M - 1);
            int col = k0 + ks * 32 + quad * 8;
            gl_lds16(A + (size_t)row * K + col, &lds[(mt * 2 + ks) * 512]);
        }
        #pragma unroll
        for (int c = 0; c < NT; c++) {
            int id = wave * NT + c;               // 0 .. 4*NT-1
            int ntile = id % NT;
            int ks = (id / NT) & 1;
            int split = id / (2 * NT);
            int n = nb + ntile * 16 + l16;
            int col = split * K + k0 + ks * 32 + quad * 8;
            gl_lds16(Bt + (size_t)n * K2 + col,
                     &lds[BOFF + ((split * NT + ntile) * 2 + ks) * 512]);
        }
        __syncthreads();
        #pragma unroll
        for (int ks = 0; ks < 2; ks++) {
            short8 af[MT];
            #pragma unroll
            for (int mt = 0; mt < MT; mt++)
                af[mt] = *(const short8*)&lds[((wave * MT + mt) * 2 + ks) * 512 + lane * 8];
            #pragma unroll
            for (int split = 0; split < 2; split++) {
                short8 bf[NT];
                #pragma unroll
                for (int nt = 0; nt < NT; nt++)
                    bf[nt] = *(const short8*)&lds[BOFF + ((split * NT + nt) * 2 + ks) * 512 + lane * 8];
                #pragma unroll
                for (int mt = 0; mt < MT; mt++)
                    #pragma unroll
                    for (int nt = 0; nt < NT; nt++)
                        acc[mt][nt] = __builtin_amdgcn_mfma_f32_16x16x32_bf16(
                            af[mt], bf[nt], acc[mt][nt], 0, 0, 0);
            }
        }
        __syncthreads();
    }
    // ---- epilogue: frag nt slot l16 = global col l16*4 + (nt%4), group nt/4 ----
    float4 as4[HG], ad4[HG], b4[HG];
    #pragma unroll
    for (int hg = 0; hg < HG; hg++) {
        int cbase = nb + hg * 64 + l16 * 4;
        if (EDOT) {
            as4[hg] = *(const float4*)(a_s + (size_t)(by * HG + hg) * 64 + l16 * 4);
            ad4[hg] = *(const float4*)(a_d + (size_t)(by * HG + hg) * 64 + l16 * 4);
        }
        if (BIAS) b4[hg] = *(const float4*)(bias + cbase);
    }
    #pragma unroll
    for (int mt = 0; mt < MT; mt++) {
        int mrow = mb + (wave * MT + mt) * 16 + quad * 4;
        #pragma unroll
        for (int r = 0; r < 4; r++) {
            int m = mrow + r;
            bool mv = m < M;
            #pragma unroll
            for (int hg = 0; hg < HG; hg++) {
                float v0 = acc[mt][hg * 4 + 0][r];
                float v1 = acc[mt][hg * 4 + 1][r];
                float v2 = acc[mt][hg * 4 + 2][r];
                float v3 = acc[mt][hg * 4 + 3][r];
                if constexpr (EDOT) {
                    float ps = v0 * as4[hg].x + v1 * as4[hg].y + v2 * as4[hg].z + v3 * as4[hg].w;
                    float pd = v0 * ad4[hg].x + v1 * ad4[hg].y + v2 * ad4[hg].z + v3 * ad4[hg].w;
                    #pragma unroll
                    for (int o = 8; o >= 1; o >>= 1) {
                        ps += __shfl_xor(ps, o, 64);
                        pd += __shfl_xor(pd, o, 64);
                    }
                    if (l16 == 0 && mv) {
                        int head = by * HG + hg;
                        es[(size_t)m * esStride + head] = ps;
                        ed[(size_t)m * esStride + head] = pd;
                    }
                }
                if (mv) {
                    if (BIAS) { v0 += b4[hg].x; v1 += b4[hg].y; v2 += b4[hg].z; v3 += b4[hg].w; }
                    if (ELU) { v0 = elu1(v0); v1 = elu1(v1); v2 = elu1(v2); v3 = elu1(v3); }
                    ushort4 o;
                    o.x = f2bf(v0); o.y = f2bf(v1); o.z = f2bf(v2); o.w = f2bf(v3);
                    *(ushort4*)&C[(size_t)m * N + nb + hg * 64 + l16 * 4] = o;
                }
            }
        }
    }
}

template<bool ELU, bool BIAS, bool EDOT, int MT, int NT>
__global__ __launch_bounds__(256) void gemm_mfma(const ushort_t* __restrict__ A,
                                                 const ushort_t* __restrict__ Bt,
                                                 const float* __restrict__ bias,
                                                 ushort_t* __restrict__ C,
                                                 const float* __restrict__ a_s,
                                                 const float* __restrict__ a_d,
                                                 float* __restrict__ es,
                                                 float* __restrict__ ed,
                                                 int esStride, int M, int K, int N) {
    gemm_body<ELU, BIAS, EDOT, MT, NT>(A, Bt, bias, C, a_s, a_d, es, ed,
                                       esStride, M, K, N, blockIdx.x, blockIdx.y);
}

// ---- fused: CSR scatter (blocks [0,GSCAT)) + input-projection GEMM
//      (blocks [GSCAT, GSCAT+GM64)) — independent work, one launch so the
//      scatter's atomic latency hides under the GEMM.
__global__ __launch_bounds__(256) void k_scat_g1(const int* __restrict__ ei,
                                                 int* __restrict__ cursor,
                                                 int* __restrict__ csr,
                                                 const ushort_t* __restrict__ A,
                                                 const ushort_t* __restrict__ Bt,
                                                 const float* __restrict__ bias,
                                                 ushort_t* __restrict__ C) {
    if (blockIdx.x < GSCAT) {
        int e = blockIdx.x * 256 + threadIdx.x;
        if (e >= ET) return;
        int s, d;
        if (e < NE) { s = ei[e]; d = ei[NE + e]; }
        else        { s = d = e - NE; }
        int pos = atomicAdd(&cursor[d], 1);
        csr[pos] = s;
    } else {
        gemm_body<true, true, false, 1, 4>(A, Bt, bias, C, nullptr, nullptr,
                                           nullptr, nullptr, 0, NN, 256, 64,
                                           blockIdx.x - GSCAT, 0);
    }
}

// ------------------------------------------------- softmax aggregate, 4 heads
// 1 wave per node; fast path deg<=64; gather unrolled x4 (R7: x8 regressed via
// VGPR 24->36). Near fabric floor: 207 MB FETCH @ ~3.6 TB/s observed ceiling.
template<bool BFOUT>
__global__ __launch_bounds__(256) void k_agg4(const ushort_t* __restrict__ xl,
                                              const float* __restrict__ es,
                                              const float* __restrict__ ed,
                                              const int* __restrict__ row_ptr,
                                              const int* __restrict__ csr,
                                              const float* __restrict__ bias,
                                              void* __restrict__ outv) {
    __shared__ float wlds[4][256];
    int lane = threadIdx.x & 63, wave = threadIdx.x >> 6;
    int node = blockIdx.x * 4 + wave;
    if (node >= NN) return;
    int head = lane >> 4;
    int start = row_ptr[node], end = row_ptr[node + 1];
    int deg = end - start;
    float4 edv = *(const float4*)(ed + (size_t)node * 4);
    float edh[4] = {edv.x, edv.y, edv.z, edv.w};
    float a0 = 0.f, a1 = 0.f, a2 = 0.f, a3 = 0.f;
    const uint_t* xb = (const uint_t*)xl;

    if (deg <= 64) {
        int i = start + lane;
        bool valid = i < end;
        int idx = csr[valid ? i : start];
        float4 ev = *(const float4*)(es + (size_t)idx * 4);
        float e[4] = {ev.x, ev.y, ev.z, ev.w};
        #pragma unroll
        for (int h = 0; h < 4; h++) {
            float v = e[h] + edh[h];
            v = v > 0.f ? v : 0.2f * v;
            e[h] = valid ? v : -1e30f;
        }
        float cm[4];
        #pragma unroll
        for (int h = 0; h < 4; h++) cm[h] = e[h];
        #pragma unroll
        for (int o = 32; o >= 1; o >>= 1)
            #pragma unroll
            for (int h = 0; h < 4; h++) cm[h] = fmaxf(cm[h], __shfl_xor(cm[h], o, 64));
        float cs[4];
        #pragma unroll
        for (int h = 0; h < 4; h++) cs[h] = valid ? __expf(e[h] - cm[h]) : 0.f;
        #pragma unroll
        for (int o = 32; o >= 1; o >>= 1)
            #pragma unroll
            for (int h = 0; h < 4; h++) cs[h] += __shfl_xor(cs[h], o, 64);
        float4 wv;
        wv.x = valid ? __expf(e[0] - cm[0]) / cs[0] : 0.f;
        wv.y = valid ? __expf(e[1] - cm[1]) / cs[1] : 0.f;
        wv.z = valid ? __expf(e[2] - cm[2]) / cs[2] : 0.f;
        wv.w = valid ? __expf(e[3] - cm[3]) / cs[3] : 0.f;
        *(float4*)&wlds[wave][lane * 4] = wv;
        int t = 0;
        for (; t + 4 <= deg; t += 4) {
            int s0 = __shfl(idx, t + 0, 64), s1 = __shfl(idx, t + 1, 64);
            int s2 = __shfl(idx, t + 2, 64), s3 = __shfl(idx, t + 3, 64);
            uint2 q0 = *(const uint2*)(xb + (size_t)s0 * 128 + lane * 2);
            uint2 q1 = *(const uint2*)(xb + (size_t)s1 * 128 + lane * 2);
            uint2 q2 = *(const uint2*)(xb + (size_t)s2 * 128 + lane * 2);
            uint2 q3 = *(const uint2*)(xb + (size_t)s3 * 128 + lane * 2);
            float w0 = wlds[wave][(t + 0) * 4 + head], w1 = wlds[wave][(t + 1) * 4 + head];
            float w2 = wlds[wave][(t + 2) * 4 + head], w3 = wlds[wave][(t + 3) * 4 + head];
            ACC2(q0, w0); ACC2(q1, w1); ACC2(q2, w2); ACC2(q3, w3);
        }
        for (; t < deg; ++t) {
            int s0 = __shfl(idx, t, 64);
            uint2 q0 = *(const uint2*)(xb + (size_t)s0 * 128 + lane * 2);
            float w0 = wlds[wave][t * 4 + head];
            ACC2(q0, w0);
        }
    } else {
        float m[4], ssum[4];
        #pragma unroll
        for (int h = 0; h < 4; h++) { m[h] = -1e30f; ssum[h] = 0.f; }
        for (int base = start; base < end; base += 64) {
            int i = base + lane;
            bool valid = i < end;
            int idx = csr[valid ? i : start];
            float4 ev = *(const float4*)(es + (size_t)idx * 4);
            float e[4] = {ev.x, ev.y, ev.z, ev.w};
            #pragma unroll
            for (int h = 0; h < 4; h++) {
                float v = e[h] + edh[h];
                v = v > 0.f ? v : 0.2f * v;
                e[h] = valid ? v : -1e30f;
            }
            float cm[4];
            #pragma unroll
            for (int h = 0; h < 4; h++) cm[h] = e[h];
            #pragma unroll
            for (int o = 32; o >= 1; o >>= 1)
                #pragma unroll
                for (int h = 0; h < 4; h++) cm[h] = fmaxf(cm[h], __shfl_xor(cm[h], o, 64));
            float cs[4];
            #pragma unroll
            for (int h = 0; h < 4; h++) cs[h] = valid ? __expf(e[h] - cm[h]) : 0.f;
            #pragma unroll
            for (int o = 32; o >= 1; o >>= 1)
                #pragma unroll
                for (int h = 0; h < 4; h++) cs[h] += __shfl_xor(cs[h], o, 64);
            #pragma unroll
            for (int h = 0; h < 4; h++) {
                float mn = fmaxf(m[h], cm[h]);
                ssum[h] = ssum[h] * __expf(m[h] - mn) + cs[h] * __expf(cm[h] - mn);
                m[h] = mn;
            }
        }
        float inv[4];
        #pragma unroll
        for (int h = 0; h < 4; h++) inv[h] = 1.f / ssum[h];
        for (int base = start; base < end; base += 64) {
            int i = base + lane;
            bool valid = i < end;
            int idx = csr[valid ? i : start];
            int cnt = min(64, end - base);
            float4 ev = *(const float4*)(es + (size_t)idx * 4);
            float e[4] = {ev.x, ev.y, ev.z, ev.w};
            #pragma unroll
            for (int h = 0; h < 4; h++) {
                float v = e[h] + edh[h];
                v = v > 0.f ? v : 0.2f * v;
                e[h] = valid ? __expf(v - m[h]) * inv[h] : 0.f;
            }
            float4 wv; wv.x = e[0]; wv.y = e[1]; wv.z = e[2]; wv.w = e[3];
            *(float4*)&wlds[wave][lane * 4] = wv;
            for (int t = 0; t < cnt; ++t) {
                int s = __shfl(idx, t, 64);
                float w = wlds[wave][t * 4 + head];
                uint2 q = *(const uint2*)(xb + (size_t)s * 128 + lane * 2);
                ACC2(q, w);
            }
        }
    }

    float o0 = elu1(a0 + bias[lane * 4 + 0]);
    float o1 = elu1(a1 + bias[lane * 4 + 1]);
    float o2 = elu1(a2 + bias[lane * 4 + 2]);
    float o3 = elu1(a3 + bias[lane * 4 + 3]);
    if constexpr (BFOUT) {
        ushort4 o; o.x = f2bf(o0); o.y = f2bf(o1); o.z = f2bf(o2); o.w = f2bf(o3);
        *(ushort4*)((ushort_t*)outv + (size_t)node * 256 + lane * 4) = o;
    } else {
        float4 o; o.x = o0; o.y = o1; o.z = o2; o.w = o3;
        *(float4*)((float*)outv + (size_t)node * 256 + lane * 4) = o;
    }
}

// ------------------------------------------------- softmax aggregate, 1 head
// 4 nodes per wave (16-lane groups); partial mean-pool stored per block
// (no atomics — R4: 200k same-line atomics serialized at the coherent point).
__global__ __launch_bounds__(256) void k_agg1(const ushort_t* __restrict__ xl,
                                              const float* __restrict__ es,
                                              const float* __restrict__ ed,
                                              const int* __restrict__ row_ptr,
                                              const int* __restrict__ csr,
                                              const float* __restrict__ bias,
                                              float* __restrict__ part) {
    __shared__ float wlds[4][64];
    __shared__ float ps[4][64];
    int lane = threadIdx.x & 63, wave = threadIdx.x >> 6;
    int g = lane >> 4, l16 = lane & 15;
    int node = blockIdx.x * 16 + wave * 4 + g;
    bool vn = node < NN;
    int start = vn ? row_ptr[node] : 0;
    int end   = vn ? row_ptr[node + 1] : 0;
    float edl = vn ? ed[node] : 0.f;

    float m = -1e30f, ssum = 0.f;
    for (int base = start; base < end; base += 16) {
        int i = base + l16;
        bool valid = i < end;
        int idx = csr[valid ? i : start];
        float e = es[idx] + edl;
        e = e > 0.f ? e : 0.2f * e;
        e = valid ? e : -1e30f;
        float cm = e;
        #pragma unroll
        for (int o = 8; o >= 1; o >>= 1) cm = fmaxf(cm, __shfl_xor(cm, o, 64));
        float cs = valid ? __expf(e - cm) : 0.f;
        #pragma unroll
        for (int o = 8; o >= 1; o >>= 1) cs += __shfl_xor(cs, o, 64);
        float mn = fmaxf(m, cm);
        ssum = ssum * __expf(m - mn) + cs * __expf(cm - mn);
        m = mn;
    }
    float inv = 1.f / ssum;

    float a0 = 0.f, a1 = 0.f, a2 = 0.f, a3 = 0.f;
    const uint_t* xb = (const uint_t*)xl;
    for (int base = start; base < end; base += 16) {
        int i = base + l16;
        bool valid = i < end;
        int idx = csr[valid ? i : start];
        int cnt = min(16, end - base);
        float e = es[idx] + edl;
        e = e > 0.f ? e : 0.2f * e;
        wlds[wave][g * 16 + l16] = valid ? __expf(e - m) * inv : 0.f;
        int t = 0;
        for (; t + 4 <= cnt; t += 4) {
            int s0 = __shfl(idx, g * 16 + t + 0, 64), s1 = __shfl(idx, g * 16 + t + 1, 64);
            int s2 = __shfl(idx, g * 16 + t + 2, 64), s3 = __shfl(idx, g * 16 + t + 3, 64);
            uint2 q0 = *(const uint2*)(xb + (size_t)s0 * 32 + l16 * 2);
            uint2 q1 = *(const uint2*)(xb + (size_t)s1 * 32 + l16 * 2);
            uint2 q2 = *(const uint2*)(xb + (size_t)s2 * 32 + l16 * 2);
            uint2 q3 = *(const uint2*)(xb + (size_t)s3 * 32 + l16 * 2);
            float w0 = wlds[wave][g * 16 + t + 0], w1 = wlds[wave][g * 16 + t + 1];
            float w2 = wlds[wave][g * 16 + t + 2], w3 = wlds[wave][g * 16 + t + 3];
            ACC2(q0, w0); ACC2(q1, w1); ACC2(q2, w2); ACC2(q3, w3);
        }
        for (; t < cnt; ++t) {
            int s = __shfl(idx, g * 16 + t, 64);
            float w = wlds[wave][g * 16 + t];
            uint2 q = *(const uint2*)(xb + (size_t)s * 32 + l16 * 2);
            ACC2(q, w);
        }
    }

    float o[4];
    o[0] = vn ? elu1(a0 + bias[l16 * 4 + 0]) : 0.f;
    o[1] = vn ? elu1(a1 + bias[l16 * 4 + 1]) : 0.f;
    o[2] = vn ? elu1(a2 + bias[l16 * 4 + 2]) : 0.f;
    o[3] = vn ? elu1(a3 + bias[l16 * 4 + 3]) : 0.f;
    #pragma unroll
    for (int j = 0; j < 4; j++) {
        o[j] += __shfl_xor(o[j], 16, 64);
        o[j] += __shfl_xor(o[j], 32, 64);
    }
    if (lane < 16) {
        float4 v; v.x = o[0]; v.y = o[1]; v.z = o[2]; v.w = o[3];
        *(float4*)&ps[wave][l16 * 4] = v;
    }
    __syncthreads();
    int tid = threadIdx.x;
    if (tid < 64) {
        float tot = ps[0][tid] + ps[1][tid] + ps[2][tid] + ps[3][tid];
        part[(size_t)blockIdx.x * 64 + tid] = tot;
    }
}

// ---- reduce part[NAGG1][64] -> gsum[64] (few blocks => few atomics) ----
__global__ void k_red(const float* __restrict__ part, float* __restrict__ gsum) {
    __shared__ float sm[4][64];
    int t = threadIdx.x, c = t & 63, w = t >> 6;
    float s = 0.f;
    for (int r = blockIdx.x * 4 + w; r < NAGG1; r += gridDim.x * 4)
        s += part[(size_t)r * 64 + c];
    sm[w][c] = s;
    __syncthreads();
    if (w == 0) {
        float tot = sm[0][c] + sm[1][c] + sm[2][c] + sm[3][c];
        atomicAdd(&gsum[c], tot);
    }
}

// ---------------------------------------------------------------- final
__global__ void k_final(const float* __restrict__ gsum, const float* __restrict__ w_out,
                        const float* __restrict__ b_out, float* __restrict__ out) {
    int j = threadIdx.x;   // 128
    float s = b_out[j];
    const float invn = 1.f / (float)NN;
    #pragma unroll 8
    for (int k = 0; k < 64; k++)
        s += (gsum[k] * invn) * w_out[k * 128 + j];
    out[j] = s;
}

// ---------------------------------------------------------------- launcher
extern "C" void kernel_launch(void* const* d_in, const int* in_sizes, int n_in,
                              void* d_out, int out_size, void* d_ws, size_t ws_size,
                              hipStream_t stream) {
    const float* x    = (const float*)d_in[0];
    const int*   ei   = (const int*)d_in[1];
    const float* w_in = (const float*)d_in[2];
    const float* b_in = (const float*)d_in[3];
    const float* W0   = (const float*)d_in[4];
    const float* as0  = (const float*)d_in[5];
    const float* ad0  = (const float*)d_in[6];
    const float* bb0  = (const float*)d_in[7];
    const float* W1   = (const float*)d_in[8];
    const float* as1  = (const float*)d_in[9];
    const float* ad1  = (const float*)d_in[10];
    const float* bb1  = (const float*)d_in[11];
    const float* W2   = (const float*)d_in[12];
    const float* as2  = (const float*)d_in[13];
    const float* ad2  = (const float*)d_in[14];
    const float* bb2  = (const float*)d_in[15];
    const float* w_out= (const float*)d_in[16];
    const float* b_out= (const float*)d_in[17];
    float* out = (float*)d_out;

    char* p = (char*)d_ws;
    size_t off = 0;
    auto take = [&](size_t bytes) {
        char* r = p + off;
        off = (off + bytes + 255) & ~(size_t)255;
        return r;
    };
    ushort_t* xb     = (ushort_t*)take((size_t)NN * 256 * 2); // 25.6 MB
    ushort_t* h0b    = (ushort_t*)take((size_t)NN * 64 * 2);  //  6.4 MB
    ushort_t* xl_bf  = (ushort_t*)take((size_t)NN * 256 * 2); // 25.6 MB
    ushort_t* hb_bf  = (ushort_t*)take((size_t)NN * 256 * 2); // 25.6 MB
    ushort_t* h2_bf  = (ushort_t*)take((size_t)NN * 64 * 2);  //  6.4 MB
    ushort_t* wiT    = (ushort_t*)take((size_t)64 * 512 * 2);
    ushort_t* w0T    = (ushort_t*)take((size_t)256 * 128 * 2);
    ushort_t* w1T    = (ushort_t*)take((size_t)256 * 512 * 2);
    ushort_t* w2T    = (ushort_t*)take((size_t)64 * 512 * 2);
    float*    es     = (float*)take((size_t)NN * 4 * 4);
    float*    ed     = (float*)take((size_t)NN * 4 * 4);
    int*      row_ptr= (int*)take((size_t)(NN + 1) * 4);
    int*      cursor = (int*)take((size_t)NN * 4);
    int*      csr    = (int*)take((size_t)ET * 4);
    int*      bsum   = (int*)take((size_t)NBLK * 4);
    float*    part   = (float*)take((size_t)NAGG1 * 64 * 4);  // 0.8 MB
    float*    gsum   = (float*)take(64 * 4);

    // cursor := 0 (degree histogram base; self-loop +1 folded into scan1)
    hipMemsetAsync(cursor, 0, (size_t)NN * 4, stream);

    // ---- mega prep: x cast + weight split-transpose + dst histogram ----
    k_mega<<<MEGA_GRID, 256, 0, stream>>>((const float4*)x, (ushort4*)xb,
                                          w_in, W0, W1, W2, wiT, w0T, w1T, w2T,
                                          ei + NE, cursor, gsum);

    // ---- scan (cnt+1) -> row_ptr ----
    k_scan1<<<NBLK, 256, 0, stream>>>(cursor, row_ptr, bsum);
    k_scan2<<<1, 256, 0, stream>>>(bsum);
    k_scan3<<<NBLK, 256, 0, stream>>>(row_ptr, bsum, cursor);

    // ---- fused: CSR scatter + input projection GEMM ----
    k_scat_g1<<<GSCAT + GM64, 256, 0, stream>>>(ei, cursor, csr, xb, wiT, b_in, h0b);

    const int GM128 = (NN + 127) / 128;   // 391

    // ---- GAT layer 0 (heads=4, concat); BN=128, es/ed fused in epilogue ----
    gemm_mfma<false, false, true, 2, 8><<<dim3(GM128, 2), 256, 0, stream>>>(
        h0b, w0T, nullptr, xl_bf, as0, ad0, es, ed, 4, NN, 64, 256);
    k_agg4<true><<<(NN + 3) / 4, 256, 0, stream>>>(xl_bf, es, ed, row_ptr, csr, bb0, hb_bf);

    // ---- GAT layer 1 (heads=4, concat); BN=128 ----
    gemm_mfma<false, false, true, 2, 8><<<dim3(GM128, 2), 256, 0, stream>>>(
        hb_bf, w1T, nullptr, xl_bf, as1, ad1, es, ed, 4, NN, 256, 256);
    k_agg4<true><<<(NN + 3) / 4, 256, 0, stream>>>(xl_bf, es, ed, row_ptr, csr, bb1, hb_bf);

    // ---- GAT layer 2 (heads=1) + partial mean-pool ----
    gemm_mfma<false, false, true, 1, 4><<<dim3(GM64, 1), 256, 0, stream>>>(
        hb_bf, w2T, nullptr, h2_bf, as2, ad2, es, ed, 1, NN, 256, 64);
    k_agg1<<<NAGG1, 256, 0, stream>>>(h2_bf, es, ed, row_ptr, csr, bb2, part);
    k_red <<<64, 256, 0, stream>>>(part, gsum);

    // ---- output projection ----
    k_final<<<1, 128, 0, stream>>>(gsum, w_out, b_out, out);
}

// Round 10
// 455.124 us; speedup vs baseline: 1.9419x; 1.0192x over previous
//
#include <hip/hip_runtime.h>

#define NN 50000
#define NE 800000
#define ET 850000   // NE + NN self-loops
#define NBLK 196    // ceil(NN/256) for the parallel scan
#define NAGG1 3125  // k_agg1 grid (= NN/16), also rows of `part`
#define MEGA_CAST 12500                 // castx blocks: NN*256/4/256
#define MEGA_W    448                   // weight-prep blocks (114688/256)
#define MEGA_HIST 3125                  // hist blocks (NE/256)
#define MEGA_GRID (MEGA_CAST + MEGA_W + MEGA_HIST)
#define GM64 782                        // (NN+63)/64
#define GM128 391                       // (NN+127)/128
#define EHALF 425000                    // scatter split point
#define SCA 1661                        // ceil(EHALF/256)
#define SCB 1661                        // ceil((ET-EHALF)/256)

typedef unsigned short ushort_t;
typedef unsigned int uint_t;
typedef __attribute__((ext_vector_type(8))) short short8;
typedef __attribute__((ext_vector_type(4))) float f32x4;

// ---------------------------------------------------------------- utilities
__device__ __forceinline__ float elu1(float x) {
    return x > 0.f ? x : (__expf(x) - 1.f);
}
__device__ __forceinline__ float bf2f(ushort_t u) {
    return __uint_as_float(((uint_t)u) << 16);
}
__device__ __forceinline__ ushort_t f2bf(float f) {   // round-to-nearest-even
    uint_t u = __float_as_uint(f);
    u += 0x7FFFu + ((u >> 16) & 1u);
    return (ushort_t)(u >> 16);
}
__device__ __forceinline__ void gl_lds16(const ushort_t* g, ushort_t* l) {
    // async global->LDS, 16B/lane; LDS dest = wave-uniform base + lane*16
    __builtin_amdgcn_global_load_lds((const __attribute__((address_space(1))) void*)g,
                                     (__attribute__((address_space(3))) void*)l,
                                     16, 0, 0);
}
// bf16 pair (packed in a dword) -> two fp32, exact (bf16 = truncated fp32)
#define ACC2(q, w) do { \
    a0 += (w) * __uint_as_float((q).x << 16); \
    a1 += (w) * __uint_as_float((q).x & 0xFFFF0000u); \
    a2 += (w) * __uint_as_float((q).y << 16); \
    a3 += (w) * __uint_as_float((q).y & 0xFFFF0000u); } while (0)

// ---------------------------------------------------------------- mega prep
// blocks [0,12500): x fp32->bf16 (+ gsum=0 init in block 0)
// blocks [12500,12948): weight split-transposes with column permutation:
//   within each 64-col group, col j -> row (j&3)*16 + (j>>2): GEMM frag nt
//   slot l16 = global col l16*4+nt -> lanes own 4 consecutive output cols.
// blocks [12948,16073): dst-degree histogram (cursor pre-zeroed by memset;
//   the +1 self-loop is folded into k_scan1).
__global__ void k_mega(const float4* __restrict__ x, ushort4* __restrict__ xb,
                       const float* __restrict__ w_in, const float* __restrict__ W0,
                       const float* __restrict__ W1, const float* __restrict__ W2,
                       ushort_t* __restrict__ wiT, ushort_t* __restrict__ w0T,
                       ushort_t* __restrict__ w1T, ushort_t* __restrict__ w2T,
                       const int* __restrict__ dst, int* __restrict__ cursor,
                       float* __restrict__ gsum) {
    int b = blockIdx.x, t = threadIdx.x;
    if (b < MEGA_CAST) {
        int i = b * 256 + t;                      // < NN*64 = 3,200,000 float4s
        float4 v = x[i];
        ushort4 o;
        o.x = f2bf(v.x); o.y = f2bf(v.y); o.z = f2bf(v.z); o.w = f2bf(v.w);
        xb[i] = o;
        if (b == 0 && t < 64) gsum[t] = 0.f;
    } else if (b < MEGA_CAST + MEGA_W) {
        int i = (b - MEGA_CAST) * 256 + t;        // 0..114687
        const float* W; ushort_t* Bt; int K, N, j;
        if (i < 16384)       { W = w_in; Bt = wiT; K = 256; N = 64;  j = i; }
        else if (i < 32768)  { W = W0;   Bt = w0T; K = 64;  N = 256; j = i - 16384; }
        else if (i < 98304)  { W = W1;   Bt = w1T; K = 256; N = 256; j = i - 32768; }
        else                 { W = W2;   Bt = w2T; K = 256; N = 64;  j = i - 98304; }
        int k = j / N, n = j % N;
        int jj = n & 63;
        int rp = (n & ~63) | ((jj & 3) << 4) | (jj >> 2);   // permuted row
        float v = W[j];
        ushort_t h = f2bf(v);
        Bt[(size_t)rp * 2 * K + k] = h;
        Bt[(size_t)rp * 2 * K + K + k] = f2bf(v - bf2f(h));
    } else {
        int e = (b - MEGA_CAST - MEGA_W) * 256 + t;
        if (e < NE) atomicAdd(&cursor[dst[e]], 1);
    }
}

// ---------------------------------------------------------------- scan
// exclusive scan of (cnt[i]+1) -> row_ptr (the +1 is the self-loop)
__global__ void k_scan1(const int* __restrict__ cnt, int* __restrict__ excl,
                        int* __restrict__ bsum) {
    __shared__ int wsum[4];
    int t = threadIdx.x, lane = t & 63, w = t >> 6;
    int i = blockIdx.x * 256 + t;
    int v = (i < NN) ? cnt[i] + 1 : 0;
    int x = v;
    #pragma unroll
    for (int o = 1; o < 64; o <<= 1) {
        int y = __shfl_up(x, o, 64);
        if (lane >= o) x += y;
    }
    if (lane == 63) wsum[w] = x;
    __syncthreads();
    int wo = 0;
    #pragma unroll
    for (int k = 0; k < 4; k++) wo += (k < w) ? wsum[k] : 0;
    if (i < NN) excl[i] = x - v + wo;
    if (t == 255) bsum[blockIdx.x] = wo + x;     // block total
}

__global__ void k_scan2(int* __restrict__ bsum) {   // 1 block, 256 threads
    __shared__ int wsum[4];
    int t = threadIdx.x, lane = t & 63, w = t >> 6;
    int v = (t < NBLK) ? bsum[t] : 0;
    int x = v;
    #pragma unroll
    for (int o = 1; o < 64; o <<= 1) {
        int y = __shfl_up(x, o, 64);
        if (lane >= o) x += y;
    }
    if (lane == 63) wsum[w] = x;
    __syncthreads();
    int wo = 0;
    #pragma unroll
    for (int k = 0; k < 4; k++) wo += (k < w) ? wsum[k] : 0;
    if (t < NBLK) bsum[t] = x - v + wo;          // exclusive
}

__global__ void k_scan3(int* __restrict__ row_ptr, const int* __restrict__ bsum,
                        int* __restrict__ cursor) {
    int i = blockIdx.x * 256 + threadIdx.x;
    if (i < NN) {
        int r = row_ptr[i] + bsum[blockIdx.x];
        row_ptr[i] = r;
        cursor[i] = r;
    }
    if (i == 0) row_ptr[NN] = ET;
}

// ---------------------------------------------------------------- GEMM body
// C[M x N](bf16) = A[M x K](bf16) @ (Bh + Bl), split-bf16 weights.
// BM=64*MT, BN=16*NT (NT=8 for N=256 GEMMs -> halves A refetch). 256 thr.
// Weight cols permuted (see k_mega) -> ushort4 C stores, float4 bias loads.
// EDOT: head = by*(NT/4)+hg; es/ed via per-16-lane butterfly.
template<bool ELU, bool BIAS, bool EDOT, int MT, int NT>
__device__ __forceinline__ void gemm_body(const ushort_t* __restrict__ A,
                                          const ushort_t* __restrict__ Bt,
                                          const float* __restrict__ bias,
                                          ushort_t* __restrict__ C,
                                          const float* __restrict__ a_s,
                                          const float* __restrict__ a_d,
                                          float* __restrict__ es,
                                          float* __restrict__ ed,
                                          int esStride, int M, int K, int N,
                                          int bx, int by) {
    constexpr int HG = NT / 4;                    // 64-col groups per block
    constexpr int BOFF = MT * 4096;               // ushort offset of B region
    __shared__ __align__(16) ushort_t lds[MT * 4096 + NT * 2048];
    int tid = threadIdx.x;
    int wave = tid >> 6, lane = tid & 63;
    int quad = lane >> 4, l16 = lane & 15;
    int mb = bx * (64 * MT), nb = by * (16 * NT);
    int K2 = 2 * K;

    f32x4 acc[MT][NT];
    #pragma unroll
    for (int mt = 0; mt < MT; mt++)
        #pragma unroll
        for (int nt = 0; nt < NT; nt++)
            acc[mt][nt] = (f32x4){0.f, 0.f, 0.f, 0.f};

    for (int k0 = 0; k0 < K; k0 += 64) {
        #pragma unroll
        for (int c = 0; c < 2 * MT; c++) {
            int mt = (MT == 2) ? (wave * 2 + (c >> 1)) : wave;
            int ks = (MT == 2) ? (c & 1) : c;
            int row = mb + mt * 16 + l16;
            row = min(row, M - 1);
            int col = k0 + ks * 32 + quad * 8;
            gl_lds16(A + (size_t)row * K + col, &lds[(mt * 2 + ks) * 512]);
        }
        #pragma unroll
        for (int c = 0; c < NT; c++) {
            int id = wave * NT + c;               // 0 .. 4*NT-1
            int ntile = id % NT;
            int ks = (id / NT) & 1;
            int split = id / (2 * NT);
            int n = nb + ntile * 16 + l16;
            int col = split * K + k0 + ks * 32 + quad * 8;
            gl_lds16(Bt + (size_t)n * K2 + col,
                     &lds[BOFF + ((split * NT + ntile) * 2 + ks) * 512]);
        }
        __syncthreads();
        #pragma unroll
        for (int ks = 0; ks < 2; ks++) {
            short8 af[MT];
            #pragma unroll
            for (int mt = 0; mt < MT; mt++)
                af[mt] = *(const short8*)&lds[((wave * MT + mt) * 2 + ks) * 512 + lane * 8];
            #pragma unroll
            for (int split = 0; split < 2; split++) {
                short8 bf[NT];
                #pragma unroll
                for (int nt = 0; nt < NT; nt++)
                    bf[nt] = *(const short8*)&lds[BOFF + ((split * NT + nt) * 2 + ks) * 512 + lane * 8];
                #pragma unroll
                for (int mt = 0; mt < MT; mt++)
                    #pragma unroll
                    for (int nt = 0; nt < NT; nt++)
                        acc[mt][nt] = __builtin_amdgcn_mfma_f32_16x16x32_bf16(
                            af[mt], bf[nt], acc[mt][nt], 0, 0, 0);
            }
        }
        __syncthreads();
    }
    // ---- epilogue: frag nt slot l16 = global col l16*4 + (nt%4), group nt/4 ----
    float4 as4[HG], ad4[HG], b4[HG];
    #pragma unroll
    for (int hg = 0; hg < HG; hg++) {
        int cbase = nb + hg * 64 + l16 * 4;
        if (EDOT) {
            as4[hg] = *(const float4*)(a_s + (size_t)(by * HG + hg) * 64 + l16 * 4);
            ad4[hg] = *(const float4*)(a_d + (size_t)(by * HG + hg) * 64 + l16 * 4);
        }
        if (BIAS) b4[hg] = *(const float4*)(bias + cbase);
    }
    #pragma unroll
    for (int mt = 0; mt < MT; mt++) {
        int mrow = mb + (wave * MT + mt) * 16 + quad * 4;
        #pragma unroll
        for (int r = 0; r < 4; r++) {
            int m = mrow + r;
            bool mv = m < M;
            #pragma unroll
            for (int hg = 0; hg < HG; hg++) {
                float v0 = acc[mt][hg * 4 + 0][r];
                float v1 = acc[mt][hg * 4 + 1][r];
                float v2 = acc[mt][hg * 4 + 2][r];
                float v3 = acc[mt][hg * 4 + 3][r];
                if constexpr (EDOT) {
                    float ps = v0 * as4[hg].x + v1 * as4[hg].y + v2 * as4[hg].z + v3 * as4[hg].w;
                    float pd = v0 * ad4[hg].x + v1 * ad4[hg].y + v2 * ad4[hg].z + v3 * ad4[hg].w;
                    #pragma unroll
                    for (int o = 8; o >= 1; o >>= 1) {
                        ps += __shfl_xor(ps, o, 64);
                        pd += __shfl_xor(pd, o, 64);
                    }
                    if (l16 == 0 && mv) {
                        int head = by * HG + hg;
                        es[(size_t)m * esStride + head] = ps;
                        ed[(size_t)m * esStride + head] = pd;
                    }
                }
                if (mv) {
                    if (BIAS) { v0 += b4[hg].x; v1 += b4[hg].y; v2 += b4[hg].z; v3 += b4[hg].w; }
                    if (ELU) { v0 = elu1(v0); v1 = elu1(v1); v2 = elu1(v2); v3 = elu1(v3); }
                    ushort4 o;
                    o.x = f2bf(v0); o.y = f2bf(v1); o.z = f2bf(v2); o.w = f2bf(v3);
                    *(ushort4*)&C[(size_t)m * N + nb + hg * 64 + l16 * 4] = o;
                }
            }
        }
    }
}

template<bool ELU, bool BIAS, bool EDOT, int MT, int NT>
__global__ __launch_bounds__(256) void gemm_mfma(const ushort_t* __restrict__ A,
                                                 const ushort_t* __restrict__ Bt,
                                                 const float* __restrict__ bias,
                                                 ushort_t* __restrict__ C,
                                                 const float* __restrict__ a_s,
                                                 const float* __restrict__ a_d,
                                                 float* __restrict__ es,
                                                 float* __restrict__ ed,
                                                 int esStride, int M, int K, int N) {
    gemm_body<ELU, BIAS, EDOT, MT, NT>(A, Bt, bias, C, a_s, a_d, es, ed,
                                       esStride, M, K, N, blockIdx.x, blockIdx.y);
}

// ---- fused launch A: input-projection GEMM (blocks [0,GM64)) + CSR scatter
//      of edges [0,EHALF) — GEMM blocks first so they dispatch immediately;
//      the scatter's ~1 TB/s random-store stream overlaps the GEMM compute.
__global__ __launch_bounds__(256) void k_fuseA(const ushort_t* __restrict__ A,
                                               const ushort_t* __restrict__ Bt,
                                               const float* __restrict__ bias,
                                               ushort_t* __restrict__ C,
                                               const int* __restrict__ ei,
                                               int* __restrict__ cursor,
                                               int* __restrict__ csr) {
    if (blockIdx.x < GM64) {
        gemm_body<true, true, false, 1, 4>(A, Bt, bias, C, nullptr, nullptr,
                                           nullptr, nullptr, 0, NN, 256, 64,
                                           blockIdx.x, 0);
    } else {
        int e = (blockIdx.x - GM64) * 256 + threadIdx.x;
        if (e >= EHALF) return;               // EHALF < NE: all real edges
        int s = ei[e], d = ei[NE + e];
        int pos = atomicAdd(&cursor[d], 1);
        csr[pos] = s;
    }
}

// ---- fused launch B: GAT-layer-0 GEMM (flattened 391x2 grid, blocks
//      [0,782)) + CSR scatter of edges [EHALF,ET) incl. self-loops.
__global__ __launch_bounds__(256) void k_fuseB(const ushort_t* __restrict__ A,
                                               const ushort_t* __restrict__ Bt,
                                               ushort_t* __restrict__ C,
                                               const float* __restrict__ a_s,
                                               const float* __restrict__ a_d,
                                               float* __restrict__ es,
                                               float* __restrict__ ed,
                                               const int* __restrict__ ei,
                                               int* __restrict__ cursor,
                                               int* __restrict__ csr) {
    if (blockIdx.x < 2 * GM128) {
        int g = blockIdx.x;
        gemm_body<false, false, true, 2, 8>(A, Bt, nullptr, C, a_s, a_d, es, ed,
                                            4, NN, 64, 256, g % GM128, g / GM128);
    } else {
        int e = EHALF + (blockIdx.x - 2 * GM128) * 256 + threadIdx.x;
        if (e >= ET) return;
        int s, d;
        if (e < NE) { s = ei[e]; d = ei[NE + e]; }
        else        { s = d = e - NE; }
        int pos = atomicAdd(&cursor[d], 1);
        csr[pos] = s;
    }
}

// ------------------------------------------------- softmax aggregate, 4 heads
// 1 wave per node; fast path deg<=64; gather unrolled x4 (R7: x8 regressed via
// VGPR 24->36). Near fabric floor: 207 MB FETCH @ ~3.6 TB/s observed ceiling.
template<bool BFOUT>
__global__ __launch_bounds__(256) void k_agg4(const ushort_t* __restrict__ xl,
                                              const float* __restrict__ es,
                                              const float* __restrict__ ed,
                                              const int* __restrict__ row_ptr,
                                              const int* __restrict__ csr,
                                              const float* __restrict__ bias,
                                              void* __restrict__ outv) {
    __shared__ float wlds[4][256];
    int lane = threadIdx.x & 63, wave = threadIdx.x >> 6;
    int node = blockIdx.x * 4 + wave;
    if (node >= NN) return;
    int head = lane >> 4;
    int start = row_ptr[node], end = row_ptr[node + 1];
    int deg = end - start;
    float4 edv = *(const float4*)(ed + (size_t)node * 4);
    float edh[4] = {edv.x, edv.y, edv.z, edv.w};
    float a0 = 0.f, a1 = 0.f, a2 = 0.f, a3 = 0.f;
    const uint_t* xb = (const uint_t*)xl;

    if (deg <= 64) {
        int i = start + lane;
        bool valid = i < end;
        int idx = csr[valid ? i : start];
        float4 ev = *(const float4*)(es + (size_t)idx * 4);
        float e[4] = {ev.x, ev.y, ev.z, ev.w};
        #pragma unroll
        for (int h = 0; h < 4; h++) {
            float v = e[h] + edh[h];
            v = v > 0.f ? v : 0.2f * v;
            e[h] = valid ? v : -1e30f;
        }
        float cm[4];
        #pragma unroll
        for (int h = 0; h < 4; h++) cm[h] = e[h];
        #pragma unroll
        for (int o = 32; o >= 1; o >>= 1)
            #pragma unroll
            for (int h = 0; h < 4; h++) cm[h] = fmaxf(cm[h], __shfl_xor(cm[h], o, 64));
        float cs[4];
        #pragma unroll
        for (int h = 0; h < 4; h++) cs[h] = valid ? __expf(e[h] - cm[h]) : 0.f;
        #pragma unroll
        for (int o = 32; o >= 1; o >>= 1)
            #pragma unroll
            for (int h = 0; h < 4; h++) cs[h] += __shfl_xor(cs[h], o, 64);
        float4 wv;
        wv.x = valid ? __expf(e[0] - cm[0]) / cs[0] : 0.f;
        wv.y = valid ? __expf(e[1] - cm[1]) / cs[1] : 0.f;
        wv.z = valid ? __expf(e[2] - cm[2]) / cs[2] : 0.f;
        wv.w = valid ? __expf(e[3] - cm[3]) / cs[3] : 0.f;
        *(float4*)&wlds[wave][lane * 4] = wv;
        int t = 0;
        for (; t + 4 <= deg; t += 4) {
            int s0 = __shfl(idx, t + 0, 64), s1 = __shfl(idx, t + 1, 64);
            int s2 = __shfl(idx, t + 2, 64), s3 = __shfl(idx, t + 3, 64);
            uint2 q0 = *(const uint2*)(xb + (size_t)s0 * 128 + lane * 2);
            uint2 q1 = *(const uint2*)(xb + (size_t)s1 * 128 + lane * 2);
            uint2 q2 = *(const uint2*)(xb + (size_t)s2 * 128 + lane * 2);
            uint2 q3 = *(const uint2*)(xb + (size_t)s3 * 128 + lane * 2);
            float w0 = wlds[wave][(t + 0) * 4 + head], w1 = wlds[wave][(t + 1) * 4 + head];
            float w2 = wlds[wave][(t + 2) * 4 + head], w3 = wlds[wave][(t + 3) * 4 + head];
            ACC2(q0, w0); ACC2(q1, w1); ACC2(q2, w2); ACC2(q3, w3);
        }
        for (; t < deg; ++t) {
            int s0 = __shfl(idx, t, 64);
            uint2 q0 = *(const uint2*)(xb + (size_t)s0 * 128 + lane * 2);
            float w0 = wlds[wave][t * 4 + head];
            ACC2(q0, w0);
        }
    } else {
        float m[4], ssum[4];
        #pragma unroll
        for (int h = 0; h < 4; h++) { m[h] = -1e30f; ssum[h] = 0.f; }
        for (int base = start; base < end; base += 64) {
            int i = base + lane;
            bool valid = i < end;
            int idx = csr[valid ? i : start];
            float4 ev = *(const float4*)(es + (size_t)idx * 4);
            float e[4] = {ev.x, ev.y, ev.z, ev.w};
            #pragma unroll
            for (int h = 0; h < 4; h++) {
                float v = e[h] + edh[h];
                v = v > 0.f ? v : 0.2f * v;
                e[h] = valid ? v : -1e30f;
            }
            float cm[4];
            #pragma unroll
            for (int h = 0; h < 4; h++) cm[h] = e[h];
            #pragma unroll
            for (int o = 32; o >= 1; o >>= 1)
                #pragma unroll
                for (int h = 0; h < 4; h++) cm[h] = fmaxf(cm[h], __shfl_xor(cm[h], o, 64));
            float cs[4];
            #pragma unroll
            for (int h = 0; h < 4; h++) cs[h] = valid ? __expf(e[h] - cm[h]) : 0.f;
            #pragma unroll
            for (int o = 32; o >= 1; o >>= 1)
                #pragma unroll
                for (int h = 0; h < 4; h++) cs[h] += __shfl_xor(cs[h], o, 64);
            #pragma unroll
            for (int h = 0; h < 4; h++) {
                float mn = fmaxf(m[h], cm[h]);
                ssum[h] = ssum[h] * __expf(m[h] - mn) + cs[h] * __expf(cm[h] - mn);
                m[h] = mn;
            }
        }
        float inv[4];
        #pragma unroll
        for (int h = 0; h < 4; h++) inv[h] = 1.f / ssum[h];
        for (int base = start; base < end; base += 64) {
            int i = base + lane;
            bool valid = i < end;
            int idx = csr[valid ? i : start];
            int cnt = min(64, end - base);
            float4 ev = *(const float4*)(es + (size_t)idx * 4);
            float e[4] = {ev.x, ev.y, ev.z, ev.w};
            #pragma unroll
            for (int h = 0; h < 4; h++) {
                float v = e[h] + edh[h];
                v = v > 0.f ? v : 0.2f * v;
                e[h] = valid ? __expf(v - m[h]) * inv[h] : 0.f;
            }
            float4 wv; wv.x = e[0]; wv.y = e[1]; wv.z = e[2]; wv.w = e[3];
            *(float4*)&wlds[wave][lane * 4] = wv;
            for (int t = 0; t < cnt; ++t) {
                int s = __shfl(idx, t, 64);
                float w = wlds[wave][t * 4 + head];
                uint2 q = *(const uint2*)(xb + (size_t)s * 128 + lane * 2);
                ACC2(q, w);
            }
        }
    }

    float o0 = elu1(a0 + bias[lane * 4 + 0]);
    float o1 = elu1(a1 + bias[lane * 4 + 1]);
    float o2 = elu1(a2 + bias[lane * 4 + 2]);
    float o3 = elu1(a3 + bias[lane * 4 + 3]);
    if constexpr (BFOUT) {
        ushort4 o; o.x = f2bf(o0); o.y = f2bf(o1); o.z = f2bf(o2); o.w = f2bf(o3);
        *(ushort4*)((ushort_t*)outv + (size_t)node * 256 + lane * 4) = o;
    } else {
        float4 o; o.x = o0; o.y = o1; o.z = o2; o.w = o3;
        *(float4*)((float*)outv + (size_t)node * 256 + lane * 4) = o;
    }
}

// ------------------------------------------------- softmax aggregate, 1 head
// 4 nodes per wave (16-lane groups); partial mean-pool stored per block
// (no atomics — R4: 200k same-line atomics serialized at the coherent point).
__global__ __launch_bounds__(256) void k_agg1(const ushort_t* __restrict__ xl,
                                              const float* __restrict__ es,
                                              const float* __restrict__ ed,
                                              const int* __restrict__ row_ptr,
                                              const int* __restrict__ csr,
                                              const float* __restrict__ bias,
                                              float* __restrict__ part) {
    __shared__ float wlds[4][64];
    __shared__ float ps[4][64];
    int lane = threadIdx.x & 63, wave = threadIdx.x >> 6;
    int g = lane >> 4, l16 = lane & 15;
    int node = blockIdx.x * 16 + wave * 4 + g;
    bool vn = node < NN;
    int start = vn ? row_ptr[node] : 0;
    int end   = vn ? row_ptr[node + 1] : 0;
    float edl = vn ? ed[node] : 0.f;

    float m = -1e30f, ssum = 0.f;
    for (int base = start; base < end; base += 16) {
        int i = base + l16;
        bool valid = i < end;
        int idx = csr[valid ? i : start];
        float e = es[idx] + edl;
        e = e > 0.f ? e : 0.2f * e;
        e = valid ? e : -1e30f;
        float cm = e;
        #pragma unroll
        for (int o = 8; o >= 1; o >>= 1) cm = fmaxf(cm, __shfl_xor(cm, o, 64));
        float cs = valid ? __expf(e - cm) : 0.f;
        #pragma unroll
        for (int o = 8; o >= 1; o >>= 1) cs += __shfl_xor(cs, o, 64);
        float mn = fmaxf(m, cm);
        ssum = ssum * __expf(m - mn) + cs * __expf(cm - mn);
        m = mn;
    }
    float inv = 1.f / ssum;

    float a0 = 0.f, a1 = 0.f, a2 = 0.f, a3 = 0.f;
    const uint_t* xb = (const uint_t*)xl;
    for (int base = start; base < end; base += 16) {
        int i = base + l16;
        bool valid = i < end;
        int idx = csr[valid ? i : start];
        int cnt = min(16, end - base);
        float e = es[idx] + edl;
        e = e > 0.f ? e : 0.2f * e;
        wlds[wave][g * 16 + l16] = valid ? __expf(e - m) * inv : 0.f;
        int t = 0;
        for (; t + 4 <= cnt; t += 4) {
            int s0 = __shfl(idx, g * 16 + t + 0, 64), s1 = __shfl(idx, g * 16 + t + 1, 64);
            int s2 = __shfl(idx, g * 16 + t + 2, 64), s3 = __shfl(idx, g * 16 + t + 3, 64);
            uint2 q0 = *(const uint2*)(xb + (size_t)s0 * 32 + l16 * 2);
            uint2 q1 = *(const uint2*)(xb + (size_t)s1 * 32 + l16 * 2);
            uint2 q2 = *(const uint2*)(xb + (size_t)s2 * 32 + l16 * 2);
            uint2 q3 = *(const uint2*)(xb + (size_t)s3 * 32 + l16 * 2);
            float w0 = wlds[wave][g * 16 + t + 0], w1 = wlds[wave][g * 16 + t + 1];
            float w2 = wlds[wave][g * 16 + t + 2], w3 = wlds[wave][g * 16 + t + 3];
            ACC2(q0, w0); ACC2(q1, w1); ACC2(q2, w2); ACC2(q3, w3);
        }
        for (; t < cnt; ++t) {
            int s = __shfl(idx, g * 16 + t, 64);
            float w = wlds[wave][g * 16 + t];
            uint2 q = *(const uint2*)(xb + (size_t)s * 32 + l16 * 2);
            ACC2(q, w);
        }
    }

    float o[4];
    o[0] = vn ? elu1(a0 + bias[l16 * 4 + 0]) : 0.f;
    o[1] = vn ? elu1(a1 + bias[l16 * 4 + 1]) : 0.f;
    o[2] = vn ? elu1(a2 + bias[l16 * 4 + 2]) : 0.f;
    o[3] = vn ? elu1(a3 + bias[l16 * 4 + 3]) : 0.f;
    #pragma unroll
    for (int j = 0; j < 4; j++) {
        o[j] += __shfl_xor(o[j], 16, 64);
        o[j] += __shfl_xor(o[j], 32, 64);
    }
    if (lane < 16) {
        float4 v; v.x = o[0]; v.y = o[1]; v.z = o[2]; v.w = o[3];
        *(float4*)&ps[wave][l16 * 4] = v;
    }
    __syncthreads();
    int tid = threadIdx.x;
    if (tid < 64) {
        float tot = ps[0][tid] + ps[1][tid] + ps[2][tid] + ps[3][tid];
        part[(size_t)blockIdx.x * 64 + tid] = tot;
    }
}

// ---- reduce part[NAGG1][64] -> gsum[64] (few blocks => few atomics) ----
__global__ void k_red(const float* __restrict__ part, float* __restrict__ gsum) {
    __shared__ float sm[4][64];
    int t = threadIdx.x, c = t & 63, w = t >> 6;
    float s = 0.f;
    for (int r = blockIdx.x * 4 + w; r < NAGG1; r += gridDim.x * 4)
        s += part[(size_t)r * 64 + c];
    sm[w][c] = s;
    __syncthreads();
    if (w == 0) {
        float tot = sm[0][c] + sm[1][c] + sm[2][c] + sm[3][c];
        atomicAdd(&gsum[c], tot);
    }
}

// ---------------------------------------------------------------- final
__global__ void k_final(const float* __restrict__ gsum, const float* __restrict__ w_out,
                        const float* __restrict__ b_out, float* __restrict__ out) {
    int j = threadIdx.x;   // 128
    float s = b_out[j];
    const float invn = 1.f / (float)NN;
    #pragma unroll 8
    for (int k = 0; k < 64; k++)
        s += (gsum[k] * invn) * w_out[k * 128 + j];
    out[j] = s;
}

// ---------------------------------------------------------------- launcher
extern "C" void kernel_launch(void* const* d_in, const int* in_sizes, int n_in,
                              void* d_out, int out_size, void* d_ws, size_t ws_size,
                              hipStream_t stream) {
    const float* x    = (const float*)d_in[0];
    const int*   ei   = (const int*)d_in[1];
    const float* w_in = (const float*)d_in[2];
    const float* b_in = (const float*)d_in[3];
    const float* W0   = (const float*)d_in[4];
    const float* as0  = (const float*)d_in[5];
    const float* ad0  = (const float*)d_in[6];
    const float* bb0  = (const float*)d_in[7];
    const float* W1   = (const float*)d_in[8];
    const float* as1  = (const float*)d_in[9];
    const float* ad1  = (const float*)d_in[10];
    const float* bb1  = (const float*)d_in[11];
    const float* W2   = (const float*)d_in[12];
    const float* as2  = (const float*)d_in[13];
    const float* ad2  = (const float*)d_in[14];
    const float* bb2  = (const float*)d_in[15];
    const float* w_out= (const float*)d_in[16];
    const float* b_out= (const float*)d_in[17];
    float* out = (float*)d_out;

    char* p = (char*)d_ws;
    size_t off = 0;
    auto take = [&](size_t bytes) {
        char* r = p + off;
        off = (off + bytes + 255) & ~(size_t)255;
        return r;
    };
    ushort_t* xb     = (ushort_t*)take((size_t)NN * 256 * 2); // 25.6 MB
    ushort_t* h0b    = (ushort_t*)take((size_t)NN * 64 * 2);  //  6.4 MB
    ushort_t* xl_bf  = (ushort_t*)take((size_t)NN * 256 * 2); // 25.6 MB
    ushort_t* hb_bf  = (ushort_t*)take((size_t)NN * 256 * 2); // 25.6 MB
    ushort_t* h2_bf  = (ushort_t*)take((size_t)NN * 64 * 2);  //  6.4 MB
    ushort_t* wiT    = (ushort_t*)take((size_t)64 * 512 * 2);
    ushort_t* w0T    = (ushort_t*)take((size_t)256 * 128 * 2);
    ushort_t* w1T    = (ushort_t*)take((size_t)256 * 512 * 2);
    ushort_t* w2T    = (ushort_t*)take((size_t)64 * 512 * 2);
    float*    es     = (float*)take((size_t)NN * 4 * 4);
    float*    ed     = (float*)take((size_t)NN * 4 * 4);
    int*      row_ptr= (int*)take((size_t)(NN + 1) * 4);
    int*      cursor = (int*)take((size_t)NN * 4);
    int*      csr    = (int*)take((size_t)ET * 4);
    int*      bsum   = (int*)take((size_t)NBLK * 4);
    float*    part   = (float*)take((size_t)NAGG1 * 64 * 4);  // 0.8 MB
    float*    gsum   = (float*)take(64 * 4);

    // cursor := 0 (degree histogram base; self-loop +1 folded into scan1)
    hipMemsetAsync(cursor, 0, (size_t)NN * 4, stream);

    // ---- mega prep: x cast + weight split-transpose + dst histogram ----
    k_mega<<<MEGA_GRID, 256, 0, stream>>>((const float4*)x, (ushort4*)xb,
                                          w_in, W0, W1, W2, wiT, w0T, w1T, w2T,
                                          ei + NE, cursor, gsum);

    // ---- scan (cnt+1) -> row_ptr ----
    k_scan1<<<NBLK, 256, 0, stream>>>(cursor, row_ptr, bsum);
    k_scan2<<<1, 256, 0, stream>>>(bsum);
    k_scan3<<<NBLK, 256, 0, stream>>>(row_ptr, bsum, cursor);

    // ---- fused A: input projection GEMM || scatter edges [0,EHALF) ----
    k_fuseA<<<GM64 + SCA, 256, 0, stream>>>(xb, wiT, b_in, h0b, ei, cursor, csr);

    // ---- fused B: GAT layer-0 GEMM (es/ed epilogue) || scatter [EHALF,ET) ----
    k_fuseB<<<2 * GM128 + SCB, 256, 0, stream>>>(h0b, w0T, xl_bf, as0, ad0,
                                                 es, ed, ei, cursor, csr);
    k_agg4<true><<<(NN + 3) / 4, 256, 0, stream>>>(xl_bf, es, ed, row_ptr, csr, bb0, hb_bf);

    // ---- GAT layer 1 (heads=4, concat); BN=128 ----
    gemm_mfma<false, false, true, 2, 8><<<dim3(GM128, 2), 256, 0, stream>>>(
        hb_bf, w1T, nullptr, xl_bf, as1, ad1, es, ed, 4, NN, 256, 256);
    k_agg4<true><<<(NN + 3) / 4, 256, 0, stream>>>(xl_bf, es, ed, row_ptr, csr, bb1, hb_bf);

    // ---- GAT layer 2 (heads=1) + partial mean-pool ----
    gemm_mfma<false, false, true, 1, 4><<<dim3(GM64, 1), 256, 0, stream>>>(
        hb_bf, w2T, nullptr, h2_bf, as2, ad2, es, ed, 1, NN, 256, 64);
    k_agg1<<<NAGG1, 256, 0, stream>>>(h2_bf, es, ed, row_ptr, csr, bb2, part);
    k_red <<<64, 256, 0, stream>>>(part, gsum);

    // ---- output projection ----
    k_final<<<1, 128, 0, stream>>>(gsum, w_out, b_out, out);
}

// Round 11
// 442.562 us; speedup vs baseline: 1.9971x; 1.0284x over previous
//
#include <hip/hip_runtime.h>

#define NN 50000
#define NE 800000
#define ET 850000   // NE + NN self-loops
#define NBLK 196    // ceil(NN/256) for the parallel scan
#define NAGG1 3125  // k_agg1 grid (= NN/16), also rows of `part`
#define MEGA_W    448                   // weight-prep blocks (114688/256)
#define MEGA_HIST 3125                  // hist blocks (NE/256)
#define MEGA_GRID (MEGA_W + MEGA_HIST)
#define GM64 782                        // (NN+63)/64
#define GM128 391                       // (NN+127)/128
#define EHALF 425000                    // scatter split point
#define SCA 1661                        // ceil(EHALF/256)
#define SCB 1661                        // ceil((ET-EHALF)/256)

typedef unsigned short ushort_t;
typedef unsigned int uint_t;
typedef __attribute__((ext_vector_type(8))) short short8;
typedef __attribute__((ext_vector_type(4))) float f32x4;

// ---------------------------------------------------------------- utilities
__device__ __forceinline__ float elu1(float x) {
    return x > 0.f ? x : (__expf(x) - 1.f);
}
__device__ __forceinline__ float bf2f(ushort_t u) {
    return __uint_as_float(((uint_t)u) << 16);
}
__device__ __forceinline__ ushort_t f2bf(float f) {   // round-to-nearest-even
    uint_t u = __float_as_uint(f);
    u += 0x7FFFu + ((u >> 16) & 1u);
    return (ushort_t)(u >> 16);
}
__device__ __forceinline__ uint_t pack2(float a, float b) {
    return (uint_t)f2bf(a) | ((uint_t)f2bf(b) << 16);
}
__device__ __forceinline__ void gl_lds16(const ushort_t* g, ushort_t* l) {
    // async global->LDS, 16B/lane; LDS dest = wave-uniform base + lane*16
    __builtin_amdgcn_global_load_lds((const __attribute__((address_space(1))) void*)g,
                                     (__attribute__((address_space(3))) void*)l,
                                     16, 0, 0);
}
// bf16 pair (packed in a dword) -> two fp32, exact (bf16 = truncated fp32)
#define ACC2(q, w) do { \
    a0 += (w) * __uint_as_float((q).x << 16); \
    a1 += (w) * __uint_as_float((q).x & 0xFFFF0000u); \
    a2 += (w) * __uint_as_float((q).y << 16); \
    a3 += (w) * __uint_as_float((q).y & 0xFFFF0000u); } while (0)

// ---------------------------------------------------------------- mega prep
// blocks [0,448): weight split-transposes with column permutation:
//   within each 64-col group, col j -> row (j&3)*16 + (j>>2): GEMM frag nt
//   slot l16 = global col l16*4+nt -> lanes own 4 consecutive output cols.
//   (x is NOT pre-cast — fuseA's GEMM converts fp32 A in-register; R11.)
// blocks [448,3573): dst-degree histogram (cursor pre-zeroed by memset;
//   the +1 self-loop is folded into k_scan1).
__global__ void k_mega(const float* __restrict__ w_in, const float* __restrict__ W0,
                       const float* __restrict__ W1, const float* __restrict__ W2,
                       ushort_t* __restrict__ wiT, ushort_t* __restrict__ w0T,
                       ushort_t* __restrict__ w1T, ushort_t* __restrict__ w2T,
                       const int* __restrict__ dst, int* __restrict__ cursor,
                       float* __restrict__ gsum) {
    int b = blockIdx.x, t = threadIdx.x;
    if (b < MEGA_W) {
        if (b == 0 && t < 64) gsum[t] = 0.f;
        int i = b * 256 + t;                      // 0..114687
        const float* W; ushort_t* Bt; int K, N, j;
        if (i < 16384)       { W = w_in; Bt = wiT; K = 256; N = 64;  j = i; }
        else if (i < 32768)  { W = W0;   Bt = w0T; K = 64;  N = 256; j = i - 16384; }
        else if (i < 98304)  { W = W1;   Bt = w1T; K = 256; N = 256; j = i - 32768; }
        else                 { W = W2;   Bt = w2T; K = 256; N = 64;  j = i - 98304; }
        int k = j / N, n = j % N;
        int jj = n & 63;
        int rp = (n & ~63) | ((jj & 3) << 4) | (jj >> 2);   // permuted row
        float v = W[j];
        ushort_t h = f2bf(v);
        Bt[(size_t)rp * 2 * K + k] = h;
        Bt[(size_t)rp * 2 * K + K + k] = f2bf(v - bf2f(h));
    } else {
        int e = (b - MEGA_W) * 256 + t;
        if (e < NE) atomicAdd(&cursor[dst[e]], 1);
    }
}

// ---------------------------------------------------------------- scan
// exclusive scan of (cnt[i]+1) -> row_ptr (the +1 is the self-loop)
__global__ void k_scan1(const int* __restrict__ cnt, int* __restrict__ excl,
                        int* __restrict__ bsum) {
    __shared__ int wsum[4];
    int t = threadIdx.x, lane = t & 63, w = t >> 6;
    int i = blockIdx.x * 256 + t;
    int v = (i < NN) ? cnt[i] + 1 : 0;
    int x = v;
    #pragma unroll
    for (int o = 1; o < 64; o <<= 1) {
        int y = __shfl_up(x, o, 64);
        if (lane >= o) x += y;
    }
    if (lane == 63) wsum[w] = x;
    __syncthreads();
    int wo = 0;
    #pragma unroll
    for (int k = 0; k < 4; k++) wo += (k < w) ? wsum[k] : 0;
    if (i < NN) excl[i] = x - v + wo;
    if (t == 255) bsum[blockIdx.x] = wo + x;     // block total
}

__global__ void k_scan2(int* __restrict__ bsum) {   // 1 block, 256 threads
    __shared__ int wsum[4];
    int t = threadIdx.x, lane = t & 63, w = t >> 6;
    int v = (t < NBLK) ? bsum[t] : 0;
    int x = v;
    #pragma unroll
    for (int o = 1; o < 64; o <<= 1) {
        int y = __shfl_up(x, o, 64);
        if (lane >= o) x += y;
    }
    if (lane == 63) wsum[w] = x;
    __syncthreads();
    int wo = 0;
    #pragma unroll
    for (int k = 0; k < 4; k++) wo += (k < w) ? wsum[k] : 0;
    if (t < NBLK) bsum[t] = x - v + wo;          // exclusive
}

__global__ void k_scan3(int* __restrict__ row_ptr, const int* __restrict__ bsum,
                        int* __restrict__ cursor) {
    int i = blockIdx.x * 256 + threadIdx.x;
    if (i < NN) {
        int r = row_ptr[i] + bsum[blockIdx.x];
        row_ptr[i] = r;
        cursor[i] = r;
    }
    if (i == 0) row_ptr[NN] = ET;
}

// ---------------------------------------------------------------- GEMM body
// C[M x N](bf16) = A[M x K] @ (Bh + Bl), split-bf16 weights.
// AF32: A is fp32; staging converts RNE in-register + ds_write_b128 (bit-
// identical to a separate cast pass). Else A is bf16 via global_load_lds.
// BM=64*MT, BN=16*NT (NT=8 for N=256 GEMMs -> halves A refetch). 256 thr.
// Weight cols permuted (see k_mega) -> ushort4 C stores, float4 bias loads.
template<bool ELU, bool BIAS, bool EDOT, int MT, int NT, bool AF32>
__device__ __forceinline__ void gemm_body(const void* __restrict__ Av,
                                          const ushort_t* __restrict__ Bt,
                                          const float* __restrict__ bias,
                                          ushort_t* __restrict__ C,
                                          const float* __restrict__ a_s,
                                          const float* __restrict__ a_d,
                                          float* __restrict__ es,
                                          float* __restrict__ ed,
                                          int esStride, int M, int K, int N,
                                          int bx, int by) {
    constexpr int HG = NT / 4;                    // 64-col groups per block
    constexpr int BOFF = MT * 4096;               // ushort offset of B region
    __shared__ __align__(16) ushort_t lds[MT * 4096 + NT * 2048];
    int tid = threadIdx.x;
    int wave = tid >> 6, lane = tid & 63;
    int quad = lane >> 4, l16 = lane & 15;
    int mb = bx * (64 * MT), nb = by * (16 * NT);
    int K2 = 2 * K;

    f32x4 acc[MT][NT];
    #pragma unroll
    for (int mt = 0; mt < MT; mt++)
        #pragma unroll
        for (int nt = 0; nt < NT; nt++)
            acc[mt][nt] = (f32x4){0.f, 0.f, 0.f, 0.f};

    for (int k0 = 0; k0 < K; k0 += 64) {
        // ---- stage B first (async DMA) ----
        #pragma unroll
        for (int c = 0; c < NT; c++) {
            int id = wave * NT + c;               // 0 .. 4*NT-1
            int ntile = id % NT;
            int ks = (id / NT) & 1;
            int split = id / (2 * NT);
            int n = nb + ntile * 16 + l16;
            int col = split * K + k0 + ks * 32 + quad * 8;
            gl_lds16(Bt + (size_t)n * K2 + col,
                     &lds[BOFF + ((split * NT + ntile) * 2 + ks) * 512]);
        }
        // ---- stage A ----
        #pragma unroll
        for (int c = 0; c < 2 * MT; c++) {
            int mt = (MT == 2) ? (wave * 2 + (c >> 1)) : wave;
            int ks = (MT == 2) ? (c & 1) : c;
            int row = mb + mt * 16 + l16;
            row = min(row, M - 1);
            int col = k0 + ks * 32 + quad * 8;
            if constexpr (AF32) {
                const float* Af = (const float*)Av;
                float4 v0 = *(const float4*)(Af + (size_t)row * K + col);
                float4 v1 = *(const float4*)(Af + (size_t)row * K + col + 4);
                uint4 pk;
                pk.x = pack2(v0.x, v0.y); pk.y = pack2(v0.z, v0.w);
                pk.z = pack2(v1.x, v1.y); pk.w = pack2(v1.z, v1.w);
                *(uint4*)&lds[(mt * 2 + ks) * 512 + lane * 8] = pk;
            } else {
                gl_lds16((const ushort_t*)Av + (size_t)row * K + col,
                         &lds[(mt * 2 + ks) * 512]);
            }
        }
        __syncthreads();
        #pragma unroll
        for (int ks = 0; ks < 2; ks++) {
            short8 af[MT];
            #pragma unroll
            for (int mt = 0; mt < MT; mt++)
                af[mt] = *(const short8*)&lds[((wave * MT + mt) * 2 + ks) * 512 + lane * 8];
            #pragma unroll
            for (int split = 0; split < 2; split++) {
                short8 bf[NT];
                #pragma unroll
                for (int nt = 0; nt < NT; nt++)
                    bf[nt] = *(const short8*)&lds[BOFF + ((split * NT + nt) * 2 + ks) * 512 + lane * 8];
                #pragma unroll
                for (int mt = 0; mt < MT; mt++)
                    #pragma unroll
                    for (int nt = 0; nt < NT; nt++)
                        acc[mt][nt] = __builtin_amdgcn_mfma_f32_16x16x32_bf16(
                            af[mt], bf[nt], acc[mt][nt], 0, 0, 0);
            }
        }
        __syncthreads();
    }
    // ---- epilogue: frag nt slot l16 = global col l16*4 + (nt%4), group nt/4 ----
    float4 as4[HG], ad4[HG], b4[HG];
    #pragma unroll
    for (int hg = 0; hg < HG; hg++) {
        int cbase = nb + hg * 64 + l16 * 4;
        if (EDOT) {
            as4[hg] = *(const float4*)(a_s + (size_t)(by * HG + hg) * 64 + l16 * 4);
            ad4[hg] = *(const float4*)(a_d + (size_t)(by * HG + hg) * 64 + l16 * 4);
        }
        if (BIAS) b4[hg] = *(const float4*)(bias + cbase);
    }
    #pragma unroll
    for (int mt = 0; mt < MT; mt++) {
        int mrow = mb + (wave * MT + mt) * 16 + quad * 4;
        #pragma unroll
        for (int r = 0; r < 4; r++) {
            int m = mrow + r;
            bool mv = m < M;
            #pragma unroll
            for (int hg = 0; hg < HG; hg++) {
                float v0 = acc[mt][hg * 4 + 0][r];
                float v1 = acc[mt][hg * 4 + 1][r];
                float v2 = acc[mt][hg * 4 + 2][r];
                float v3 = acc[mt][hg * 4 + 3][r];
                if constexpr (EDOT) {
                    float ps = v0 * as4[hg].x + v1 * as4[hg].y + v2 * as4[hg].z + v3 * as4[hg].w;
                    float pd = v0 * ad4[hg].x + v1 * ad4[hg].y + v2 * ad4[hg].z + v3 * ad4[hg].w;
                    #pragma unroll
                    for (int o = 8; o >= 1; o >>= 1) {
                        ps += __shfl_xor(ps, o, 64);
                        pd += __shfl_xor(pd, o, 64);
                    }
                    if (l16 == 0 && mv) {
                        int head = by * HG + hg;
                        es[(size_t)m * esStride + head] = ps;
                        ed[(size_t)m * esStride + head] = pd;
                    }
                }
                if (mv) {
                    if (BIAS) { v0 += b4[hg].x; v1 += b4[hg].y; v2 += b4[hg].z; v3 += b4[hg].w; }
                    if (ELU) { v0 = elu1(v0); v1 = elu1(v1); v2 = elu1(v2); v3 = elu1(v3); }
                    ushort4 o;
                    o.x = f2bf(v0); o.y = f2bf(v1); o.z = f2bf(v2); o.w = f2bf(v3);
                    *(ushort4*)&C[(size_t)m * N + nb + hg * 64 + l16 * 4] = o;
                }
            }
        }
    }
}

template<bool ELU, bool BIAS, bool EDOT, int MT, int NT>
__global__ __launch_bounds__(256) void gemm_mfma(const ushort_t* __restrict__ A,
                                                 const ushort_t* __restrict__ Bt,
                                                 const float* __restrict__ bias,
                                                 ushort_t* __restrict__ C,
                                                 const float* __restrict__ a_s,
                                                 const float* __restrict__ a_d,
                                                 float* __restrict__ es,
                                                 float* __restrict__ ed,
                                                 int esStride, int M, int K, int N) {
    gemm_body<ELU, BIAS, EDOT, MT, NT, false>(A, Bt, bias, C, a_s, a_d, es, ed,
                                              esStride, M, K, N, blockIdx.x, blockIdx.y);
}

// ---- fused launch A: input-projection GEMM reading fp32 x directly
//      (blocks [0,GM64)) + CSR scatter of edges [0,EHALF).
__global__ __launch_bounds__(256) void k_fuseA(const float* __restrict__ x,
                                               const ushort_t* __restrict__ Bt,
                                               const float* __restrict__ bias,
                                               ushort_t* __restrict__ C,
                                               const int* __restrict__ ei,
                                               int* __restrict__ cursor,
                                               int* __restrict__ csr) {
    if (blockIdx.x < GM64) {
        gemm_body<true, true, false, 1, 4, true>(x, Bt, bias, C, nullptr, nullptr,
                                                 nullptr, nullptr, 0, NN, 256, 64,
                                                 blockIdx.x, 0);
    } else {
        int e = (blockIdx.x - GM64) * 256 + threadIdx.x;
        if (e >= EHALF) return;               // EHALF < NE: all real edges
        int s = ei[e], d = ei[NE + e];
        int pos = atomicAdd(&cursor[d], 1);
        csr[pos] = s;
    }
}

// ---- fused launch B: GAT-layer-0 GEMM (flattened 391x2 grid, blocks
//      [0,782)) + CSR scatter of edges [EHALF,ET) incl. self-loops.
__global__ __launch_bounds__(256) void k_fuseB(const ushort_t* __restrict__ A,
                                               const ushort_t* __restrict__ Bt,
                                               ushort_t* __restrict__ C,
                                               const float* __restrict__ a_s,
                                               const float* __restrict__ a_d,
                                               float* __restrict__ es,
                                               float* __restrict__ ed,
                                               const int* __restrict__ ei,
                                               int* __restrict__ cursor,
                                               int* __restrict__ csr) {
    if (blockIdx.x < 2 * GM128) {
        int g = blockIdx.x;
        gemm_body<false, false, true, 2, 8, false>(A, Bt, nullptr, C, a_s, a_d, es, ed,
                                                   4, NN, 64, 256, g % GM128, g / GM128);
    } else {
        int e = EHALF + (blockIdx.x - 2 * GM128) * 256 + threadIdx.x;
        if (e >= ET) return;
        int s, d;
        if (e < NE) { s = ei[e]; d = ei[NE + e]; }
        else        { s = d = e - NE; }
        int pos = atomicAdd(&cursor[d], 1);
        csr[pos] = s;
    }
}

// ------------------------------------------------- softmax aggregate, 4 heads
// 1 wave per node; fast path deg<=64; gather unrolled x4 (R7: x8 regressed via
// VGPR 24->36). Near fabric floor: 207 MB FETCH @ ~3.6 TB/s observed ceiling.
template<bool BFOUT>
__global__ __launch_bounds__(256) void k_agg4(const ushort_t* __restrict__ xl,
                                              const float* __restrict__ es,
                                              const float* __restrict__ ed,
                                              const int* __restrict__ row_ptr,
                                              const int* __restrict__ csr,
                                              const float* __restrict__ bias,
                                              void* __restrict__ outv) {
    __shared__ float wlds[4][256];
    int lane = threadIdx.x & 63, wave = threadIdx.x >> 6;
    int node = blockIdx.x * 4 + wave;
    if (node >= NN) return;
    int head = lane >> 4;
    int start = row_ptr[node], end = row_ptr[node + 1];
    int deg = end - start;
    float4 edv = *(const float4*)(ed + (size_t)node * 4);
    float edh[4] = {edv.x, edv.y, edv.z, edv.w};
    float a0 = 0.f, a1 = 0.f, a2 = 0.f, a3 = 0.f;
    const uint_t* xb = (const uint_t*)xl;

    if (deg <= 64) {
        int i = start + lane;
        bool valid = i < end;
        int idx = csr[valid ? i : start];
        float4 ev = *(const float4*)(es + (size_t)idx * 4);
        float e[4] = {ev.x, ev.y, ev.z, ev.w};
        #pragma unroll
        for (int h = 0; h < 4; h++) {
            float v = e[h] + edh[h];
            v = v > 0.f ? v : 0.2f * v;
            e[h] = valid ? v : -1e30f;
        }
        float cm[4];
        #pragma unroll
        for (int h = 0; h < 4; h++) cm[h] = e[h];
        #pragma unroll
        for (int o = 32; o >= 1; o >>= 1)
            #pragma unroll
            for (int h = 0; h < 4; h++) cm[h] = fmaxf(cm[h], __shfl_xor(cm[h], o, 64));
        float cs[4];
        #pragma unroll
        for (int h = 0; h < 4; h++) cs[h] = valid ? __expf(e[h] - cm[h]) : 0.f;
        #pragma unroll
        for (int o = 32; o >= 1; o >>= 1)
            #pragma unroll
            for (int h = 0; h < 4; h++) cs[h] += __shfl_xor(cs[h], o, 64);
        float4 wv;
        wv.x = valid ? __expf(e[0] - cm[0]) / cs[0] : 0.f;
        wv.y = valid ? __expf(e[1] - cm[1]) / cs[1] : 0.f;
        wv.z = valid ? __expf(e[2] - cm[2]) / cs[2] : 0.f;
        wv.w = valid ? __expf(e[3] - cm[3]) / cs[3] : 0.f;
        *(float4*)&wlds[wave][lane * 4] = wv;
        int t = 0;
        for (; t + 4 <= deg; t += 4) {
            int s0 = __shfl(idx, t + 0, 64), s1 = __shfl(idx, t + 1, 64);
            int s2 = __shfl(idx, t + 2, 64), s3 = __shfl(idx, t + 3, 64);
            uint2 q0 = *(const uint2*)(xb + (size_t)s0 * 128 + lane * 2);
            uint2 q1 = *(const uint2*)(xb + (size_t)s1 * 128 + lane * 2);
            uint2 q2 = *(const uint2*)(xb + (size_t)s2 * 128 + lane * 2);
            uint2 q3 = *(const uint2*)(xb + (size_t)s3 * 128 + lane * 2);
            float w0 = wlds[wave][(t + 0) * 4 + head], w1 = wlds[wave][(t + 1) * 4 + head];
            float w2 = wlds[wave][(t + 2) * 4 + head], w3 = wlds[wave][(t + 3) * 4 + head];
            ACC2(q0, w0); ACC2(q1, w1); ACC2(q2, w2); ACC2(q3, w3);
        }
        for (; t < deg; ++t) {
            int s0 = __shfl(idx, t, 64);
            uint2 q0 = *(const uint2*)(xb + (size_t)s0 * 128 + lane * 2);
            float w0 = wlds[wave][t * 4 + head];
            ACC2(q0, w0);
        }
    } else {
        float m[4], ssum[4];
        #pragma unroll
        for (int h = 0; h < 4; h++) { m[h] = -1e30f; ssum[h] = 0.f; }
        for (int base = start; base < end; base += 64) {
            int i = base + lane;
            bool valid = i < end;
            int idx = csr[valid ? i : start];
            float4 ev = *(const float4*)(es + (size_t)idx * 4);
            float e[4] = {ev.x, ev.y, ev.z, ev.w};
            #pragma unroll
            for (int h = 0; h < 4; h++) {
                float v = e[h] + edh[h];
                v = v > 0.f ? v : 0.2f * v;
                e[h] = valid ? v : -1e30f;
            }
            float cm[4];
            #pragma unroll
            for (int h = 0; h < 4; h++) cm[h] = e[h];
            #pragma unroll
            for (int o = 32; o >= 1; o >>= 1)
                #pragma unroll
                for (int h = 0; h < 4; h++) cm[h] = fmaxf(cm[h], __shfl_xor(cm[h], o, 64));
            float cs[4];
            #pragma unroll
            for (int h = 0; h < 4; h++) cs[h] = valid ? __expf(e[h] - cm[h]) : 0.f;
            #pragma unroll
            for (int o = 32; o >= 1; o >>= 1)
                #pragma unroll
                for (int h = 0; h < 4; h++) cs[h] += __shfl_xor(cs[h], o, 64);
            #pragma unroll
            for (int h = 0; h < 4; h++) {
                float mn = fmaxf(m[h], cm[h]);
                ssum[h] = ssum[h] * __expf(m[h] - mn) + cs[h] * __expf(cm[h] - mn);
                m[h] = mn;
            }
        }
        float inv[4];
        #pragma unroll
        for (int h = 0; h < 4; h++) inv[h] = 1.f / ssum[h];
        for (int base = start; base < end; base += 64) {
            int i = base + lane;
            bool valid = i < end;
            int idx = csr[valid ? i : start];
            int cnt = min(64, end - base);
            float4 ev = *(const float4*)(es + (size_t)idx * 4);
            float e[4] = {ev.x, ev.y, ev.z, ev.w};
            #pragma unroll
            for (int h = 0; h < 4; h++) {
                float v = e[h] + edh[h];
                v = v > 0.f ? v : 0.2f * v;
                e[h] = valid ? __expf(v - m[h]) * inv[h] : 0.f;
            }
            float4 wv; wv.x = e[0]; wv.y = e[1]; wv.z = e[2]; wv.w = e[3];
            *(float4*)&wlds[wave][lane * 4] = wv;
            for (int t = 0; t < cnt; ++t) {
                int s = __shfl(idx, t, 64);
                float w = wlds[wave][t * 4 + head];
                uint2 q = *(const uint2*)(xb + (size_t)s * 128 + lane * 2);
                ACC2(q, w);
            }
        }
    }

    float o0 = elu1(a0 + bias[lane * 4 + 0]);
    float o1 = elu1(a1 + bias[lane * 4 + 1]);
    float o2 = elu1(a2 + bias[lane * 4 + 2]);
    float o3 = elu1(a3 + bias[lane * 4 + 3]);
    if constexpr (BFOUT) {
        ushort4 o; o.x = f2bf(o0); o.y = f2bf(o1); o.z = f2bf(o2); o.w = f2bf(o3);
        *(ushort4*)((ushort_t*)outv + (size_t)node * 256 + lane * 4) = o;
    } else {
        float4 o; o.x = o0; o.y = o1; o.z = o2; o.w = o3;
        *(float4*)((float*)outv + (size_t)node * 256 + lane * 4) = o;
    }
}

// ------------------------------------------------- softmax aggregate, 1 head
// 4 nodes per wave (16-lane groups); partial mean-pool stored per block
// (no atomics — R4: 200k same-line atomics serialized at the coherent point).
__global__ __launch_bounds__(256) void k_agg1(const ushort_t* __restrict__ xl,
                                              const float* __restrict__ es,
                                              const float* __restrict__ ed,
                                              const int* __restrict__ row_ptr,
                                              const int* __restrict__ csr,
                                              const float* __restrict__ bias,
                                              float* __restrict__ part) {
    __shared__ float wlds[4][64];
    __shared__ float ps[4][64];
    int lane = threadIdx.x & 63, wave = threadIdx.x >> 6;
    int g = lane >> 4, l16 = lane & 15;
    int node = blockIdx.x * 16 + wave * 4 + g;
    bool vn = node < NN;
    int start = vn ? row_ptr[node] : 0;
    int end   = vn ? row_ptr[node + 1] : 0;
    float edl = vn ? ed[node] : 0.f;

    float m = -1e30f, ssum = 0.f;
    for (int base = start; base < end; base += 16) {
        int i = base + l16;
        bool valid = i < end;
        int idx = csr[valid ? i : start];
        float e = es[idx] + edl;
        e = e > 0.f ? e : 0.2f * e;
        e = valid ? e : -1e30f;
        float cm = e;
        #pragma unroll
        for (int o = 8; o >= 1; o >>= 1) cm = fmaxf(cm, __shfl_xor(cm, o, 64));
        float cs = valid ? __expf(e - cm) : 0.f;
        #pragma unroll
        for (int o = 8; o >= 1; o >>= 1) cs += __shfl_xor(cs, o, 64);
        float mn = fmaxf(m, cm);
        ssum = ssum * __expf(m - mn) + cs * __expf(cm - mn);
        m = mn;
    }
    float inv = 1.f / ssum;

    float a0 = 0.f, a1 = 0.f, a2 = 0.f, a3 = 0.f;
    const uint_t* xb = (const uint_t*)xl;
    for (int base = start; base < end; base += 16) {
        int i = base + l16;
        bool valid = i < end;
        int idx = csr[valid ? i : start];
        int cnt = min(16, end - base);
        float e = es[idx] + edl;
        e = e > 0.f ? e : 0.2f * e;
        wlds[wave][g * 16 + l16] = valid ? __expf(e - m) * inv : 0.f;
        int t = 0;
        for (; t + 4 <= cnt; t += 4) {
            int s0 = __shfl(idx, g * 16 + t + 0, 64), s1 = __shfl(idx, g * 16 + t + 1, 64);
            int s2 = __shfl(idx, g * 16 + t + 2, 64), s3 = __shfl(idx, g * 16 + t + 3, 64);
            uint2 q0 = *(const uint2*)(xb + (size_t)s0 * 32 + l16 * 2);
            uint2 q1 = *(const uint2*)(xb + (size_t)s1 * 32 + l16 * 2);
            uint2 q2 = *(const uint2*)(xb + (size_t)s2 * 32 + l16 * 2);
            uint2 q3 = *(const uint2*)(xb + (size_t)s3 * 32 + l16 * 2);
            float w0 = wlds[wave][g * 16 + t + 0], w1 = wlds[wave][g * 16 + t + 1];
            float w2 = wlds[wave][g * 16 + t + 2], w3 = wlds[wave][g * 16 + t + 3];
            ACC2(q0, w0); ACC2(q1, w1); ACC2(q2, w2); ACC2(q3, w3);
        }
        for (; t < cnt; ++t) {
            int s = __shfl(idx, g * 16 + t, 64);
            float w = wlds[wave][g * 16 + t];
            uint2 q = *(const uint2*)(xb + (size_t)s * 32 + l16 * 2);
            ACC2(q, w);
        }
    }

    float o[4];
    o[0] = vn ? elu1(a0 + bias[l16 * 4 + 0]) : 0.f;
    o[1] = vn ? elu1(a1 + bias[l16 * 4 + 1]) : 0.f;
    o[2] = vn ? elu1(a2 + bias[l16 * 4 + 2]) : 0.f;
    o[3] = vn ? elu1(a3 + bias[l16 * 4 + 3]) : 0.f;
    #pragma unroll
    for (int j = 0; j < 4; j++) {
        o[j] += __shfl_xor(o[j], 16, 64);
        o[j] += __shfl_xor(o[j], 32, 64);
    }
    if (lane < 16) {
        float4 v; v.x = o[0]; v.y = o[1]; v.z = o[2]; v.w = o[3];
        *(float4*)&ps[wave][l16 * 4] = v;
    }
    __syncthreads();
    int tid = threadIdx.x;
    if (tid < 64) {
        float tot = ps[0][tid] + ps[1][tid] + ps[2][tid] + ps[3][tid];
        part[(size_t)blockIdx.x * 64 + tid] = tot;
    }
}

// ---- reduce part[NAGG1][64] -> gsum[64] (few blocks => few atomics) ----
__global__ void k_red(const float* __restrict__ part, float* __restrict__ gsum) {
    __shared__ float sm[4][64];
    int t = threadIdx.x, c = t & 63, w = t >> 6;
    float s = 0.f;
    for (int r = blockIdx.x * 4 + w; r < NAGG1; r += gridDim.x * 4)
        s += part[(size_t)r * 64 + c];
    sm[w][c] = s;
    __syncthreads();
    if (w == 0) {
        float tot = sm[0][c] + sm[1][c] + sm[2][c] + sm[3][c];
        atomicAdd(&gsum[c], tot);
    }
}

// ---------------------------------------------------------------- final
__global__ void k_final(const float* __restrict__ gsum, const float* __restrict__ w_out,
                        const float* __restrict__ b_out, float* __restrict__ out) {
    int j = threadIdx.x;   // 128
    float s = b_out[j];
    const float invn = 1.f / (float)NN;
    #pragma unroll 8
    for (int k = 0; k < 64; k++)
        s += (gsum[k] * invn) * w_out[k * 128 + j];
    out[j] = s;
}

// ---------------------------------------------------------------- launcher
extern "C" void kernel_launch(void* const* d_in, const int* in_sizes, int n_in,
                              void* d_out, int out_size, void* d_ws, size_t ws_size,
                              hipStream_t stream) {
    const float* x    = (const float*)d_in[0];
    const int*   ei   = (const int*)d_in[1];
    const float* w_in = (const float*)d_in[2];
    const float* b_in = (const float*)d_in[3];
    const float* W0   = (const float*)d_in[4];
    const float* as0  = (const float*)d_in[5];
    const float* ad0  = (const float*)d_in[6];
    const float* bb0  = (const float*)d_in[7];
    const float* W1   = (const float*)d_in[8];
    const float* as1  = (const float*)d_in[9];
    const float* ad1  = (const float*)d_in[10];
    const float* bb1  = (const float*)d_in[11];
    const float* W2   = (const float*)d_in[12];
    const float* as2  = (const float*)d_in[13];
    const float* ad2  = (const float*)d_in[14];
    const float* bb2  = (const float*)d_in[15];
    const float* w_out= (const float*)d_in[16];
    const float* b_out= (const float*)d_in[17];
    float* out = (float*)d_out;

    char* p = (char*)d_ws;
    size_t off = 0;
    auto take = [&](size_t bytes) {
        char* r = p + off;
        off = (off + bytes + 255) & ~(size_t)255;
        return r;
    };
    ushort_t* h0b    = (ushort_t*)take((size_t)NN * 64 * 2);  //  6.4 MB
    ushort_t* xl_bf  = (ushort_t*)take((size_t)NN * 256 * 2); // 25.6 MB
    ushort_t* hb_bf  = (ushort_t*)take((size_t)NN * 256 * 2); // 25.6 MB
    ushort_t* h2_bf  = (ushort_t*)take((size_t)NN * 64 * 2);  //  6.4 MB
    ushort_t* wiT    = (ushort_t*)take((size_t)64 * 512 * 2);
    ushort_t* w0T    = (ushort_t*)take((size_t)256 * 128 * 2);
    ushort_t* w1T    = (ushort_t*)take((size_t)256 * 512 * 2);
    ushort_t* w2T    = (ushort_t*)take((size_t)64 * 512 * 2);
    float*    es     = (float*)take((size_t)NN * 4 * 4);
    float*    ed     = (float*)take((size_t)NN * 4 * 4);
    int*      row_ptr= (int*)take((size_t)(NN + 1) * 4);
    int*      cursor = (int*)take((size_t)NN * 4);
    int*      csr    = (int*)take((size_t)ET * 4);
    int*      bsum   = (int*)take((size_t)NBLK * 4);
    float*    part   = (float*)take((size_t)NAGG1 * 64 * 4);  // 0.8 MB
    float*    gsum   = (float*)take(64 * 4);

    // cursor := 0 (degree histogram base; self-loop +1 folded into scan1)
    hipMemsetAsync(cursor, 0, (size_t)NN * 4, stream);

    // ---- mega prep: weight split-transpose + dst histogram ----
    k_mega<<<MEGA_GRID, 256, 0, stream>>>(w_in, W0, W1, W2, wiT, w0T, w1T, w2T,
                                          ei + NE, cursor, gsum);

    // ---- scan (cnt+1) -> row_ptr ----
    k_scan1<<<NBLK, 256, 0, stream>>>(cursor, row_ptr, bsum);
    k_scan2<<<1, 256, 0, stream>>>(bsum);
    k_scan3<<<NBLK, 256, 0, stream>>>(row_ptr, bsum, cursor);

    // ---- fused A: input projection GEMM (fp32 A) || scatter [0,EHALF) ----
    k_fuseA<<<GM64 + SCA, 256, 0, stream>>>(x, wiT, b_in, h0b, ei, cursor, csr);

    // ---- fused B: GAT layer-0 GEMM (es/ed epilogue) || scatter [EHALF,ET) ----
    k_fuseB<<<2 * GM128 + SCB, 256, 0, stream>>>(h0b, w0T, xl_bf, as0, ad0,
                                                 es, ed, ei, cursor, csr);
    k_agg4<true><<<(NN + 3) / 4, 256, 0, stream>>>(xl_bf, es, ed, row_ptr, csr, bb0, hb_bf);

    // ---- GAT layer 1 (heads=4, concat); BN=128 ----
    gemm_mfma<false, false, true, 2, 8><<<dim3(GM128, 2), 256, 0, stream>>>(
        hb_bf, w1T, nullptr, xl_bf, as1, ad1, es, ed, 4, NN, 256, 256);
    k_agg4<true><<<(NN + 3) / 4, 256, 0, stream>>>(xl_bf, es, ed, row_ptr, csr, bb1, hb_bf);

    // ---- GAT layer 2 (heads=1) + partial mean-pool ----
    gemm_mfma<false, false, true, 1, 4><<<dim3(GM64, 1), 256, 0, stream>>>(
        hb_bf, w2T, nullptr, h2_bf, as2, ad2, es, ed, 1, NN, 256, 64);
    k_agg1<<<NAGG1, 256, 0, stream>>>(h2_bf, es, ed, row_ptr, csr, bb2, part);
    k_red <<<64, 256, 0, stream>>>(part, gsum);

    // ---- output projection ----
    k_final<<<1, 128, 0, stream>>>(gsum, w_out, b_out, out);
}